// Round 2
// baseline (22677.071 us; speedup 1.0000x reference)
//
#include <hip/hip_runtime.h>
#include <hip/hip_bf16.h>

using bf16 = __hip_bfloat16;

constexpr int BB    = 2;
constexpr int NSEQ  = 8193;
constexpr int CDIM  = 512;
constexpr int NH    = 8;
constexpr int DHD   = 64;
constexpr int ML    = 256;
constexpr int LF    = 33;
constexpr int NPAD  = 8448;
constexpr int PADL  = 255;
constexpr int ROWS  = BB * NSEQ;     // 16386
constexpr int BH    = BB * NH;       // 16
constexpr int RKS   = 33;
constexpr int HG    = 91;
constexpr int HW2   = HG * HG;       // 8281
constexpr int NPATCH = 8192;

__device__ __forceinline__ float b2f(unsigned short u) {
  union { unsigned int i; float f; } x; x.i = (unsigned int)u << 16; return x.f;
}

// ---------------- small kernels ----------------

__global__ __launch_bounds__(256) void k_zero(uint4* __restrict__ p, long n) {
  long i = (long)blockIdx.x * 256 + threadIdx.x;
  const long st = (long)gridDim.x * 256;
  for (; i < n; i += st) p[i] = make_uint4(0u, 0u, 0u, 0u);
}

__global__ __launch_bounds__(256) void k_build_h(
    const float* __restrict__ x, const float* __restrict__ cls, float* __restrict__ h)
{
  long idx = (long)blockIdx.x * 256 + threadIdx.x;
  if (idx >= (long)ROWS * CDIM) return;
  int c = idx & 511;
  long r = idx >> 9;
  int b = (int)(r / NSEQ), i = (int)(r % NSEQ);
  h[idx] = (i == 0) ? cls[c] : x[((long)b * (NSEQ - 1) + (i - 1)) * CDIM + c];
}

// per-row LN stats: stats[row] = (mu, rstd)
__global__ __launch_bounds__(256) void k_ln_stats(
    const float* __restrict__ X, float* __restrict__ stats)
{
  __shared__ float red[4];
  const long row = blockIdx.x;
  const float* x = X + row * CDIM;
  const int t = threadIdx.x;
  float a0 = x[t], a1 = x[t + 256];
  float s = a0 + a1;
  for (int o = 32; o; o >>= 1) s += __shfl_down(s, o);
  if ((t & 63) == 0) red[t >> 6] = s;
  __syncthreads();
  const float mu = (red[0] + red[1] + red[2] + red[3]) * (1.0f / CDIM);
  __syncthreads();
  float d0 = a0 - mu, d1 = a1 - mu;
  float q = d0 * d0 + d1 * d1;
  for (int o = 32; o; o >>= 1) q += __shfl_down(q, o);
  if ((t & 63) == 0) red[t >> 6] = q;
  __syncthreads();
  if (t == 0) {
    const float var = (red[0] + red[1] + red[2] + red[3]) * (1.0f / CDIM);
    stats[row * 2]     = mu;
    stats[row * 2 + 1] = rsqrtf(var + 1e-5f);
  }
}

__global__ __launch_bounds__(256) void k_final_ln(
    const float* __restrict__ H, const float* __restrict__ g,
    const float* __restrict__ bb, float* __restrict__ out)
{
  __shared__ float red[4];
  const float* x = H + (long)blockIdx.x * NSEQ * CDIM;
  const int t = threadIdx.x;
  float a0 = x[t], a1 = x[t + 256];
  float s = a0 + a1;
  for (int o = 32; o; o >>= 1) s += __shfl_down(s, o);
  if ((t & 63) == 0) red[t >> 6] = s;
  __syncthreads();
  const float mu = (red[0] + red[1] + red[2] + red[3]) * (1.0f / CDIM);
  __syncthreads();
  float d0 = a0 - mu, d1 = a1 - mu;
  float q = d0 * d0 + d1 * d1;
  for (int o = 32; o; o >>= 1) q += __shfl_down(q, o);
  if ((t & 63) == 0) red[t >> 6] = q;
  __syncthreads();
  const float var = (red[0] + red[1] + red[2] + red[3]) * (1.0f / CDIM);
  const float rs = rsqrtf(var + 1e-5f);
  out[blockIdx.x * CDIM + t]       = d0 * rs * g[t]       + bb[t];
  out[blockIdx.x * CDIM + t + 256] = d1 * rs * g[t + 256] + bb[t + 256];
}

__global__ __launch_bounds__(256) void k_landmark(
    const bf16* __restrict__ src, bf16* __restrict__ dst)
{
  int idx = blockIdx.x * 256 + threadIdx.x;
  if (idx >= BH * ML * DHD) return;
  int d = idx & 63, j = (idx >> 6) & 255, bh = idx >> 14;
  const unsigned short* p = (const unsigned short*)src + ((long)bh * NPAD + (long)j * LF) * DHD + d;
  float s = 0.f;
#pragma unroll
  for (int t = 0; t < LF; ++t) s += b2f(p[t * DHD]);
  dst[idx] = __float2bfloat16(s * (1.0f / LF));
}

// row softmax in place; one block per row; W <= NPAD
__global__ __launch_bounds__(256) void k_softmax(float* __restrict__ S, int W)
{
  __shared__ float buf[NPAD];
  __shared__ float red[4];
  float* p = S + (long)blockIdx.x * W;
  const int t = threadIdx.x;
  float mx = -3.4e38f;
  for (int j = t; j < W; j += 256) { float v = p[j]; buf[j] = v; mx = fmaxf(mx, v); }
  for (int o = 32; o; o >>= 1) mx = fmaxf(mx, __shfl_down(mx, o));
  if ((t & 63) == 0) red[t >> 6] = mx;
  __syncthreads();
  mx = fmaxf(fmaxf(red[0], red[1]), fmaxf(red[2], red[3]));
  __syncthreads();
  float sum = 0.f;
  for (int j = t; j < W; j += 256) { float e = __expf(buf[j] - mx); buf[j] = e; sum += e; }
  for (int o = 32; o; o >>= 1) sum += __shfl_down(sum, o);
  if ((t & 63) == 0) red[t >> 6] = sum;
  __syncthreads();
  const float inv = 1.0f / (red[0] + red[1] + red[2] + red[3]);
  for (int j = t; j < W; j += 256) p[j] = buf[j] * inv;
}

__global__ __launch_bounds__(256) void k_pinv_prep(
    const float* __restrict__ A, float* __restrict__ red)
{
  __shared__ float r1[4], r2[4];
  const float* Ab = A + (long)blockIdx.x * ML * ML;
  const int t = threadIdx.x;
  float rs = 0.f, cs = 0.f;
  for (int j = 0; j < ML; ++j) { rs += fabsf(Ab[t * ML + j]); cs += fabsf(Ab[j * ML + t]); }
  for (int o = 32; o; o >>= 1) { rs = fmaxf(rs, __shfl_down(rs, o)); cs = fmaxf(cs, __shfl_down(cs, o)); }
  if ((t & 63) == 0) { r1[t >> 6] = rs; r2[t >> 6] = cs; }
  __syncthreads();
  if (t == 0) {
    red[blockIdx.x]      = fmaxf(fmaxf(r1[0], r1[1]), fmaxf(r1[2], r1[3]));
    red[16 + blockIdx.x] = fmaxf(fmaxf(r2[0], r2[1]), fmaxf(r2[2], r2[3]));
  }
}

__global__ void k_pinv_scale(float* __restrict__ red)
{
  if (threadIdx.x == 0 && blockIdx.x == 0) {
    float cmax = red[0], rmax = red[16];
    for (int i = 1; i < 16; ++i) { cmax = fmaxf(cmax, red[i]); rmax = fmaxf(rmax, red[16 + i]); }
    red[32] = 1.0f / (cmax * rmax);
  }
}

// z0 = attn2^T * scale
__global__ __launch_bounds__(256) void k_tscale(
    const float* __restrict__ A, const float* __restrict__ red, float* __restrict__ Z)
{
  long idx = (long)blockIdx.x * 256 + threadIdx.x;
  if (idx >= (long)BH * ML * ML) return;
  int j = idx & 255, i = (int)((idx >> 8) & 255);
  long bh = idx >> 16;
  Z[idx] = A[(bh << 16) + ((long)j << 8) + i] * red[32];
}

// Y = a*I - X
__global__ __launch_bounds__(256) void k_aib(
    const float* __restrict__ X, float* __restrict__ Y, float a)
{
  long idx = (long)blockIdx.x * 256 + threadIdx.x;
  if (idx >= (long)BH * ML * ML) return;
  int j = idx & 255, i = (int)((idx >> 8) & 255);
  float v = -X[idx];
  if (i == j) v += a;
  Y[idx] = v;
}

// depthwise conv over sequence axis of v (bf16), out1 (bf16) += res
__global__ __launch_bounds__(256) void k_resconv(
    const bf16* __restrict__ v, const float* __restrict__ w, bf16* __restrict__ out)
{
  long idx = (long)blockIdx.x * 256 + threadIdx.x;
  if (idx >= (long)BH * NPAD * DHD) return;
  int d = idx & 63;
  long r = idx >> 6;
  int i = (int)(r % NPAD);
  int bh = (int)(r / NPAD);
  const float* wp = w + (bh & 7) * RKS;
  const unsigned short* vb = (const unsigned short*)v + (long)bh * NPAD * DHD + d;
  float s = 0.f;
#pragma unroll
  for (int t = 0; t < RKS; ++t) {
    int src = i + t - 16;
    if (src >= 0 && src < NPAD) s += b2f(vb[(long)src * DHD]) * wp[t];
  }
  out[idx] = __float2bfloat16(__bfloat162float(out[idx]) + s);
}

// ---------------- PPEG ----------------

__global__ __launch_bounds__(256) void k_ppeg_build(
    const float* __restrict__ h, float* __restrict__ feat)
{
  long idx = (long)blockIdx.x * 256 + threadIdx.x;
  if (idx >= (long)BB * CDIM * HW2) return;
  int pos = (int)(idx % HW2);
  long t = idx / HW2;
  int c = (int)(t % CDIM), b = (int)(t / CDIM);
  int src = pos < NPATCH ? pos : pos - NPATCH;
  feat[idx] = h[((long)b * NSEQ + 1 + src) * CDIM + c];
}

__device__ __forceinline__ float convk(const float* __restrict__ f, int y, int x,
                                       const float* __restrict__ w, int k)
{
  int r = k >> 1;
  float s = 0.f;
  for (int dy = 0; dy < k; ++dy) {
    int yy = y + dy - r;
    if (yy < 0 || yy >= HG) continue;
    for (int dx = 0; dx < k; ++dx) {
      int xx = x + dx - r;
      if (xx < 0 || xx >= HG) continue;
      s += f[yy * HG + xx] * w[dy * k + dx];
    }
  }
  return s;
}

__global__ __launch_bounds__(256) void k_ppeg_conv(
    const float* __restrict__ feat,
    const float* __restrict__ w7, const float* __restrict__ b7,
    const float* __restrict__ w5, const float* __restrict__ b5,
    const float* __restrict__ w3, const float* __restrict__ b3,
    float* __restrict__ h)
{
  long idx = (long)blockIdx.x * 256 + threadIdx.x;
  if (idx >= (long)BB * CDIM * HW2) return;
  int pos = (int)(idx % HW2);
  if (pos >= NPATCH) return;
  long t = idx / HW2;
  int c = (int)(t % CDIM), b = (int)(t / CDIM);
  const float* f = feat + (idx - pos);
  int y = pos / HG, x = pos % HG;
  float s = f[pos];
  s += convk(f, y, x, w7 + c * 49, 7) + b7[c];
  s += convk(f, y, x, w5 + c * 25, 5) + b5[c];
  s += convk(f, y, x, w3 + c * 9, 3) + b3[c];
  h[((long)b * NSEQ + 1 + pos) * CDIM + c] = s;
}

// ---------------- GEMMs ----------------

// C fp32 [M,N] = A_bf16[M,64] @ B_bf16[N,64]^T ; K fixed = 64; M,N multiples of 64
__global__ __launch_bounds__(256) void k_gemm_nt64(
    const bf16* __restrict__ A, const bf16* __restrict__ Bm, float* __restrict__ Cm,
    int N, long sA, long sB, long sC)
{
  __shared__ float As[64][65], Bs[64][65];
  const bf16* Ab = A + (long)blockIdx.z * sA;
  const bf16* Bb = Bm + (long)blockIdx.z * sB;
  float* Cb = Cm + (long)blockIdx.z * sC;
  const int m0 = blockIdx.x << 6, n0 = blockIdx.y << 6;
  const int t = threadIdx.x;
  const int row = t >> 2, c0 = (t & 3) << 4;
  {
    const unsigned short* ap = (const unsigned short*)Ab + (long)(m0 + row) * DHD + c0;
    const unsigned short* bp = (const unsigned short*)Bb + (long)(n0 + row) * DHD + c0;
    uint4 ua0 = *(const uint4*)ap, ua1 = *(const uint4*)(ap + 8);
    uint4 ub0 = *(const uint4*)bp, ub1 = *(const uint4*)(bp + 8);
    float* pa = &As[row][c0];
    float* pb = &Bs[row][c0];
    pa[0]  = b2f((unsigned short)ua0.x); pa[1]  = b2f((unsigned short)(ua0.x >> 16));
    pa[2]  = b2f((unsigned short)ua0.y); pa[3]  = b2f((unsigned short)(ua0.y >> 16));
    pa[4]  = b2f((unsigned short)ua0.z); pa[5]  = b2f((unsigned short)(ua0.z >> 16));
    pa[6]  = b2f((unsigned short)ua0.w); pa[7]  = b2f((unsigned short)(ua0.w >> 16));
    pa[8]  = b2f((unsigned short)ua1.x); pa[9]  = b2f((unsigned short)(ua1.x >> 16));
    pa[10] = b2f((unsigned short)ua1.y); pa[11] = b2f((unsigned short)(ua1.y >> 16));
    pa[12] = b2f((unsigned short)ua1.z); pa[13] = b2f((unsigned short)(ua1.z >> 16));
    pa[14] = b2f((unsigned short)ua1.w); pa[15] = b2f((unsigned short)(ua1.w >> 16));
    pb[0]  = b2f((unsigned short)ub0.x); pb[1]  = b2f((unsigned short)(ub0.x >> 16));
    pb[2]  = b2f((unsigned short)ub0.y); pb[3]  = b2f((unsigned short)(ub0.y >> 16));
    pb[4]  = b2f((unsigned short)ub0.z); pb[5]  = b2f((unsigned short)(ub0.z >> 16));
    pb[6]  = b2f((unsigned short)ub0.w); pb[7]  = b2f((unsigned short)(ub0.w >> 16));
    pb[8]  = b2f((unsigned short)ub1.x); pb[9]  = b2f((unsigned short)(ub1.x >> 16));
    pb[10] = b2f((unsigned short)ub1.y); pb[11] = b2f((unsigned short)(ub1.y >> 16));
    pb[12] = b2f((unsigned short)ub1.z); pb[13] = b2f((unsigned short)(ub1.z >> 16));
    pb[14] = b2f((unsigned short)ub1.w); pb[15] = b2f((unsigned short)(ub1.w >> 16));
  }
  __syncthreads();
  const int ty = t >> 4, tx = t & 15;
  float acc[4][4] = {};
#pragma unroll 16
  for (int kk = 0; kk < 64; ++kk) {
    float a[4], b[4];
#pragma unroll
    for (int i = 0; i < 4; ++i) a[i] = As[ty * 4 + i][kk];
#pragma unroll
    for (int j = 0; j < 4; ++j) b[j] = Bs[tx * 4 + j][kk];
#pragma unroll
    for (int i = 0; i < 4; ++i)
#pragma unroll
      for (int j = 0; j < 4; ++j) acc[i][j] += a[i] * b[j];
  }
#pragma unroll
  for (int i = 0; i < 4; ++i)
#pragma unroll
    for (int j = 0; j < 4; ++j)
      Cb[(long)(m0 + ty * 4 + i) * N + n0 + tx * 4 + j] = acc[i][j];
}

__device__ __forceinline__ float4 load4(const float* p) { return *(const float4*)p; }
__device__ __forceinline__ float4 load4(const bf16* p) {
  ushort4 u = *(const ushort4*)p;
  return make_float4(b2f(u.x), b2f(u.y), b2f(u.z), b2f(u.w));
}
__device__ __forceinline__ void store1(float* p, float v) { *p = v; }
__device__ __forceinline__ void store1(bf16* p, float v) { *p = __float2bfloat16(v); }

// C[M,N] = alpha * A_f32[M,K] @ B[K,N] + diag*I  (batched via grid.z)
template<typename TB, typename TC>
__global__ __launch_bounds__(256) void k_gemm_nn(
    const float* __restrict__ A, const TB* __restrict__ Bm, TC* __restrict__ Cm,
    int M, int N, int K, long sA, long sB, long sC, float alpha, float diag)
{
  __shared__ float As[64][17], Bs[16][68];
  const float* Ab = A + (long)blockIdx.z * sA;
  const TB* Bb = Bm + (long)blockIdx.z * sB;
  TC* Cb = Cm + (long)blockIdx.z * sC;
  const int m0 = blockIdx.x << 6, n0 = blockIdx.y << 6;
  const int t = threadIdx.x, ty = t >> 4, tx = t & 15;
  const int lr = t >> 2, lk = (t & 3) << 2;
  const int bk = t >> 4, bn = (t & 15) << 2;
  float acc[4][4] = {};
  for (int k0 = 0; k0 < K; k0 += 16) {
    float4 av = make_float4(0.f, 0.f, 0.f, 0.f), bv = make_float4(0.f, 0.f, 0.f, 0.f);
    if (m0 + lr < M) av = *(const float4*)(Ab + (long)(m0 + lr) * K + k0 + lk);
    if (n0 + bn < N) bv = load4(Bb + (long)(k0 + bk) * N + n0 + bn);
    As[lr][lk] = av.x; As[lr][lk + 1] = av.y; As[lr][lk + 2] = av.z; As[lr][lk + 3] = av.w;
    Bs[bk][bn] = bv.x; Bs[bk][bn + 1] = bv.y; Bs[bk][bn + 2] = bv.z; Bs[bk][bn + 3] = bv.w;
    __syncthreads();
#pragma unroll
    for (int kk = 0; kk < 16; ++kk) {
      float a[4], b[4];
#pragma unroll
      for (int i = 0; i < 4; ++i) a[i] = As[ty * 4 + i][kk];
#pragma unroll
      for (int j = 0; j < 4; ++j) b[j] = Bs[kk][tx * 4 + j];
#pragma unroll
      for (int i = 0; i < 4; ++i)
#pragma unroll
        for (int j = 0; j < 4; ++j) acc[i][j] += a[i] * b[j];
    }
    __syncthreads();
  }
#pragma unroll
  for (int i = 0; i < 4; ++i) {
    int r = m0 + ty * 4 + i;
    if (r >= M) continue;
#pragma unroll
    for (int j = 0; j < 4; ++j) {
      int n = n0 + tx * 4 + j;
      if (n >= N) continue;
      float v = alpha * acc[i][j];
      if (r == n) v += diag;
      store1(&Cb[(long)r * N + n], v);
    }
  }
}

// qkv = LN(h) @ qkv_w^T (LN fused via stats), scatter bf16 into padded q/k/v (q*0.125)
__global__ __launch_bounds__(256) void k_gemm_qkv(
    const float* __restrict__ H, const float* __restrict__ st,
    const float* __restrict__ ga, const float* __restrict__ be,
    const float* __restrict__ Wm,
    bf16* __restrict__ Q, bf16* __restrict__ Kp, bf16* __restrict__ V)
{
  __shared__ float As[64][17], Bs[64][17];
  const int m0 = blockIdx.x << 6, n0 = blockIdx.y << 6;
  const int t = threadIdx.x, ty = t >> 4, tx = t & 15;
  const int lr = t >> 2, lk = (t & 3) << 2;
  const int arow = m0 + lr;
  float mu = 0.f, rs = 0.f;
  if (arow < ROWS) { float2 s2 = *(const float2*)(st + arow * 2); mu = s2.x; rs = s2.y; }
  float acc[4][4] = {};
  for (int k0 = 0; k0 < CDIM; k0 += 16) {
    float4 av = make_float4(0.f, 0.f, 0.f, 0.f);
    if (arow < ROWS) {
      float4 hv = *(const float4*)(H + (long)arow * CDIM + k0 + lk);
      float4 gv = *(const float4*)(ga + k0 + lk);
      float4 b2 = *(const float4*)(be + k0 + lk);
      av.x = (hv.x - mu) * rs * gv.x + b2.x;
      av.y = (hv.y - mu) * rs * gv.y + b2.y;
      av.z = (hv.z - mu) * rs * gv.z + b2.z;
      av.w = (hv.w - mu) * rs * gv.w + b2.w;
    }
    float4 wv = *(const float4*)(Wm + (long)(n0 + lr) * CDIM + k0 + lk);
    As[lr][lk] = av.x; As[lr][lk + 1] = av.y; As[lr][lk + 2] = av.z; As[lr][lk + 3] = av.w;
    Bs[lr][lk] = wv.x; Bs[lr][lk + 1] = wv.y; Bs[lr][lk + 2] = wv.z; Bs[lr][lk + 3] = wv.w;
    __syncthreads();
#pragma unroll
    for (int kk = 0; kk < 16; ++kk) {
      float a[4], b[4];
#pragma unroll
      for (int i = 0; i < 4; ++i) a[i] = As[ty * 4 + i][kk];
#pragma unroll
      for (int j = 0; j < 4; ++j) b[j] = Bs[tx * 4 + j][kk];
#pragma unroll
      for (int i = 0; i < 4; ++i)
#pragma unroll
        for (int j = 0; j < 4; ++j) acc[i][j] += a[i] * b[j];
    }
    __syncthreads();
  }
#pragma unroll
  for (int i = 0; i < 4; ++i) {
    int r = m0 + ty * 4 + i;
    if (r >= ROWS) continue;
    int b = r / NSEQ, ii = r - b * NSEQ;
#pragma unroll
    for (int j = 0; j < 4; ++j) {
      int n = n0 + tx * 4 + j;
      int which = n >> 9, rem = n & 511, hd = rem >> 6, d = rem & 63;
      float val = acc[i][j];
      if (which == 0) val *= 0.125f;
      bf16* dst = which == 0 ? Q : (which == 1 ? Kp : V);
      dst[(((long)(b * NH + hd)) * NPAD + PADL + ii) * DHD + d] = __float2bfloat16(val);
    }
  }
}

// h += merge(out1_bf16) @ out_w^T + out_b   (merge fused into A-load)
__global__ __launch_bounds__(256) void k_gemm_out(
    const bf16* __restrict__ O1, const float* __restrict__ Wm,
    const float* __restrict__ bias, float* __restrict__ Hh)
{
  __shared__ float As[64][17], Bs[64][17];
  const int m0 = blockIdx.x << 6, n0 = blockIdx.y << 6;
  const int t = threadIdx.x, ty = t >> 4, tx = t & 15;
  const int lr = t >> 2, lk = (t & 3) << 2;
  const int arow = m0 + lr;
  int bb = 0, ii = 0;
  if (arow < ROWS) { bb = arow / NSEQ; ii = arow - bb * NSEQ; }
  float acc[4][4] = {};
  for (int k0 = 0; k0 < CDIM; k0 += 16) {
    float4 av = make_float4(0.f, 0.f, 0.f, 0.f);
    if (arow < ROWS) {
      int c = k0 + lk, hd = c >> 6, d = c & 63;
      const unsigned short* op =
          (const unsigned short*)O1 + (((long)(bb * NH + hd)) * NPAD + PADL + ii) * DHD + d;
      ushort4 u = *(const ushort4*)op;
      av = make_float4(b2f(u.x), b2f(u.y), b2f(u.z), b2f(u.w));
    }
    float4 wv = *(const float4*)(Wm + (long)(n0 + lr) * CDIM + k0 + lk);
    As[lr][lk] = av.x; As[lr][lk + 1] = av.y; As[lr][lk + 2] = av.z; As[lr][lk + 3] = av.w;
    Bs[lr][lk] = wv.x; Bs[lr][lk + 1] = wv.y; Bs[lr][lk + 2] = wv.z; Bs[lr][lk + 3] = wv.w;
    __syncthreads();
#pragma unroll
    for (int kk = 0; kk < 16; ++kk) {
      float a[4], b[4];
#pragma unroll
      for (int i = 0; i < 4; ++i) a[i] = As[ty * 4 + i][kk];
#pragma unroll
      for (int j = 0; j < 4; ++j) b[j] = Bs[tx * 4 + j][kk];
#pragma unroll
      for (int i = 0; i < 4; ++i)
#pragma unroll
        for (int j = 0; j < 4; ++j) acc[i][j] += a[i] * b[j];
    }
    __syncthreads();
  }
#pragma unroll
  for (int i = 0; i < 4; ++i) {
    int r = m0 + ty * 4 + i;
    if (r >= ROWS) continue;
#pragma unroll
    for (int j = 0; j < 4; ++j) {
      int n = n0 + tx * 4 + j;
      Hh[(long)r * CDIM + n] += acc[i][j] + bias[n];
    }
  }
}

// ---------------- host orchestration ----------------

struct WSP {
  float *h, *st, *a2, *Za, *Zb, *T0, *T1, *T2, *t3v, *t2m, *red, *sc;
  bf16 *q, *k, *v, *ql, *kl;
};

static void run_translayer(const float* nw, const float* nb, const float* qkvw,
                           const float* outw, const float* outb, const float* resw,
                           WSP& w, hipStream_t s)
{
  const long QKV_ELEMS = (long)BH * NPAD * DHD;     // per buffer, bf16
  const long QKV_U4 = QKV_ELEMS * 3 * 2 / 16;       // q,k,v contiguous

  k_ln_stats<<<ROWS, 256, 0, s>>>(w.h, w.st);
  k_zero<<<2048, 256, 0, s>>>((uint4*)w.q, QKV_U4);
  k_gemm_qkv<<<dim3((ROWS + 63) / 64, (3 * CDIM) / 64, 1), 256, 0, s>>>(
      w.h, w.st, nw, nb, qkvw, w.q, w.k, w.v);

  const int lmN = BH * ML * DHD;
  k_landmark<<<(lmN + 255) / 256, 256, 0, s>>>(w.q, w.ql);
  k_landmark<<<(lmN + 255) / 256, 256, 0, s>>>(w.k, w.kl);

  // attn2 = softmax(q_l @ k_l^T)
  k_gemm_nt64<<<dim3(4, 4, BH), 256, 0, s>>>(w.ql, w.kl, w.a2, ML,
                                             (long)ML * DHD, (long)ML * DHD, (long)ML * ML);
  k_softmax<<<BH * ML, 256, 0, s>>>(w.a2, ML);

  // Moore-Penrose pinv (6 iterations, fp32)
  k_pinv_prep<<<BH, 256, 0, s>>>(w.a2, w.red);
  k_pinv_scale<<<1, 64, 0, s>>>(w.red);
  const int nz = BH * ML * ML;
  k_tscale<<<(nz + 255) / 256, 256, 0, s>>>(w.a2, w.red, w.Za);
  float* Za = w.Za; float* Zb = w.Zb;
  const long sq = (long)ML * ML;
  for (int it = 0; it < 6; ++it) {
    k_gemm_nn<<<dim3(4, 4, BH), 256, 0, s>>>(w.a2, Za, w.T0, ML, ML, ML, sq, sq, sq, 1.f, 0.f);
    k_aib<<<(nz + 255) / 256, 256, 0, s>>>(w.T0, w.T1, 7.f);
    k_gemm_nn<<<dim3(4, 4, BH), 256, 0, s>>>(w.T0, w.T1, w.T2, ML, ML, ML, sq, sq, sq, -1.f, 15.f);
    k_gemm_nn<<<dim3(4, 4, BH), 256, 0, s>>>(w.T0, w.T2, w.T1, ML, ML, ML, sq, sq, sq, -1.f, 13.f);
    k_gemm_nn<<<dim3(4, 4, BH), 256, 0, s>>>(Za, w.T1, Zb, ML, ML, ML, sq, sq, sq, 0.25f, 0.f);
    float* tmp = Za; Za = Zb; Zb = tmp;
  }

  // attn3 = softmax(q_l @ k^T); t3v = attn3 @ v     (per-bh, small score buffer)
  for (int bh = 0; bh < BH; ++bh) {
    k_gemm_nt64<<<dim3(4, NPAD / 64, 1), 256, 0, s>>>(
        w.ql + (long)bh * ML * DHD, w.k + (long)bh * NPAD * DHD, w.sc, NPAD, 0, 0, 0);
    k_softmax<<<ML, 256, 0, s>>>(w.sc, NPAD);
    k_gemm_nn<<<dim3(4, 1, 1), 256, 0, s>>>(
        w.sc, w.v + (long)bh * NPAD * DHD, w.t3v + (long)bh * ML * DHD,
        ML, DHD, NPAD, 0, 0, 0, 1.f, 0.f);
  }

  // t2m = Z @ t3v  (batched)
  k_gemm_nn<<<dim3(4, 1, BH), 256, 0, s>>>(Za, w.t3v, w.t2m, ML, DHD, ML,
                                           sq, (long)ML * DHD, (long)ML * DHD, 1.f, 0.f);

  // attn1 = softmax(q @ k_l^T); out1 = attn1 @ t2m (overwrites q, per-bh)
  for (int bh = 0; bh < BH; ++bh) {
    k_gemm_nt64<<<dim3(NPAD / 64, 4, 1), 256, 0, s>>>(
        w.q + (long)bh * NPAD * DHD, w.kl + (long)bh * ML * DHD, w.sc, ML, 0, 0, 0);
    k_softmax<<<NPAD, 256, 0, s>>>(w.sc, ML);
    k_gemm_nn<<<dim3(NPAD / 64, 1, 1), 256, 0, s>>>(
        w.sc, w.t2m + (long)bh * ML * DHD, w.q + (long)bh * NPAD * DHD,
        NPAD, DHD, ML, 0, 0, 0, 1.f, 0.f);
  }

  // out1 += depthwise res conv of v
  const long rcN = (long)BH * NPAD * DHD;
  k_resconv<<<(int)((rcN + 255) / 256), 256, 0, s>>>(w.v, resw, w.q);

  // h += merge(out1) @ out_w^T + out_b
  k_gemm_out<<<dim3((ROWS + 63) / 64, CDIM / 64, 1), 256, 0, s>>>(w.q, outw, outb, w.h);
}

extern "C" void kernel_launch(void* const* d_in, const int* in_sizes, int n_in,
                              void* d_out, int out_size, void* d_ws, size_t ws_size,
                              hipStream_t stream)
{
  const float* x      = (const float*)d_in[0];
  const float* cls    = (const float*)d_in[1];
  const float* l1nw   = (const float*)d_in[2];
  const float* l1nb   = (const float*)d_in[3];
  const float* l1qkvw = (const float*)d_in[4];
  const float* l1outw = (const float*)d_in[5];
  const float* l1outb = (const float*)d_in[6];
  const float* l1resw = (const float*)d_in[7];
  const float* l2nw   = (const float*)d_in[8];
  const float* l2nb   = (const float*)d_in[9];
  const float* l2qkvw = (const float*)d_in[10];
  const float* l2outw = (const float*)d_in[11];
  const float* l2outb = (const float*)d_in[12];
  const float* l2resw = (const float*)d_in[13];
  const float* pw7    = (const float*)d_in[14];
  const float* pb7    = (const float*)d_in[15];
  const float* pw5    = (const float*)d_in[16];
  const float* pb5    = (const float*)d_in[17];
  const float* pw3    = (const float*)d_in[18];
  const float* pb3    = (const float*)d_in[19];
  const float* fnw    = (const float*)d_in[20];
  const float* fnb    = (const float*)d_in[21];
  (void)in_sizes; (void)n_in; (void)out_size; (void)ws_size;

  float* W = (float*)d_ws;
  size_t o = 0;
  auto alloc = [&](size_t n) { float* p = W + o; o += n; return p; };
  WSP w;
  w.h   = alloc((size_t)ROWS * CDIM);            // 33.6 MB
  w.st  = alloc(32776);                          // LN stats (mu,rstd)
  float* qkv_region = alloc((size_t)3 * BH * NPAD * DHD / 2);  // 51.9 MB as bf16
  w.q   = (bf16*)qkv_region;
  w.k   = w.q + (size_t)BH * NPAD * DHD;
  w.v   = w.k + (size_t)BH * NPAD * DHD;
  float* lm_region = alloc((size_t)2 * BH * ML * DHD / 2);     // 1 MB as bf16
  w.ql  = (bf16*)lm_region;
  w.kl  = w.ql + (size_t)BH * ML * DHD;
  w.a2  = alloc((size_t)BH * ML * ML);           // 4.2 MB x6
  w.Za  = alloc((size_t)BH * ML * ML);
  w.Zb  = alloc((size_t)BH * ML * ML);
  w.T0  = alloc((size_t)BH * ML * ML);
  w.T1  = alloc((size_t)BH * ML * ML);
  w.T2  = alloc((size_t)BH * ML * ML);
  w.t3v = alloc((size_t)BH * ML * DHD);
  w.t2m = alloc((size_t)BH * ML * DHD);
  w.red = alloc(64);
  w.sc  = alloc((size_t)NPAD * ML);              // 8.65 MB (one bh)
  // total ~121 MB

  const long nh = (long)ROWS * CDIM;
  k_build_h<<<(int)((nh + 255) / 256), 256, 0, stream>>>(x, cls, w.h);

  run_translayer(l1nw, l1nb, l1qkvw, l1outw, l1outb, l1resw, w, stream);

  // PPEG (feat aliases dead q/k region: 33.9 MB fp32 <= 34.6 MB)
  float* feat = (float*)w.q;
  const long fe = (long)BB * CDIM * HW2;
  k_ppeg_build<<<(int)((fe + 255) / 256), 256, 0, stream>>>(w.h, feat);
  k_ppeg_conv<<<(int)((fe + 255) / 256), 256, 0, stream>>>(feat, pw7, pb7, pw5, pb5, pw3, pb3, w.h);

  run_translayer(l2nw, l2nb, l2qkvw, l2outw, l2outb, l2resw, w, stream);

  k_final_ln<<<BB, 256, 0, stream>>>(w.h, fnw, fnb, (float*)d_out);
}

// Round 4
// 2304.730 us; speedup vs baseline: 9.8394x; 9.8394x over previous
//
#include <hip/hip_runtime.h>
#include <hip/hip_bf16.h>

using bf16 = __hip_bfloat16;
typedef unsigned short u16;
typedef short bf16x8 __attribute__((ext_vector_type(8)));
typedef float f32x4 __attribute__((ext_vector_type(4)));

constexpr int BB    = 2;
constexpr int NSEQ  = 8193;
constexpr int CDIM  = 512;
constexpr int NH    = 8;
constexpr int DHD   = 64;
constexpr int ML    = 256;
constexpr int LF    = 33;
constexpr int NPAD  = 8448;
constexpr int PADL  = 255;
constexpr int ROWS  = BB * NSEQ;     // 16386
constexpr int BH    = BB * NH;       // 16
constexpr int RKS   = 33;
constexpr int HG    = 91;
constexpr int HW2   = HG * HG;       // 8281
constexpr int NPATCH = 8192;
constexpr long SQ   = (long)ML * ML; // 65536 per bh

__device__ __forceinline__ float b2f(u16 u) {
  union { unsigned int i; float f; } x; x.i = (unsigned int)u << 16; return x.f;
}
__device__ __forceinline__ short f2b(float f) {
  __hip_bfloat16 h = __float2bfloat16(f);
  return *reinterpret_cast<short*>(&h);
}
__device__ __forceinline__ f32x4 mfma16(bf16x8 a, bf16x8 b, f32x4 c) {
  return __builtin_amdgcn_mfma_f32_16x16x32_bf16(a, b, c, 0, 0, 0);
}

// ---------------- small kernels ----------------

__global__ __launch_bounds__(256) void k_zero(uint4* __restrict__ p, long n) {
  long i = (long)blockIdx.x * 256 + threadIdx.x;
  const long st = (long)gridDim.x * 256;
  for (; i < n; i += st) p[i] = make_uint4(0u, 0u, 0u, 0u);
}

__global__ __launch_bounds__(256) void k_build_h(
    const float* __restrict__ x, const float* __restrict__ cls, float* __restrict__ h)
{
  long idx = (long)blockIdx.x * 256 + threadIdx.x;
  if (idx >= (long)ROWS * CDIM) return;
  int c = idx & 511;
  long r = idx >> 9;
  int b = (int)(r / NSEQ), i = (int)(r % NSEQ);
  h[idx] = (i == 0) ? cls[c] : x[((long)b * (NSEQ - 1) + (i - 1)) * CDIM + c];
}

__global__ __launch_bounds__(256) void k_ln_stats(
    const float* __restrict__ X, float* __restrict__ stats)
{
  __shared__ float red[4];
  const long row = blockIdx.x;
  const float* x = X + row * CDIM;
  const int t = threadIdx.x;
  float a0 = x[t], a1 = x[t + 256];
  float s = a0 + a1;
  for (int o = 32; o; o >>= 1) s += __shfl_down(s, o);
  if ((t & 63) == 0) red[t >> 6] = s;
  __syncthreads();
  const float mu = (red[0] + red[1] + red[2] + red[3]) * (1.0f / CDIM);
  __syncthreads();
  float d0 = a0 - mu, d1 = a1 - mu;
  float q = d0 * d0 + d1 * d1;
  for (int o = 32; o; o >>= 1) q += __shfl_down(q, o);
  if ((t & 63) == 0) red[t >> 6] = q;
  __syncthreads();
  if (t == 0) {
    const float var = (red[0] + red[1] + red[2] + red[3]) * (1.0f / CDIM);
    stats[row * 2]     = mu;
    stats[row * 2 + 1] = rsqrtf(var + 1e-5f);
  }
}

__global__ __launch_bounds__(256) void k_final_ln(
    const float* __restrict__ H, const float* __restrict__ g,
    const float* __restrict__ bb, float* __restrict__ out)
{
  __shared__ float red[4];
  const float* x = H + (long)blockIdx.x * NSEQ * CDIM;
  const int t = threadIdx.x;
  float a0 = x[t], a1 = x[t + 256];
  float s = a0 + a1;
  for (int o = 32; o; o >>= 1) s += __shfl_down(s, o);
  if ((t & 63) == 0) red[t >> 6] = s;
  __syncthreads();
  const float mu = (red[0] + red[1] + red[2] + red[3]) * (1.0f / CDIM);
  __syncthreads();
  float d0 = a0 - mu, d1 = a1 - mu;
  float q = d0 * d0 + d1 * d1;
  for (int o = 32; o; o >>= 1) q += __shfl_down(q, o);
  if ((t & 63) == 0) red[t >> 6] = q;
  __syncthreads();
  const float var = (red[0] + red[1] + red[2] + red[3]) * (1.0f / CDIM);
  const float rs = rsqrtf(var + 1e-5f);
  out[blockIdx.x * CDIM + t]       = d0 * rs * g[t]       + bb[t];
  out[blockIdx.x * CDIM + t + 256] = d1 * rs * g[t + 256] + bb[t + 256];
}

__global__ __launch_bounds__(256) void k_landmark(
    const bf16* __restrict__ src, bf16* __restrict__ dst)
{
  int idx = blockIdx.x * 256 + threadIdx.x;
  if (idx >= BH * ML * DHD) return;
  int d = idx & 63, j = (idx >> 6) & 255, bh = idx >> 14;
  const u16* p = (const u16*)src + ((long)bh * NPAD + (long)j * LF) * DHD + d;
  float s = 0.f;
#pragma unroll
  for (int t = 0; t < LF; ++t) s += b2f(p[t * DHD]);
  ((u16*)dst)[idx] = (u16)f2b(s * (1.0f / LF));
}

__global__ __launch_bounds__(256) void k_softmax(float* __restrict__ S, int W)
{
  __shared__ float buf[NPAD];
  __shared__ float red[4];
  float* p = S + (long)blockIdx.x * W;
  const int t = threadIdx.x;
  float mx = -3.4e38f;
  for (int j = t; j < W; j += 256) { float v = p[j]; buf[j] = v; mx = fmaxf(mx, v); }
  for (int o = 32; o; o >>= 1) mx = fmaxf(mx, __shfl_down(mx, o));
  if ((t & 63) == 0) red[t >> 6] = mx;
  __syncthreads();
  mx = fmaxf(fmaxf(red[0], red[1]), fmaxf(red[2], red[3]));
  __syncthreads();
  float sum = 0.f;
  for (int j = t; j < W; j += 256) { float e = __expf(buf[j] - mx); buf[j] = e; sum += e; }
  for (int o = 32; o; o >>= 1) sum += __shfl_down(sum, o);
  if ((t & 63) == 0) red[t >> 6] = sum;
  __syncthreads();
  const float inv = 1.0f / (red[0] + red[1] + red[2] + red[3]);
  for (int j = t; j < W; j += 256) p[j] = buf[j] * inv;
}

__global__ __launch_bounds__(256) void k_pinv_prep(
    const float* __restrict__ A, float* __restrict__ red)
{
  __shared__ float r1[4], r2[4];
  const float* Ab = A + (long)blockIdx.x * SQ;
  const int t = threadIdx.x;
  float rs = 0.f, cs = 0.f;
  for (int j = 0; j < ML; ++j) { rs += fabsf(Ab[t * ML + j]); cs += fabsf(Ab[j * ML + t]); }
  for (int o = 32; o; o >>= 1) { rs = fmaxf(rs, __shfl_down(rs, o)); cs = fmaxf(cs, __shfl_down(cs, o)); }
  if ((t & 63) == 0) { r1[t >> 6] = rs; r2[t >> 6] = cs; }
  __syncthreads();
  if (t == 0) {
    red[blockIdx.x]      = fmaxf(fmaxf(r1[0], r1[1]), fmaxf(r1[2], r1[3]));
    red[16 + blockIdx.x] = fmaxf(fmaxf(r2[0], r2[1]), fmaxf(r2[2], r2[3]));
  }
}

__global__ void k_pinv_scale(float* __restrict__ red)
{
  if (threadIdx.x == 0 && blockIdx.x == 0) {
    float cmax = red[0], rmax = red[16];
    for (int i = 1; i < 16; ++i) { cmax = fmaxf(cmax, red[i]); rmax = fmaxf(rmax, red[16 + i]); }
    red[32] = 1.0f / (cmax * rmax);
  }
}

// Ab = bf16(attn2); Zt = bf16(attn2*s) [= z0^T storage]; Z = bf16(attn2^T*s) [= z0]
__global__ __launch_bounds__(256) void k_tscale2(
    const float* __restrict__ A, const float* __restrict__ red,
    short* __restrict__ Ab, short* __restrict__ Z, short* __restrict__ Zt)
{
  long idx = (long)blockIdx.x * 256 + threadIdx.x;
  if (idx >= (long)BH * SQ) return;
  int c = idx & 255, r = (int)((idx >> 8) & 255);
  long bh = idx >> 16;
  float a = A[idx];
  float s = red[32];
  Ab[idx] = f2b(a);
  Zt[idx] = f2b(a * s);
  Z[(bh << 16) + ((long)c << 8) + r] = f2b(a * s);
}

__global__ __launch_bounds__(256) void k_aib(
    const float* __restrict__ X, float* __restrict__ Y, float a)
{
  long idx = (long)blockIdx.x * 256 + threadIdx.x;
  if (idx >= (long)BH * SQ) return;
  int j = idx & 255, i = (int)((idx >> 8) & 255);
  float v = -X[idx];
  if (i == j) v += a;
  Y[idx] = v;
}

__global__ __launch_bounds__(256) void k_resconv(
    const bf16* __restrict__ v, const float* __restrict__ w, bf16* __restrict__ out)
{
  long idx = (long)blockIdx.x * 256 + threadIdx.x;
  if (idx >= (long)BH * NPAD * DHD) return;
  int d = idx & 63;
  long r = idx >> 6;
  int i = (int)(r % NPAD);
  int bh = (int)(r / NPAD);
  const float* wp = w + (bh & 7) * RKS;
  const u16* vb = (const u16*)v + (long)bh * NPAD * DHD + d;
  float s = 0.f;
#pragma unroll
  for (int t = 0; t < RKS; ++t) {
    int src = i + t - 16;
    if (src >= 0 && src < NPAD) s += b2f(vb[(long)src * DHD]) * wp[t];
  }
  u16* ob = (u16*)out;
  ob[idx] = (u16)f2b(b2f(ob[idx]) + s);
}

// vT[bh][d][row] = v[bh][row][d]
__global__ __launch_bounds__(256) void k_vT(const bf16* __restrict__ V, bf16* __restrict__ VT)
{
  __shared__ u16 tl[64][72];
  const int r0 = blockIdx.x * 64, bh = blockIdx.y;
  const u16* vp = (const u16*)V + ((long)bh * NPAD + r0) * DHD;
  const int t = threadIdx.x;
  {
    int r = t >> 2, c0 = (t & 3) * 16;
    bf16x8 u0 = *(const bf16x8*)(vp + (long)r * DHD + c0);
    bf16x8 u1 = *(const bf16x8*)(vp + (long)r * DHD + c0 + 8);
#pragma unroll
    for (int i = 0; i < 8; ++i) { tl[r][c0 + i] = (u16)u0[i]; tl[r][c0 + 8 + i] = (u16)u1[i]; }
  }
  __syncthreads();
  {
    int d = t >> 2, k0 = (t & 3) * 16;
    bf16x8 u0, u1;
#pragma unroll
    for (int i = 0; i < 8; ++i) { u0[i] = (short)tl[k0 + i][d]; u1[i] = (short)tl[k0 + 8 + i][d]; }
    u16* dst = (u16*)VT + ((long)bh * DHD + d) * NPAD + r0 + k0;
    *(bf16x8*)dst = u0;
    *(bf16x8*)(dst + 8) = u1;
  }
}

__global__ __launch_bounds__(256) void k_t2mT(const float* __restrict__ T2M, short* __restrict__ T2MT)
{
  int idx = blockIdx.x * 256 + threadIdx.x;
  if (idx >= BH * DHD * ML) return;
  int k = idx & 255, d = (idx >> 8) & 63, bh = idx >> 14;
  T2MT[idx] = f2b(T2M[((long)bh * ML + k) * DHD + d]);
}

// ---------------- PPEG ----------------

__global__ __launch_bounds__(256) void k_ppeg_build(
    const float* __restrict__ h, float* __restrict__ feat)
{
  long idx = (long)blockIdx.x * 256 + threadIdx.x;
  if (idx >= (long)BB * CDIM * HW2) return;
  int pos = (int)(idx % HW2);
  long t = idx / HW2;
  int c = (int)(t % CDIM), b = (int)(t / CDIM);
  int src = pos < NPATCH ? pos : pos - NPATCH;
  feat[idx] = h[((long)b * NSEQ + 1 + src) * CDIM + c];
}

__device__ __forceinline__ float convk(const float* __restrict__ f, int y, int x,
                                       const float* __restrict__ w, int k)
{
  int r = k >> 1;
  float s = 0.f;
  for (int dy = 0; dy < k; ++dy) {
    int yy = y + dy - r;
    if (yy < 0 || yy >= HG) continue;
    for (int dx = 0; dx < k; ++dx) {
      int xx = x + dx - r;
      if (xx < 0 || xx >= HG) continue;
      s += f[yy * HG + xx] * w[dy * k + dx];
    }
  }
  return s;
}

__global__ __launch_bounds__(256) void k_ppeg_conv(
    const float* __restrict__ feat,
    const float* __restrict__ w7, const float* __restrict__ b7,
    const float* __restrict__ w5, const float* __restrict__ b5,
    const float* __restrict__ w3, const float* __restrict__ b3,
    float* __restrict__ h)
{
  long idx = (long)blockIdx.x * 256 + threadIdx.x;
  if (idx >= (long)BB * CDIM * HW2) return;
  int pos = (int)(idx % HW2);
  if (pos >= NPATCH) return;
  long t = idx / HW2;
  int c = (int)(t % CDIM), b = (int)(t / CDIM);
  const float* f = feat + (idx - pos);
  int y = pos / HG, x = pos % HG;
  float s = f[pos];
  s += convk(f, y, x, w7 + c * 49, 7) + b7[c];
  s += convk(f, y, x, w5 + c * 25, 5) + b5[c];
  s += convk(f, y, x, w3 + c * 9, 3) + b3[c];
  h[((long)b * NSEQ + 1 + pos) * CDIM + c] = s;
}

// ---------------- fp32 GEMM (pinv tail + t2m) ----------------

__global__ __launch_bounds__(256) void k_gemm_nn(
    const float* __restrict__ A, const float* __restrict__ Bm, float* __restrict__ Cm,
    int M, int N, int K, long sA, long sB, long sC, float alpha, float diag)
{
  __shared__ float As[64][17], Bs[16][68];
  const float* Ab = A + (long)blockIdx.z * sA;
  const float* Bb = Bm + (long)blockIdx.z * sB;
  float* Cb = Cm + (long)blockIdx.z * sC;
  const int m0 = blockIdx.x << 6, n0 = blockIdx.y << 6;
  const int t = threadIdx.x, ty = t >> 4, tx = t & 15;
  const int lr = t >> 2, lk = (t & 3) << 2;
  const int bk = t >> 4, bn = (t & 15) << 2;
  float acc[4][4] = {};
  for (int k0 = 0; k0 < K; k0 += 16) {
    float4 av = make_float4(0.f, 0.f, 0.f, 0.f), bv = make_float4(0.f, 0.f, 0.f, 0.f);
    if (m0 + lr < M) av = *(const float4*)(Ab + (long)(m0 + lr) * K + k0 + lk);
    if (n0 + bn < N) bv = *(const float4*)(Bb + (long)(k0 + bk) * N + n0 + bn);
    As[lr][lk] = av.x; As[lr][lk + 1] = av.y; As[lr][lk + 2] = av.z; As[lr][lk + 3] = av.w;
    Bs[bk][bn] = bv.x; Bs[bk][bn + 1] = bv.y; Bs[bk][bn + 2] = bv.z; Bs[bk][bn + 3] = bv.w;
    __syncthreads();
#pragma unroll
    for (int kk = 0; kk < 16; ++kk) {
      float a[4], b[4];
#pragma unroll
      for (int i = 0; i < 4; ++i) a[i] = As[ty * 4 + i][kk];
#pragma unroll
      for (int j = 0; j < 4; ++j) b[j] = Bs[kk][tx * 4 + j];
#pragma unroll
      for (int i = 0; i < 4; ++i)
#pragma unroll
        for (int j = 0; j < 4; ++j) acc[i][j] += a[i] * b[j];
    }
    __syncthreads();
  }
#pragma unroll
  for (int i = 0; i < 4; ++i) {
    int r = m0 + ty * 4 + i;
    if (r >= M) continue;
#pragma unroll
    for (int j = 0; j < 4; ++j) {
      int n = n0 + tx * 4 + j;
      if (n >= N) continue;
      float v = alpha * acc[i][j];
      if (r == n) v += diag;
      Cb[(long)r * N + n] = v;
    }
  }
}

// attn2 scores: C fp32 = A_bf16 @ B_bf16^T, K=64 (batched)
__global__ __launch_bounds__(256) void k_gemm_nt64(
    const bf16* __restrict__ A, const bf16* __restrict__ Bm, float* __restrict__ Cm,
    int N, long sA, long sB, long sC)
{
  __shared__ float As[64][65], Bs[64][65];
  const bf16* Ab = A + (long)blockIdx.z * sA;
  const bf16* Bb = Bm + (long)blockIdx.z * sB;
  float* Cb = Cm + (long)blockIdx.z * sC;
  const int m0 = blockIdx.x << 6, n0 = blockIdx.y << 6;
  const int t = threadIdx.x;
  const int row = t >> 2, c0 = (t & 3) << 4;
  {
    const u16* ap = (const u16*)Ab + (long)(m0 + row) * DHD + c0;
    const u16* bp = (const u16*)Bb + (long)(n0 + row) * DHD + c0;
#pragma unroll
    for (int i = 0; i < 16; ++i) { As[row][c0 + i] = b2f(ap[i]); Bs[row][c0 + i] = b2f(bp[i]); }
  }
  __syncthreads();
  const int ty = t >> 4, tx = t & 15;
  float acc[4][4] = {};
#pragma unroll 16
  for (int kk = 0; kk < 64; ++kk) {
    float a[4], b[4];
#pragma unroll
    for (int i = 0; i < 4; ++i) a[i] = As[ty * 4 + i][kk];
#pragma unroll
    for (int j = 0; j < 4; ++j) b[j] = Bs[tx * 4 + j][kk];
#pragma unroll
    for (int i = 0; i < 4; ++i)
#pragma unroll
      for (int j = 0; j < 4; ++j) acc[i][j] += a[i] * b[j];
  }
#pragma unroll
  for (int i = 0; i < 4; ++i)
#pragma unroll
    for (int j = 0; j < 4; ++j)
      Cb[(long)(m0 + ty * 4 + i) * N + n0 + tx * 4 + j] = acc[i][j];
}

// ---------------- MFMA projection GEMMs ----------------

// qkv = LN(h) @ qkv_w^T  -> scatter bf16 q/k/v (q*0.125). 128x128 tile, K=512.
__global__ __launch_bounds__(256) void k_mfma_qkv(
    const float* __restrict__ H, const float* __restrict__ st,
    const float* __restrict__ ga, const float* __restrict__ be,
    const float* __restrict__ Wm,
    bf16* __restrict__ Q, bf16* __restrict__ Kp, bf16* __restrict__ V)
{
  __shared__ __align__(16) short As[128 * 32];
  __shared__ __align__(16) short Bs[128 * 32];
  const int m0 = blockIdx.x * 128, n0 = blockIdx.y * 128;
  const int t = threadIdx.x, w = t >> 6, l = t & 63;
  const int srow = t >> 1, skh = (t & 1) * 16;   // staging: row 0..127, k 0/16
  const int aR = m0 + srow;
  float mu = 0.f, rs = 0.f;
  if (aR < ROWS) { mu = st[aR * 2]; rs = st[aR * 2 + 1]; }
  const int wR = n0 + srow;
  const int g0 = skh >> 3;                       // k-block 0 or 2
  const int sw0 = ((g0 ^ (srow & 3)) << 3), sw1 = (((g0 + 1) ^ (srow & 3)) << 3);
  f32x4 acc[4][4] = {};
  for (int kt = 0; kt < 16; ++kt) {
    const int kbase = kt * 32 + skh;
    {
      bf16x8 v0, v1;
      if (aR < ROWS) {
        const float4* hp = (const float4*)(H + (long)aR * CDIM + kbase);
        const float4* gp = (const float4*)(ga + kbase);
        const float4* bp = (const float4*)(be + kbase);
#pragma unroll
        for (int q = 0; q < 2; ++q) {
          float4 hv = hp[q], gv = gp[q], bv = bp[q];
          v0[q * 4 + 0] = f2b((hv.x - mu) * rs * gv.x + bv.x);
          v0[q * 4 + 1] = f2b((hv.y - mu) * rs * gv.y + bv.y);
          v0[q * 4 + 2] = f2b((hv.z - mu) * rs * gv.z + bv.z);
          v0[q * 4 + 3] = f2b((hv.w - mu) * rs * gv.w + bv.w);
        }
#pragma unroll
        for (int q = 2; q < 4; ++q) {
          float4 hv = hp[q], gv = gp[q], bv = bp[q];
          v1[(q - 2) * 4 + 0] = f2b((hv.x - mu) * rs * gv.x + bv.x);
          v1[(q - 2) * 4 + 1] = f2b((hv.y - mu) * rs * gv.y + bv.y);
          v1[(q - 2) * 4 + 2] = f2b((hv.z - mu) * rs * gv.z + bv.z);
          v1[(q - 2) * 4 + 3] = f2b((hv.w - mu) * rs * gv.w + bv.w);
        }
      } else {
#pragma unroll
        for (int i = 0; i < 8; ++i) { v0[i] = 0; v1[i] = 0; }
      }
      *(bf16x8*)(As + srow * 32 + sw0) = v0;
      *(bf16x8*)(As + srow * 32 + sw1) = v1;
    }
    {
      const float4* wp = (const float4*)(Wm + (long)wR * CDIM + kbase);
      bf16x8 v0, v1;
#pragma unroll
      for (int q = 0; q < 2; ++q) {
        float4 wv = wp[q];
        v0[q * 4 + 0] = f2b(wv.x); v0[q * 4 + 1] = f2b(wv.y);
        v0[q * 4 + 2] = f2b(wv.z); v0[q * 4 + 3] = f2b(wv.w);
      }
#pragma unroll
      for (int q = 2; q < 4; ++q) {
        float4 wv = wp[q];
        v1[(q - 2) * 4 + 0] = f2b(wv.x); v1[(q - 2) * 4 + 1] = f2b(wv.y);
        v1[(q - 2) * 4 + 2] = f2b(wv.z); v1[(q - 2) * 4 + 3] = f2b(wv.w);
      }
      *(bf16x8*)(Bs + srow * 32 + sw0) = v0;
      *(bf16x8*)(Bs + srow * 32 + sw1) = v1;
    }
    __syncthreads();
    const int ar0 = (w >> 1) * 64, bc0 = (w & 1) * 64;
    const int kg = l >> 4;
    bf16x8 a[4], b[4];
#pragma unroll
    for (int am = 0; am < 4; ++am) {
      int row = ar0 + am * 16 + (l & 15);
      a[am] = *(const bf16x8*)(As + row * 32 + ((kg ^ (row & 3)) << 3));
    }
#pragma unroll
    for (int bn = 0; bn < 4; ++bn) {
      int row = bc0 + bn * 16 + (l & 15);
      b[bn] = *(const bf16x8*)(Bs + row * 32 + ((kg ^ (row & 3)) << 3));
    }
#pragma unroll
    for (int am = 0; am < 4; ++am)
#pragma unroll
      for (int bn = 0; bn < 4; ++bn) acc[am][bn] = mfma16(a[am], b[bn], acc[am][bn]);
    __syncthreads();
  }
  // epilogue scatter
  const int ar0 = (w >> 1) * 64, bc0 = (w & 1) * 64;
#pragma unroll
  for (int am = 0; am < 4; ++am) {
#pragma unroll
    for (int rr = 0; rr < 4; ++rr) {
      int R = m0 + ar0 + am * 16 + ((l >> 4) << 2) + rr;
      if (R >= ROWS) continue;
      int b = R / NSEQ, ii = R - b * NSEQ;
#pragma unroll
      for (int bn = 0; bn < 4; ++bn) {
        int n = n0 + bc0 + bn * 16 + (l & 15);
        int which = n >> 9, rem = n & 511, hd = rem >> 6, d = rem & 63;
        float val = acc[am][bn][rr];
        if (which == 0) val *= 0.125f;
        u16* dst = (u16*)(which == 0 ? Q : (which == 1 ? Kp : V));
        dst[(((long)(b * NH + hd)) * NPAD + PADL + ii) * DHD + d] = (u16)f2b(val);
      }
    }
  }
}

// h += merge(out1) @ out_w^T + out_b. 128x128 tile, K=512.
__global__ __launch_bounds__(256) void k_mfma_out(
    const bf16* __restrict__ O1, const float* __restrict__ Wm,
    const float* __restrict__ bias, float* __restrict__ Hh)
{
  __shared__ __align__(16) short As[128 * 32];
  __shared__ __align__(16) short Bs[128 * 32];
  const int m0 = blockIdx.x * 128, n0 = blockIdx.y * 128;
  const int t = threadIdx.x, w = t >> 6, l = t & 63;
  const int srow = t >> 1, skh = (t & 1) * 16;
  const int aR = m0 + srow;
  int bb = 0, ii = 0;
  if (aR < ROWS) { bb = aR / NSEQ; ii = aR - bb * NSEQ; }
  const int wR = n0 + srow;
  const int g0 = skh >> 3;
  const int sw0 = ((g0 ^ (srow & 3)) << 3), sw1 = (((g0 + 1) ^ (srow & 3)) << 3);
  const u16* o1 = (const u16*)O1;
  f32x4 acc[4][4] = {};
  for (int kt = 0; kt < 16; ++kt) {
    const int kbase = kt * 32 + skh;
    {
      bf16x8 v0, v1;
      if (aR < ROWS) {
        int hd = kbase >> 6, d0 = kbase & 63;
        const u16* src = o1 + (((long)(bb * NH + hd)) * NPAD + PADL + ii) * DHD + d0;
        v0 = *(const bf16x8*)src;
        v1 = *(const bf16x8*)(src + 8);
      } else {
#pragma unroll
        for (int i = 0; i < 8; ++i) { v0[i] = 0; v1[i] = 0; }
      }
      *(bf16x8*)(As + srow * 32 + sw0) = v0;
      *(bf16x8*)(As + srow * 32 + sw1) = v1;
    }
    {
      const float4* wp = (const float4*)(Wm + (long)wR * CDIM + kbase);
      bf16x8 v0, v1;
#pragma unroll
      for (int q = 0; q < 2; ++q) {
        float4 wv = wp[q];
        v0[q * 4 + 0] = f2b(wv.x); v0[q * 4 + 1] = f2b(wv.y);
        v0[q * 4 + 2] = f2b(wv.z); v0[q * 4 + 3] = f2b(wv.w);
      }
#pragma unroll
      for (int q = 2; q < 4; ++q) {
        float4 wv = wp[q];
        v1[(q - 2) * 4 + 0] = f2b(wv.x); v1[(q - 2) * 4 + 1] = f2b(wv.y);
        v1[(q - 2) * 4 + 2] = f2b(wv.z); v1[(q - 2) * 4 + 3] = f2b(wv.w);
      }
      *(bf16x8*)(Bs + srow * 32 + sw0) = v0;
      *(bf16x8*)(Bs + srow * 32 + sw1) = v1;
    }
    __syncthreads();
    const int ar0 = (w >> 1) * 64, bc0 = (w & 1) * 64;
    const int kg = l >> 4;
    bf16x8 a[4], b[4];
#pragma unroll
    for (int am = 0; am < 4; ++am) {
      int row = ar0 + am * 16 + (l & 15);
      a[am] = *(const bf16x8*)(As + row * 32 + ((kg ^ (row & 3)) << 3));
    }
#pragma unroll
    for (int bn = 0; bn < 4; ++bn) {
      int row = bc0 + bn * 16 + (l & 15);
      b[bn] = *(const bf16x8*)(Bs + row * 32 + ((kg ^ (row & 3)) << 3));
    }
#pragma unroll
    for (int am = 0; am < 4; ++am)
#pragma unroll
      for (int bn = 0; bn < 4; ++bn) acc[am][bn] = mfma16(a[am], b[bn], acc[am][bn]);
    __syncthreads();
  }
  const int ar0 = (w >> 1) * 64, bc0 = (w & 1) * 64;
#pragma unroll
  for (int am = 0; am < 4; ++am) {
#pragma unroll
    for (int rr = 0; rr < 4; ++rr) {
      int R = m0 + ar0 + am * 16 + ((l >> 4) << 2) + rr;
      if (R >= ROWS) continue;
      float* hrow = Hh + (long)R * CDIM;
#pragma unroll
      for (int bn = 0; bn < 4; ++bn) {
        int n = n0 + bc0 + bn * 16 + (l & 15);
        hrow[n] += acc[am][bn][rr] + bias[n];
      }
    }
  }
}

// ---------------- batched pinv MFMA GEMM (bf16) ----------------
// C = A @ Bt^T-storage; epilogue: outN[r][c]=aN*x+dN*I, outT[c][r]=aT*x+dT*I, outF fp32
__global__ __launch_bounds__(256) void k_pinv_g(
    const short* __restrict__ A, const short* __restrict__ Bt,
    short* __restrict__ outN, float aN, float dN,
    short* __restrict__ outT, float aT, float dT,
    float* __restrict__ outF, float aF)
{
  const int bh = blockIdx.z;
  const long off = (long)bh * SQ;
  const short* Ab = A + off;
  const short* Btb = Bt + off;
  const int t = threadIdx.x, w = t >> 6, l = t & 63;
  const int r0 = blockIdx.x * 64 + (w >> 1) * 32;
  const int c0 = blockIdx.y * 64 + (w & 1) * 32;
  f32x4 acc[2][2] = {};
#pragma unroll
  for (int ks = 0; ks < 8; ++ks) {
    bf16x8 a[2], b[2];
#pragma unroll
    for (int am = 0; am < 2; ++am)
      a[am] = *(const bf16x8*)(Ab + (long)(r0 + am * 16 + (l & 15)) * ML + ks * 32 + (l >> 4) * 8);
#pragma unroll
    for (int bn = 0; bn < 2; ++bn)
      b[bn] = *(const bf16x8*)(Btb + (long)(c0 + bn * 16 + (l & 15)) * ML + ks * 32 + (l >> 4) * 8);
#pragma unroll
    for (int am = 0; am < 2; ++am)
#pragma unroll
      for (int bn = 0; bn < 2; ++bn) acc[am][bn] = mfma16(a[am], b[bn], acc[am][bn]);
  }
#pragma unroll
  for (int am = 0; am < 2; ++am)
#pragma unroll
    for (int bn = 0; bn < 2; ++bn)
#pragma unroll
      for (int rr = 0; rr < 4; ++rr) {
        int R = r0 + am * 16 + ((l >> 4) << 2) + rr;
        int C = c0 + bn * 16 + (l & 15);
        float x = acc[am][bn][rr];
        float dg = (R == C) ? 1.f : 0.f;
        if (outN) outN[off + (long)R * ML + C] = f2b(aN * x + dN * dg);
        if (outT) outT[off + (long)C * ML + R] = f2b(aT * x + dT * dg);
        if (outF) outF[off + (long)R * ML + C] = aF * x;
      }
}

// ---------------- fused attentions ----------------

__device__ __forceinline__ int pswz(int row, int col) {
  return row * 256 + ((((col >> 3) ^ (row & 7)) << 3) | (col & 7));
}

// attn3: t3v[bh] = softmax(ql @ k^T) @ v   (two-pass, no score buffer)
__global__ __launch_bounds__(256) void k_attn3(
    const bf16* __restrict__ QL, const bf16* __restrict__ Kb,
    const bf16* __restrict__ VT, float* __restrict__ T3V)
{
  __shared__ __align__(16) u16 Pl[64 * 256];
  __shared__ float psum[4][64];
  __shared__ float lsum[64];
  const int bh = blockIdx.y;
  const int m0 = blockIdx.x * 64;
  const int t = threadIdx.x, w = t >> 6, l = t & 63;
  const u16* qlp = (const u16*)QL + (long)bh * ML * DHD;
  const u16* kp  = (const u16*)Kb + (long)bh * NPAD * DHD;
  const u16* vtp = (const u16*)VT + (long)bh * DHD * NPAD;

  bf16x8 a[4][2];
#pragma unroll
  for (int am = 0; am < 4; ++am)
#pragma unroll
    for (int ks = 0; ks < 2; ++ks)
      a[am][ks] = *(const bf16x8*)(qlp + (long)(m0 + am * 16 + (l & 15)) * DHD + ks * 32 + (l >> 4) * 8);

  float p_[16];
#pragma unroll
  for (int i = 0; i < 16; ++i) p_[i] = 0.f;

  for (int kt = 0; kt < NPAD / 256; ++kt) {
    const int kv0 = kt * 256 + w * 64;
    f32x4 s[4][4] = {};
#pragma unroll
    for (int ks = 0; ks < 2; ++ks)
#pragma unroll
      for (int bc = 0; bc < 4; ++bc) {
        bf16x8 bbv = *(const bf16x8*)(kp + (long)(kv0 + bc * 16 + (l & 15)) * DHD + ks * 32 + (l >> 4) * 8);
#pragma unroll
        for (int am = 0; am < 4; ++am) s[am][bc] = mfma16(a[am][ks], bbv, s[am][bc]);
      }
#pragma unroll
    for (int am = 0; am < 4; ++am)
#pragma unroll
      for (int rr = 0; rr < 4; ++rr)
        p_[am * 4 + rr] += __expf(s[am][0][rr]) + __expf(s[am][1][rr])
                         + __expf(s[am][2][rr]) + __expf(s[am][3][rr]);
  }
#pragma unroll
  for (int i = 0; i < 16; ++i) {
    float v = p_[i];
    v += __shfl_xor(v, 1); v += __shfl_xor(v, 2); v += __shfl_xor(v, 4); v += __shfl_xor(v, 8);
    p_[i] = v;
  }
  if ((l & 15) == 0) {
#pragma unroll
    for (int am = 0; am < 4; ++am)
#pragma unroll
      for (int rr = 0; rr < 4; ++rr)
        psum[w][am * 16 + ((l >> 4) << 2) + rr] = p_[am * 4 + rr];
  }
  __syncthreads();
  if (t < 64) lsum[t] = psum[0][t] + psum[1][t] + psum[2][t] + psum[3][t];
  __syncthreads();

  f32x4 o[4][4] = {};
  for (int kt = 0; kt < NPAD / 256; ++kt) {
    const int kv0 = kt * 256 + w * 64;
    f32x4 s[4][4] = {};
#pragma unroll
    for (int ks = 0; ks < 2; ++ks)
#pragma unroll
      for (int bc = 0; bc < 4; ++bc) {
        bf16x8 bbv = *(const bf16x8*)(kp + (long)(kv0 + bc * 16 + (l & 15)) * DHD + ks * 32 + (l >> 4) * 8);
#pragma unroll
        for (int am = 0; am < 4; ++am) s[am][bc] = mfma16(a[am][ks], bbv, s[am][bc]);
      }
#pragma unroll
    for (int am = 0; am < 4; ++am)
#pragma unroll
      for (int bc = 0; bc < 4; ++bc)
#pragma unroll
        for (int rr = 0; rr < 4; ++rr)
          Pl[pswz(am * 16 + ((l >> 4) << 2) + rr, w * 64 + bc * 16 + (l & 15))] =
              (u16)f2b(__expf(s[am][bc][rr]));
    __syncthreads();
#pragma unroll
    for (int ks = 0; ks < 2; ++ks) {
      bf16x8 pa[4];
#pragma unroll
      for (int am = 0; am < 4; ++am)
        pa[am] = *(const bf16x8*)(Pl + pswz(am * 16 + (l & 15), w * 64 + ks * 32 + (l >> 4) * 8));
#pragma unroll
      for (int dn = 0; dn < 4; ++dn) {
        bf16x8 vb = *(const bf16x8*)(vtp + (long)(dn * 16 + (l & 15)) * NPAD + kt * 256 + w * 64 + ks * 32 + (l >> 4) * 8);
#pragma unroll
        for (int am = 0; am < 4; ++am) o[am][dn] = mfma16(pa[am], vb, o[am][dn]);
      }
    }
    __syncthreads();
  }
  float* Obuf = (float*)Pl;
  for (int wv = 0; wv < 4; ++wv) {
    if (w == wv) {
#pragma unroll
      for (int am = 0; am < 4; ++am)
#pragma unroll
        for (int dn = 0; dn < 4; ++dn)
#pragma unroll
          for (int rr = 0; rr < 4; ++rr) {
            int row = am * 16 + ((l >> 4) << 2) + rr, col = dn * 16 + (l & 15);
            if (wv == 0) Obuf[row * 64 + col] = o[am][dn][rr];
            else         Obuf[row * 64 + col] += o[am][dn][rr];
          }
    }
    __syncthreads();
  }
  {
    int row = t >> 2, c0 = (t & 3) * 16;
    float inv = 1.0f / lsum[row];
    float* dst = T3V + ((long)bh * ML + m0 + row) * DHD + c0;
#pragma unroll
    for (int i = 0; i < 16; ++i) dst[i] = Obuf[row * 64 + c0 + i] * inv;
  }
}

// attn1: out1[bh] = softmax(q @ kl^T) @ t2m   (fused, K-len 256)
__global__ __launch_bounds__(256) void k_attn1(
    const bf16* __restrict__ Qb, const bf16* __restrict__ KL,
    const short* __restrict__ T2MT, bf16* __restrict__ O1)
{
  __shared__ __align__(16) u16 Pl[64 * 256];
  __shared__ float psum[4][64];
  __shared__ float lsum[64];
  const int bh = blockIdx.y;
  const int m0 = blockIdx.x * 64;
  const int t = threadIdx.x, w = t >> 6, l = t & 63;
  const u16* qp  = (const u16*)Qb + (long)bh * NPAD * DHD;
  const u16* klp = (const u16*)KL + (long)bh * ML * DHD;
  const short* tp = T2MT + (long)bh * DHD * ML;

  bf16x8 a[4][2];
#pragma unroll
  for (int am = 0; am < 4; ++am)
#pragma unroll
    for (int ks = 0; ks < 2; ++ks)
      a[am][ks] = *(const bf16x8*)(qp + (long)(m0 + am * 16 + (l & 15)) * DHD + ks * 32 + (l >> 4) * 8);

  f32x4 s[4][4] = {};
#pragma unroll
  for (int ks = 0; ks < 2; ++ks)
#pragma unroll
    for (int bc = 0; bc < 4; ++bc) {
      bf16x8 bbv = *(const bf16x8*)(klp + (long)(w * 64 + bc * 16 + (l & 15)) * DHD + ks * 32 + (l >> 4) * 8);
#pragma unroll
      for (int am = 0; am < 4; ++am) s[am][bc] = mfma16(a[am][ks], bbv, s[am][bc]);
    }
  float p_[16];
#pragma unroll
  for (int am = 0; am < 4; ++am)
#pragma unroll
    for (int rr = 0; rr < 4; ++rr)
      p_[am * 4 + rr] = __expf(s[am][0][rr]) + __expf(s[am][1][rr])
                      + __expf(s[am][2][rr]) + __expf(s[am][3][rr]);
#pragma unroll
  for (int i = 0; i < 16; ++i) {
    float v = p_[i];
    v += __shfl_xor(v, 1); v += __shfl_xor(v, 2); v += __shfl_xor(v, 4); v += __shfl_xor(v, 8);
    p_[i] = v;
  }
  if ((l & 15) == 0) {
#pragma unroll
    for (int am = 0; am < 4; ++am)
#pragma unroll
      for (int rr = 0; rr < 4; ++rr)
        psum[w][am * 16 + ((l >> 4) << 2) + rr] = p_[am * 4 + rr];
  }
#pragma unroll
  for (int am = 0; am < 4; ++am)
#pragma unroll
    for (int bc = 0; bc < 4; ++bc)
#pragma unroll
      for (int rr = 0; rr < 4; ++rr)
        Pl[pswz(am * 16 + ((l >> 4) << 2) + rr, w * 64 + bc * 16 + (l & 15))] =
            (u16)f2b(__expf(s[am][bc][rr]));
  __syncthreads();
  if (t < 64) lsum[t] = psum[0][t] + psum[1][t] + psum[2][t] + psum[3][t];
  __syncthreads();

  f32x4 o[4][4] = {};
#pragma unroll
  for (int ks = 0; ks < 2; ++ks) {
    bf16x8 pa[4];
#pragma unroll
    for (int am = 0; am < 4; ++am)
      pa[am] = *(const bf16x8*)(Pl + pswz(am * 16 + (l & 15), w * 64 + ks * 32 + (l >> 4) * 8));
#pragma unroll
    for (int dn = 0; dn < 4; ++dn) {
      bf16x8 vb = *(const bf16x8*)((const u16*)tp + (long)(dn * 16 + (l & 15)) * ML + w * 64 + ks * 32 + (l >> 4) * 8);
#pragma unroll
      for (int am = 0; am < 4; ++am) o[am][dn] = mfma16(pa[am], vb, o[am][dn]);
    }
  }
  float* Obuf = (float*)Pl;
  __syncthreads();
  for (int wv = 0; wv < 4; ++wv) {
    if (w == wv) {
#pragma unroll
      for (int am = 0; am < 4; ++am)
#pragma unroll
        for (int dn = 0; dn < 4; ++dn)
#pragma unroll
          for (int rr = 0; rr < 4; ++rr) {
            int row = am * 16 + ((l >> 4) << 2) + rr, col = dn * 16 + (l & 15);
            if (wv == 0) Obuf[row * 64 + col] = o[am][dn][rr];
            else         Obuf[row * 64 + col] += o[am][dn][rr];
          }
    }
    __syncthreads();
  }
  {
    int row = t >> 2, c0 = (t & 3) * 16;
    float inv = 1.0f / lsum[row];
    u16* dst = (u16*)O1 + ((long)bh * NPAD + m0 + row) * DHD + c0;
    bf16x8 r0, r1;
#pragma unroll
    for (int i = 0; i < 8; ++i) {
      r0[i] = f2b(Obuf[row * 64 + c0 + i] * inv);
      r1[i] = f2b(Obuf[row * 64 + c0 + 8 + i] * inv);
    }
    *(bf16x8*)dst = r0;
    *(bf16x8*)(dst + 8) = r1;
  }
}

// ---------------- host orchestration ----------------

struct WSP {
  float *h, *st, *a2, *Za, *Zb, *T0, *T1, *T2, *t3v, *t2m, *red;
  bf16 *q, *k, *v, *vT, *ql, *kl;
  short *Ab, *Zc, *Zt, *Z2, *Z2t, *xz, *w1t, *w2t, *t2mT;
};

static void run_translayer(const float* nw, const float* nb, const float* qkvw,
                           const float* outw, const float* outb, const float* resw,
                           WSP& w, hipStream_t s)
{
  const long QKV_U4 = (long)3 * BH * NPAD * DHD * 2 / 16;

  k_ln_stats<<<ROWS, 256, 0, s>>>(w.h, w.st);
  k_zero<<<2048, 256, 0, s>>>((uint4*)w.q, QKV_U4);
  k_mfma_qkv<<<dim3(129, 12), 256, 0, s>>>(w.h, w.st, nw, nb, qkvw, w.q, w.k, w.v);
  k_vT<<<dim3(NPAD / 64, BH), 256, 0, s>>>(w.v, w.vT);

  const int lmN = BH * ML * DHD;
  k_landmark<<<(lmN + 255) / 256, 256, 0, s>>>(w.q, w.ql);
  k_landmark<<<(lmN + 255) / 256, 256, 0, s>>>(w.k, w.kl);

  // attn2 = softmax(ql @ kl^T)
  k_gemm_nt64<<<dim3(4, 4, BH), 256, 0, s>>>(w.ql, w.kl, w.a2, ML,
                                             (long)ML * DHD, (long)ML * DHD, SQ);
  k_softmax<<<BH * ML, 256, 0, s>>>(w.a2, ML);
  k_pinv_prep<<<BH, 256, 0, s>>>(w.a2, w.red);
  k_pinv_scale<<<1, 64, 0, s>>>(w.red);

  // t3v = softmax(ql @ k^T) @ v  (fused flash; LAST use of vT -> pinv scratch may alias it)
  k_attn3<<<dim3(4, BH), 256, 0, s>>>(w.ql, w.k, w.vT, w.t3v);

  // pinv: 5 bf16 MFMA iters + 1 fp32 iter (scratch aliases vT region)
  const long nz = (long)BH * SQ;
  k_tscale2<<<(int)((nz + 255) / 256), 256, 0, s>>>(w.a2, w.red, w.Ab, w.Zc, w.Zt);
  short *Zc = w.Zc, *Zt = w.Zt, *Z2 = w.Z2, *Z2t = w.Z2t;
  for (int it = 0; it < 5; ++it) {
    k_pinv_g<<<dim3(4, 4, BH), 256, 0, s>>>(w.Ab, Zt, w.xz, 1.f, 0.f, w.w1t, -1.f, 7.f, nullptr, 0.f);
    k_pinv_g<<<dim3(4, 4, BH), 256, 0, s>>>(w.xz, w.w1t, nullptr, 0.f, 0.f, w.w2t, -1.f, 15.f, nullptr, 0.f);
    k_pinv_g<<<dim3(4, 4, BH), 256, 0, s>>>(w.xz, w.w2t, nullptr, 0.f, 0.f, w.w1t, -1.f, 13.f, nullptr, 0.f);
    k_pinv_g<<<dim3(4, 4, BH), 256, 0, s>>>(Zc, w.w1t, Z2, 0.25f, 0.f, Z2t, 0.25f, 0.f,
                                            (it == 4) ? w.Za : nullptr, 0.25f);
    short* tm;
    tm = Zc; Zc = Z2; Z2 = tm;
    tm = Zt; Zt = Z2t; Z2t = tm;
  }
  // fp32 final iteration (restores precision; bf16 buffers now dead)
  k_gemm_nn<<<dim3(4, 4, BH), 256, 0, s>>>(w.a2, w.Za, w.T0, ML, ML, ML, SQ, SQ, SQ, 1.f, 0.f);
  k_aib<<<(int)((nz + 255) / 256), 256, 0, s>>>(w.T0, w.T1, 7.f);
  k_gemm_nn<<<dim3(4, 4, BH), 256, 0, s>>>(w.T0, w.T1, w.T2, ML, ML, ML, SQ, SQ, SQ, -1.f, 15.f);
  k_gemm_nn<<<dim3(4, 4, BH), 256, 0, s>>>(w.T0, w.T2, w.T1, ML, ML, ML, SQ, SQ, SQ, -1.f, 13.f);
  k_gemm_nn<<<dim3(4, 4, BH), 256, 0, s>>>(w.Za, w.T1, w.Zb, ML, ML, ML, SQ, SQ, SQ, 0.25f, 0.f);

  // t2m = Z @ t3v ; transpose to bf16
  k_gemm_nn<<<dim3(4, 1, BH), 256, 0, s>>>(w.Zb, w.t3v, w.t2m, ML, DHD, ML,
                                           SQ, (long)ML * DHD, (long)ML * DHD, 1.f, 0.f);
  k_t2mT<<<(BH * DHD * ML + 255) / 256, 256, 0, s>>>(w.t2m, w.t2mT);

  // out1 = softmax(q @ kl^T) @ t2m  (fused; overwrites q)
  k_attn1<<<dim3(NPAD / 64, BH), 256, 0, s>>>(w.q, w.kl, w.t2mT, w.q);

  // out1 += depthwise res conv of v
  const long rcN = (long)BH * NPAD * DHD;
  k_resconv<<<(int)((rcN + 255) / 256), 256, 0, s>>>(w.v, resw, w.q);

  // h += merge(out1) @ out_w^T + out_b
  k_mfma_out<<<dim3(129, 4), 256, 0, s>>>(w.q, outw, outb, w.h);
}

extern "C" void kernel_launch(void* const* d_in, const int* in_sizes, int n_in,
                              void* d_out, int out_size, void* d_ws, size_t ws_size,
                              hipStream_t stream)
{
  const float* x      = (const float*)d_in[0];
  const float* cls    = (const float*)d_in[1];
  const float* l1nw   = (const float*)d_in[2];
  const float* l1nb   = (const float*)d_in[3];
  const float* l1qkvw = (const float*)d_in[4];
  const float* l1outw = (const float*)d_in[5];
  const float* l1outb = (const float*)d_in[6];
  const float* l1resw = (const float*)d_in[7];
  const float* l2nw   = (const float*)d_in[8];
  const float* l2nb   = (const float*)d_in[9];
  const float* l2qkvw = (const float*)d_in[10];
  const float* l2outw = (const float*)d_in[11];
  const float* l2outb = (const float*)d_in[12];
  const float* l2resw = (const float*)d_in[13];
  const float* pw7    = (const float*)d_in[14];
  const float* pb7    = (const float*)d_in[15];
  const float* pw5    = (const float*)d_in[16];
  const float* pb5    = (const float*)d_in[17];
  const float* pw3    = (const float*)d_in[18];
  const float* pb3    = (const float*)d_in[19];
  const float* fnw    = (const float*)d_in[20];
  const float* fnb    = (const float*)d_in[21];
  (void)in_sizes; (void)n_in; (void)out_size; (void)ws_size;

  float* W = (float*)d_ws;
  size_t o = 0;
  auto alloc = [&](size_t n) { float* p = W + o; o += n; return p; };
  WSP w;
  w.h  = alloc((size_t)ROWS * CDIM);                       // 33.6 MB
  w.st = alloc((size_t)ROWS * 2);
  float* qkvr = alloc((size_t)3 * BH * NPAD * DHD / 2);    // 51.9 MB bf16
  w.q = (bf16*)qkvr;
  w.k = w.q + (size_t)BH * NPAD * DHD;
  w.v = w.k + (size_t)BH * NPAD * DHD;
  // vT (17.3 MB bf16) shares its region with the pinv scratch:
  //   8 bf16 buffers of BH*SQ shorts = 16.8 MB, or fp32 Zb/T0/T1/T2 = 16.8 MB.
  // Disjoint live ranges: vT dies at k_attn3; scratch born at k_tscale2.
  float* vtr = alloc((size_t)BH * NPAD * DHD / 2);
  w.vT = (bf16*)vtr;
  {
    const size_t S2f = (size_t)BH * SQ;      // floats per fp32 buffer
    w.Zb = vtr; w.T0 = vtr + S2f; w.T1 = vtr + 2 * S2f; w.T2 = vtr + 3 * S2f;
    short* pb = (short*)vtr;
    const size_t S2 = (size_t)BH * SQ;       // shorts per bf16 buffer
    w.Ab = pb;           w.Zc  = pb + S2;     w.Zt  = pb + 2 * S2; w.Z2 = pb + 3 * S2;
    w.Z2t = pb + 4 * S2; w.xz  = pb + 5 * S2; w.w1t = pb + 6 * S2; w.w2t = pb + 7 * S2;
  }
  float* lmr = alloc((size_t)2 * BH * ML * DHD / 2);       // 1 MB bf16
  w.ql = (bf16*)lmr;
  w.kl = w.ql + (size_t)BH * ML * DHD;
  w.a2 = alloc((size_t)BH * SQ);                           // 4.2 MB
  w.Za = alloc((size_t)BH * SQ);                           // 4.2 MB
  w.t3v = alloc((size_t)BH * ML * DHD);
  w.t2m = alloc((size_t)BH * ML * DHD);
  float* ttr = alloc((size_t)BH * ML * DHD / 2);
  w.t2mT = (short*)ttr;
  w.red = alloc(64);
  // total ~115 MB (< 121 MB proven safe in round 2)

  const long nh = (long)ROWS * CDIM;
  k_build_h<<<(int)((nh + 255) / 256), 256, 0, stream>>>(x, cls, w.h);

  run_translayer(l1nw, l1nb, l1qkvw, l1outw, l1outb, l1resw, w, stream);

  // PPEG (feat aliases dead q/k bf16 region: 33.9 MB <= 34.6 MB)
  float* feat = (float*)w.q;
  const long fe = (long)BB * CDIM * HW2;
  k_ppeg_build<<<(int)((fe + 255) / 256), 256, 0, stream>>>(w.h, feat);
  k_ppeg_conv<<<(int)((fe + 255) / 256), 256, 0, stream>>>(feat, pw7, pb7, pw5, pb5, pw3, pb3, w.h);

  run_translayer(l2nw, l2nb, l2qkvw, l2outw, l2outb, l2resw, w, stream);

  k_final_ln<<<BB, 256, 0, stream>>>(w.h, fnw, fnb, (float*)d_out);
}

// Round 5
// 1712.108 us; speedup vs baseline: 13.2451x; 1.3461x over previous
//
#include <hip/hip_runtime.h>
#include <hip/hip_bf16.h>

using bf16 = __hip_bfloat16;
typedef unsigned short u16;
typedef short bf16x8 __attribute__((ext_vector_type(8)));
typedef float f32x4 __attribute__((ext_vector_type(4)));

constexpr int BB    = 2;
constexpr int NSEQ  = 8193;
constexpr int CDIM  = 512;
constexpr int NH    = 8;
constexpr int DHD   = 64;
constexpr int ML    = 256;
constexpr int LF    = 33;
constexpr int NPAD  = 8448;
constexpr int PADL  = 255;
constexpr int ROWS  = BB * NSEQ;     // 16386
constexpr int BH    = BB * NH;       // 16
constexpr int RKS   = 33;
constexpr int HG    = 91;
constexpr int HW2   = HG * HG;       // 8281
constexpr int NPATCH = 8192;
constexpr long SQ   = (long)ML * ML; // 65536 per bh

__device__ __forceinline__ float b2f(u16 u) {
  union { unsigned int i; float f; } x; x.i = (unsigned int)u << 16; return x.f;
}
__device__ __forceinline__ short f2b(float f) {
  __hip_bfloat16 h = __float2bfloat16(f);
  return *reinterpret_cast<short*>(&h);
}
__device__ __forceinline__ f32x4 mfma16(bf16x8 a, bf16x8 b, f32x4 c) {
  return __builtin_amdgcn_mfma_f32_16x16x32_bf16(a, b, c, 0, 0, 0);
}

// ---------------- small kernels ----------------

__global__ __launch_bounds__(256) void k_build_h(
    const float* __restrict__ x, const float* __restrict__ cls, float* __restrict__ h)
{
  long idx = (long)blockIdx.x * 256 + threadIdx.x;
  if (idx >= (long)ROWS * CDIM) return;
  int c = idx & 511;
  long r = idx >> 9;
  int b = (int)(r / NSEQ), i = (int)(r % NSEQ);
  h[idx] = (i == 0) ? cls[c] : x[((long)b * (NSEQ - 1) + (i - 1)) * CDIM + c];
}

// generic fp32 -> bf16 convert
__global__ __launch_bounds__(256) void k_cvt(
    const float* __restrict__ X, short* __restrict__ Y, long n)
{
  long i = (long)blockIdx.x * 256 + threadIdx.x;
  const long st = (long)gridDim.x * 256;
  for (; i < n; i += st) Y[i] = f2b(X[i]);
}

// zero the PADL pad rows of q,k,v (3 contiguous buffers)
__global__ __launch_bounds__(256) void k_zpad(uint4* __restrict__ q)
{
  const int seg = blockIdx.y;            // buf*16 + bh
  const int buf = seg >> 4, bh = seg & 15;
  const long base_e = ((long)buf * BH + bh) * ((long)NPAD * DHD);
  uint4* p = (uint4*)((u16*)q + base_e);
  const int n16 = PADL * DHD * 2 / 16;   // 2040
  for (int i = blockIdx.x * 256 + threadIdx.x; i < n16; i += gridDim.x * 256)
    p[i] = make_uint4(0u, 0u, 0u, 0u);
}

// fused LayerNorm -> bf16 output
__global__ __launch_bounds__(256) void k_lnq(
    const float* __restrict__ X, const float* __restrict__ g,
    const float* __restrict__ bb, bf16* __restrict__ Y)
{
  __shared__ float red[4];
  const long row = blockIdx.x;
  const float* x = X + row * CDIM;
  const int t = threadIdx.x;
  float a0 = x[t], a1 = x[t + 256];
  float s = a0 + a1;
  for (int o = 32; o; o >>= 1) s += __shfl_down(s, o);
  if ((t & 63) == 0) red[t >> 6] = s;
  __syncthreads();
  const float mu = (red[0] + red[1] + red[2] + red[3]) * (1.0f / CDIM);
  __syncthreads();
  float d0 = a0 - mu, d1 = a1 - mu;
  float q = d0 * d0 + d1 * d1;
  for (int o = 32; o; o >>= 1) q += __shfl_down(q, o);
  if ((t & 63) == 0) red[t >> 6] = q;
  __syncthreads();
  const float var = (red[0] + red[1] + red[2] + red[3]) * (1.0f / CDIM);
  const float rs = rsqrtf(var + 1e-5f);
  u16* y = (u16*)Y + row * CDIM;
  y[t]       = (u16)f2b(d0 * rs * g[t]       + bb[t]);
  y[t + 256] = (u16)f2b(d1 * rs * g[t + 256] + bb[t + 256]);
}

__global__ __launch_bounds__(256) void k_final_ln(
    const float* __restrict__ H, const float* __restrict__ g,
    const float* __restrict__ bb, float* __restrict__ out)
{
  __shared__ float red[4];
  const float* x = H + (long)blockIdx.x * NSEQ * CDIM;
  const int t = threadIdx.x;
  float a0 = x[t], a1 = x[t + 256];
  float s = a0 + a1;
  for (int o = 32; o; o >>= 1) s += __shfl_down(s, o);
  if ((t & 63) == 0) red[t >> 6] = s;
  __syncthreads();
  const float mu = (red[0] + red[1] + red[2] + red[3]) * (1.0f / CDIM);
  __syncthreads();
  float d0 = a0 - mu, d1 = a1 - mu;
  float q = d0 * d0 + d1 * d1;
  for (int o = 32; o; o >>= 1) q += __shfl_down(q, o);
  if ((t & 63) == 0) red[t >> 6] = q;
  __syncthreads();
  const float var = (red[0] + red[1] + red[2] + red[3]) * (1.0f / CDIM);
  const float rs = rsqrtf(var + 1e-5f);
  out[blockIdx.x * CDIM + t]       = d0 * rs * g[t]       + bb[t];
  out[blockIdx.x * CDIM + t + 256] = d1 * rs * g[t + 256] + bb[t + 256];
}

__global__ __launch_bounds__(256) void k_landmark(
    const bf16* __restrict__ src, bf16* __restrict__ dst)
{
  int idx = blockIdx.x * 256 + threadIdx.x;
  if (idx >= BH * ML * DHD) return;
  int d = idx & 63, j = (idx >> 6) & 255, bh = idx >> 14;
  const u16* p = (const u16*)src + ((long)bh * NPAD + (long)j * LF) * DHD + d;
  float s = 0.f;
#pragma unroll
  for (int t = 0; t < LF; ++t) s += b2f(p[t * DHD]);
  ((u16*)dst)[idx] = (u16)f2b(s * (1.0f / LF));
}

__global__ __launch_bounds__(256) void k_softmax(float* __restrict__ S, int W)
{
  __shared__ float buf[ML];
  __shared__ float red[4];
  float* p = S + (long)blockIdx.x * W;
  const int t = threadIdx.x;
  float mx = -3.4e38f;
  for (int j = t; j < W; j += 256) { float v = p[j]; buf[j] = v; mx = fmaxf(mx, v); }
  for (int o = 32; o; o >>= 1) mx = fmaxf(mx, __shfl_down(mx, o));
  if ((t & 63) == 0) red[t >> 6] = mx;
  __syncthreads();
  mx = fmaxf(fmaxf(red[0], red[1]), fmaxf(red[2], red[3]));
  __syncthreads();
  float sum = 0.f;
  for (int j = t; j < W; j += 256) { float e = __expf(buf[j] - mx); buf[j] = e; sum += e; }
  for (int o = 32; o; o >>= 1) sum += __shfl_down(sum, o);
  if ((t & 63) == 0) red[t >> 6] = sum;
  __syncthreads();
  const float inv = 1.0f / (red[0] + red[1] + red[2] + red[3]);
  for (int j = t; j < W; j += 256) p[j] = buf[j] * inv;
}

__global__ __launch_bounds__(256) void k_pinv_prep(
    const float* __restrict__ A, float* __restrict__ red)
{
  __shared__ float r1[4], r2[4];
  const float* Ab = A + (long)blockIdx.x * SQ;
  const int t = threadIdx.x;
  float rs = 0.f, cs = 0.f;
  for (int j = 0; j < ML; ++j) { rs += fabsf(Ab[t * ML + j]); cs += fabsf(Ab[j * ML + t]); }
  for (int o = 32; o; o >>= 1) { rs = fmaxf(rs, __shfl_down(rs, o)); cs = fmaxf(cs, __shfl_down(cs, o)); }
  if ((t & 63) == 0) { r1[t >> 6] = rs; r2[t >> 6] = cs; }
  __syncthreads();
  if (t == 0) {
    red[blockIdx.x]      = fmaxf(fmaxf(r1[0], r1[1]), fmaxf(r1[2], r1[3]));
    red[16 + blockIdx.x] = fmaxf(fmaxf(r2[0], r2[1]), fmaxf(r2[2], r2[3]));
  }
}

__global__ void k_pinv_scale(float* __restrict__ red)
{
  if (threadIdx.x == 0 && blockIdx.x == 0) {
    float cmax = red[0], rmax = red[16];
    for (int i = 1; i < 16; ++i) { cmax = fmaxf(cmax, red[i]); rmax = fmaxf(rmax, red[16 + i]); }
    red[32] = 1.0f / (cmax * rmax);
  }
}

// Ab = bf16(attn2); Zt = bf16(attn2*s) [= z0^T]; Z = bf16(attn2^T*s) [= z0]
__global__ __launch_bounds__(256) void k_tscale2(
    const float* __restrict__ A, const float* __restrict__ red,
    short* __restrict__ Ab, short* __restrict__ Z, short* __restrict__ Zt)
{
  long idx = (long)blockIdx.x * 256 + threadIdx.x;
  if (idx >= (long)BH * SQ) return;
  int c = idx & 255, r = (int)((idx >> 8) & 255);
  long bh = idx >> 16;
  float a = A[idx];
  float s = red[32];
  Ab[idx] = f2b(a);
  Zt[idx] = f2b(a * s);
  Z[(bh << 16) + ((long)c << 8) + r] = f2b(a * s);
}

// hi/lo bf16 split of (alpha*X + diag*I): optional row-major and transposed outputs
__global__ __launch_bounds__(256) void k_split(
    const float* __restrict__ X, float alpha, float diag,
    short* __restrict__ rH, short* __restrict__ rL,
    short* __restrict__ cH, short* __restrict__ cL)
{
  long idx = (long)blockIdx.x * 256 + threadIdx.x;
  if (idx >= (long)BH * SQ) return;
  int c = idx & 255, r = (int)((idx >> 8) & 255);
  long bh = idx >> 16;
  float v = alpha * X[idx] + ((r == c) ? diag : 0.f);
  short h = f2b(v);
  short lo = f2b(v - b2f((u16)h));
  if (rH) { rH[idx] = h; rL[idx] = lo; }
  if (cH) { long tix = (bh << 16) + ((long)c << 8) + r; cH[tix] = h; cL[tix] = lo; }
}

// depthwise seq-conv of v, tiled in LDS; out1 += res
__global__ __launch_bounds__(256) void k_resconv2(
    const bf16* __restrict__ v, const float* __restrict__ w, bf16* __restrict__ out)
{
  __shared__ u16 vb[96][64];
  __shared__ float ws[RKS];
  const int bh = blockIdx.y, i0 = blockIdx.x * 64;
  const int t = threadIdx.x;
  if (t < RKS) ws[t] = w[(bh & 7) * RKS + t];
  const u16* vsrc = (const u16*)v + (long)bh * NPAD * DHD;
#pragma unroll
  for (int i = 0; i < 3; ++i) {
    int chunk = t + 256 * i;
    int row = chunk >> 3, c8 = (chunk & 7) * 8;
    int vrow = i0 - 16 + row;
    bf16x8 val;
    if (vrow >= 0 && vrow < NPAD) val = *(const bf16x8*)(vsrc + (long)vrow * DHD + c8);
    else { for (int j = 0; j < 8; ++j) val[j] = 0; }
    *(bf16x8*)(&vb[row][c8]) = val;
  }
  __syncthreads();
  const int d = t & 63;
  u16* ob = (u16*)out + ((long)bh * NPAD + i0) * DHD;
#pragma unroll
  for (int j = 0; j < 16; ++j) {
    int r = (t >> 6) + j * 4;
    float s = 0.f;
#pragma unroll
    for (int k = 0; k < RKS; ++k) s += b2f(vb[r + k][d]) * ws[k];
    long oi = (long)r * DHD + d;
    ob[oi] = (u16)f2b(b2f(ob[oi]) + s);
  }
}

// vT[bh][d][row] = v[bh][row][d]
__global__ __launch_bounds__(256) void k_vT(const bf16* __restrict__ V, bf16* __restrict__ VT)
{
  __shared__ u16 tl[64][72];
  const int r0 = blockIdx.x * 64, bh = blockIdx.y;
  const u16* vp = (const u16*)V + ((long)bh * NPAD + r0) * DHD;
  const int t = threadIdx.x;
  {
    int r = t >> 2, c0 = (t & 3) * 16;
    bf16x8 u0 = *(const bf16x8*)(vp + (long)r * DHD + c0);
    bf16x8 u1 = *(const bf16x8*)(vp + (long)r * DHD + c0 + 8);
#pragma unroll
    for (int i = 0; i < 8; ++i) { tl[r][c0 + i] = (u16)u0[i]; tl[r][c0 + 8 + i] = (u16)u1[i]; }
  }
  __syncthreads();
  {
    int d = t >> 2, k0 = (t & 3) * 16;
    bf16x8 u0, u1;
#pragma unroll
    for (int i = 0; i < 8; ++i) { u0[i] = (short)tl[k0 + i][d]; u1[i] = (short)tl[k0 + 8 + i][d]; }
    u16* dst = (u16*)VT + ((long)bh * DHD + d) * NPAD + r0 + k0;
    *(bf16x8*)dst = u0;
    *(bf16x8*)(dst + 8) = u1;
  }
}

__global__ __launch_bounds__(256) void k_t2mT(const float* __restrict__ T2M, short* __restrict__ T2MT)
{
  int idx = blockIdx.x * 256 + threadIdx.x;
  if (idx >= BH * DHD * ML) return;
  int k = idx & 255, d = (idx >> 8) & 63, bh = idx >> 14;
  T2MT[idx] = f2b(T2M[((long)bh * ML + k) * DHD + d]);
}

// ---------------- PPEG (tiled transposes + LDS-plane conv) ----------------

__global__ __launch_bounds__(256) void k_ppeg_build_t(
    const float* __restrict__ h, float* __restrict__ feat)
{
  __shared__ float tile[32][33];
  const int c0 = blockIdx.x * 32;
  const int p0 = blockIdx.y * 32;
  const int b  = blockIdx.z;
  const int t = threadIdx.x;
  const int tc = t & 31, tr8 = t >> 5;
  const int srcb = (p0 >= NPATCH) ? p0 - NPATCH : p0;
#pragma unroll
  for (int i = 0; i < 4; ++i) {
    int pp = tr8 + i * 8;
    if (p0 + pp < HW2)
      tile[pp][tc] = h[((long)b * NSEQ + 1 + srcb + pp) * CDIM + c0 + tc];
  }
  __syncthreads();
#pragma unroll
  for (int i = 0; i < 4; ++i) {
    int cc = tr8 + i * 8;
    if (p0 + tc < HW2)
      feat[((long)(b * CDIM + c0 + cc)) * HW2 + p0 + tc] = tile[tc][cc];
  }
}

__global__ __launch_bounds__(256) void k_ppeg_conv2(
    const float* __restrict__ feat,
    const float* __restrict__ w7, const float* __restrict__ b7,
    const float* __restrict__ w5, const float* __restrict__ b5,
    const float* __restrict__ w3, const float* __restrict__ b3,
    float* __restrict__ ofeat)
{
  __shared__ float P[97 * 97];
  __shared__ float ws[84];
  const int bx = blockIdx.x;       // b*512 + c
  const int c = bx & 511;
  const int t = threadIdx.x;
  for (int i = t; i < 97 * 97; i += 256) P[i] = 0.f;
  if (t < 49) ws[t] = w7[c * 49 + t];
  else if (t < 74) ws[t] = w5[c * 25 + (t - 49)];
  else if (t < 83) ws[t] = w3[c * 9 + (t - 74)];
  __syncthreads();
  const float* fp = feat + (long)bx * HW2;
  for (int i = t; i < HW2; i += 256) {
    int y = i / HG, x = i - y * HG;
    P[(y + 3) * 97 + x + 3] = fp[i];
  }
  __syncthreads();
  const float bias = b7[c] + b5[c] + b3[c];
  float* op = ofeat + (long)bx * HW2;
  for (int i = t; i < HW2; i += 256) {
    int y = i / HG, x = i - y * HG;
    const float* pc = &P[y * 97 + x];
    float s = pc[3 * 97 + 3] + bias;
#pragma unroll
    for (int dy = 0; dy < 7; ++dy)
#pragma unroll
      for (int dx = 0; dx < 7; ++dx)
        s += pc[dy * 97 + dx] * ws[dy * 7 + dx];
#pragma unroll
    for (int dy = 0; dy < 5; ++dy)
#pragma unroll
      for (int dx = 0; dx < 5; ++dx)
        s += pc[(dy + 1) * 97 + dx + 1] * ws[49 + dy * 5 + dx];
#pragma unroll
    for (int dy = 0; dy < 3; ++dy)
#pragma unroll
      for (int dx = 0; dx < 3; ++dx)
        s += pc[(dy + 2) * 97 + dx + 2] * ws[74 + dy * 3 + dx];
    op[i] = s;
  }
}

__global__ __launch_bounds__(256) void k_ppeg_scat_t(
    const float* __restrict__ ofeat, float* __restrict__ h)
{
  __shared__ float tile[32][33];
  const int c0 = blockIdx.x * 32;
  const int p0 = blockIdx.y * 32;   // grid.y = 256 -> pos < 8192 always
  const int b  = blockIdx.z;
  const int t = threadIdx.x;
  const int tc = t & 31, tr8 = t >> 5;
#pragma unroll
  for (int i = 0; i < 4; ++i) {
    int cc = tr8 + i * 8;
    tile[cc][tc] = ofeat[((long)(b * CDIM + c0 + cc)) * HW2 + p0 + tc];
  }
  __syncthreads();
#pragma unroll
  for (int i = 0; i < 4; ++i) {
    int pp = tr8 + i * 8;
    h[((long)b * NSEQ + 1 + p0 + pp) * CDIM + c0 + tc] = tile[tc][pp];
  }
}

// ---------------- fp32 GEMM (t2m only) ----------------

__global__ __launch_bounds__(256) void k_gemm_nn(
    const float* __restrict__ A, const float* __restrict__ Bm, float* __restrict__ Cm,
    int M, int N, int K, long sA, long sB, long sC, float alpha, float diag)
{
  __shared__ float As[64][17], Bs[16][68];
  const float* Ab = A + (long)blockIdx.z * sA;
  const float* Bb = Bm + (long)blockIdx.z * sB;
  float* Cb = Cm + (long)blockIdx.z * sC;
  const int m0 = blockIdx.x << 6, n0 = blockIdx.y << 6;
  const int t = threadIdx.x, ty = t >> 4, tx = t & 15;
  const int lr = t >> 2, lk = (t & 3) << 2;
  const int bk = t >> 4, bn = (t & 15) << 2;
  float acc[4][4] = {};
  for (int k0 = 0; k0 < K; k0 += 16) {
    float4 av = make_float4(0.f, 0.f, 0.f, 0.f), bv = make_float4(0.f, 0.f, 0.f, 0.f);
    if (m0 + lr < M) av = *(const float4*)(Ab + (long)(m0 + lr) * K + k0 + lk);
    if (n0 + bn < N) bv = *(const float4*)(Bb + (long)(k0 + bk) * N + n0 + bn);
    As[lr][lk] = av.x; As[lr][lk + 1] = av.y; As[lr][lk + 2] = av.z; As[lr][lk + 3] = av.w;
    Bs[bk][bn] = bv.x; Bs[bk][bn + 1] = bv.y; Bs[bk][bn + 2] = bv.z; Bs[bk][bn + 3] = bv.w;
    __syncthreads();
#pragma unroll
    for (int kk = 0; kk < 16; ++kk) {
      float a[4], b[4];
#pragma unroll
      for (int i = 0; i < 4; ++i) a[i] = As[ty * 4 + i][kk];
#pragma unroll
      for (int j = 0; j < 4; ++j) b[j] = Bs[kk][tx * 4 + j];
#pragma unroll
      for (int i = 0; i < 4; ++i)
#pragma unroll
        for (int j = 0; j < 4; ++j) acc[i][j] += a[i] * b[j];
    }
    __syncthreads();
  }
#pragma unroll
  for (int i = 0; i < 4; ++i) {
    int r = m0 + ty * 4 + i;
    if (r >= M) continue;
#pragma unroll
    for (int j = 0; j < 4; ++j) {
      int n = n0 + tx * 4 + j;
      if (n >= N) continue;
      float v = alpha * acc[i][j];
      if (r == n) v += diag;
      Cb[(long)r * N + n] = v;
    }
  }
}

// ---------------- MFMA projection GEMMs (all-bf16 operands) ----------------

// qkv = lnq @ wqb^T -> scatter bf16 q/k/v (q*0.125). 128x128 tile, K=512.
__global__ __launch_bounds__(256) void k_mfma_qkv2(
    const bf16* __restrict__ Aq, const short* __restrict__ Wm,
    bf16* __restrict__ Q, bf16* __restrict__ Kp, bf16* __restrict__ V)
{
  __shared__ __align__(16) short As[128 * 32];
  __shared__ __align__(16) short Bs[128 * 32];
  const int m0 = blockIdx.x * 128, n0 = blockIdx.y * 128;
  const int t = threadIdx.x, w = t >> 6, l = t & 63;
  const int srow = t >> 1, skh = (t & 1) * 16;
  const int aR = m0 + srow;
  const int wR = n0 + srow;
  const int g0 = skh >> 3;
  const int sw0 = ((g0 ^ (srow & 3)) << 3), sw1 = (((g0 + 1) ^ (srow & 3)) << 3);
  const u16* ap = (const u16*)Aq;
  f32x4 acc[4][4] = {};
  for (int kt = 0; kt < 16; ++kt) {
    const int kbase = kt * 32 + skh;
    {
      bf16x8 v0, v1;
      if (aR < ROWS) {
        v0 = *(const bf16x8*)(ap + (long)aR * CDIM + kbase);
        v1 = *(const bf16x8*)(ap + (long)aR * CDIM + kbase + 8);
      } else {
#pragma unroll
        for (int i = 0; i < 8; ++i) { v0[i] = 0; v1[i] = 0; }
      }
      *(bf16x8*)(As + srow * 32 + sw0) = v0;
      *(bf16x8*)(As + srow * 32 + sw1) = v1;
    }
    {
      bf16x8 v0 = *(const bf16x8*)(Wm + (long)wR * CDIM + kbase);
      bf16x8 v1 = *(const bf16x8*)(Wm + (long)wR * CDIM + kbase + 8);
      *(bf16x8*)(Bs + srow * 32 + sw0) = v0;
      *(bf16x8*)(Bs + srow * 32 + sw1) = v1;
    }
    __syncthreads();
    const int ar0 = (w >> 1) * 64, bc0 = (w & 1) * 64;
    const int kg = l >> 4;
    bf16x8 a[4], b[4];
#pragma unroll
    for (int am = 0; am < 4; ++am) {
      int row = ar0 + am * 16 + (l & 15);
      a[am] = *(const bf16x8*)(As + row * 32 + ((kg ^ (row & 3)) << 3));
    }
#pragma unroll
    for (int bn = 0; bn < 4; ++bn) {
      int row = bc0 + bn * 16 + (l & 15);
      b[bn] = *(const bf16x8*)(Bs + row * 32 + ((kg ^ (row & 3)) << 3));
    }
#pragma unroll
    for (int am = 0; am < 4; ++am)
#pragma unroll
      for (int bn = 0; bn < 4; ++bn) acc[am][bn] = mfma16(a[am], b[bn], acc[am][bn]);
    __syncthreads();
  }
  const int ar0 = (w >> 1) * 64, bc0 = (w & 1) * 64;
#pragma unroll
  for (int am = 0; am < 4; ++am) {
#pragma unroll
    for (int rr = 0; rr < 4; ++rr) {
      int R = m0 + ar0 + am * 16 + ((l >> 4) << 2) + rr;
      if (R >= ROWS) continue;
      int b = R / NSEQ, ii = R - b * NSEQ;
#pragma unroll
      for (int bn = 0; bn < 4; ++bn) {
        int n = n0 + bc0 + bn * 16 + (l & 15);
        int which = n >> 9, rem = n & 511, hd = rem >> 6, d = rem & 63;
        float val = acc[am][bn][rr];
        if (which == 0) val *= 0.125f;
        u16* dst = (u16*)(which == 0 ? Q : (which == 1 ? Kp : V));
        dst[(((long)(b * NH + hd)) * NPAD + PADL + ii) * DHD + d] = (u16)f2b(val);
      }
    }
  }
}

// h += merge(out1) @ wob^T + out_b. 128x128 tile, K=512.
__global__ __launch_bounds__(256) void k_mfma_out2(
    const bf16* __restrict__ O1, const short* __restrict__ Wm,
    const float* __restrict__ bias, float* __restrict__ Hh)
{
  __shared__ __align__(16) short As[128 * 32];
  __shared__ __align__(16) short Bs[128 * 32];
  const int m0 = blockIdx.x * 128, n0 = blockIdx.y * 128;
  const int t = threadIdx.x, w = t >> 6, l = t & 63;
  const int srow = t >> 1, skh = (t & 1) * 16;
  const int aR = m0 + srow;
  int bb = 0, ii = 0;
  if (aR < ROWS) { bb = aR / NSEQ; ii = aR - bb * NSEQ; }
  const int wR = n0 + srow;
  const int g0 = skh >> 3;
  const int sw0 = ((g0 ^ (srow & 3)) << 3), sw1 = (((g0 + 1) ^ (srow & 3)) << 3);
  const u16* o1 = (const u16*)O1;
  f32x4 acc[4][4] = {};
  for (int kt = 0; kt < 16; ++kt) {
    const int kbase = kt * 32 + skh;
    {
      bf16x8 v0, v1;
      if (aR < ROWS) {
        int hd = kbase >> 6, d0 = kbase & 63;
        const u16* src = o1 + (((long)(bb * NH + hd)) * NPAD + PADL + ii) * DHD + d0;
        v0 = *(const bf16x8*)src;
        v1 = *(const bf16x8*)(src + 8);
      } else {
#pragma unroll
        for (int i = 0; i < 8; ++i) { v0[i] = 0; v1[i] = 0; }
      }
      *(bf16x8*)(As + srow * 32 + sw0) = v0;
      *(bf16x8*)(As + srow * 32 + sw1) = v1;
    }
    {
      bf16x8 v0 = *(const bf16x8*)(Wm + (long)wR * CDIM + kbase);
      bf16x8 v1 = *(const bf16x8*)(Wm + (long)wR * CDIM + kbase + 8);
      *(bf16x8*)(Bs + srow * 32 + sw0) = v0;
      *(bf16x8*)(Bs + srow * 32 + sw1) = v1;
    }
    __syncthreads();
    const int ar0 = (w >> 1) * 64, bc0 = (w & 1) * 64;
    const int kg = l >> 4;
    bf16x8 a[4], b[4];
#pragma unroll
    for (int am = 0; am < 4; ++am) {
      int row = ar0 + am * 16 + (l & 15);
      a[am] = *(const bf16x8*)(As + row * 32 + ((kg ^ (row & 3)) << 3));
    }
#pragma unroll
    for (int bn = 0; bn < 4; ++bn) {
      int row = bc0 + bn * 16 + (l & 15);
      b[bn] = *(const bf16x8*)(Bs + row * 32 + ((kg ^ (row & 3)) << 3));
    }
#pragma unroll
    for (int am = 0; am < 4; ++am)
#pragma unroll
      for (int bn = 0; bn < 4; ++bn) acc[am][bn] = mfma16(a[am], b[bn], acc[am][bn]);
    __syncthreads();
  }
  const int ar0 = (w >> 1) * 64, bc0 = (w & 1) * 64;
#pragma unroll
  for (int am = 0; am < 4; ++am) {
#pragma unroll
    for (int rr = 0; rr < 4; ++rr) {
      int R = m0 + ar0 + am * 16 + ((l >> 4) << 2) + rr;
      if (R >= ROWS) continue;
      float* hrow = Hh + (long)R * CDIM;
#pragma unroll
      for (int bn = 0; bn < 4; ++bn) {
        int n = n0 + bc0 + bn * 16 + (l & 15);
        hrow[n] += acc[am][bn][rr] + bias[n];
      }
    }
  }
}

// ---------------- batched pinv MFMA GEMMs ----------------

// C = A @ Bt^T-storage (bf16); epilogue: outN=aN*x+dN*I, outT=(aT*x+dT*I)^T, outF fp32
__global__ __launch_bounds__(256) void k_pinv_g(
    const short* __restrict__ A, const short* __restrict__ Bt,
    short* __restrict__ outN, float aN, float dN,
    short* __restrict__ outT, float aT, float dT,
    float* __restrict__ outF, float aF)
{
  const int bh = blockIdx.z;
  const long off = (long)bh * SQ;
  const short* Ab = A + off;
  const short* Btb = Bt + off;
  const int t = threadIdx.x, w = t >> 6, l = t & 63;
  const int r0 = blockIdx.x * 64 + (w >> 1) * 32;
  const int c0 = blockIdx.y * 64 + (w & 1) * 32;
  f32x4 acc[2][2] = {};
#pragma unroll
  for (int ks = 0; ks < 8; ++ks) {
    bf16x8 a[2], b[2];
#pragma unroll
    for (int am = 0; am < 2; ++am)
      a[am] = *(const bf16x8*)(Ab + (long)(r0 + am * 16 + (l & 15)) * ML + ks * 32 + (l >> 4) * 8);
#pragma unroll
    for (int bn = 0; bn < 2; ++bn)
      b[bn] = *(const bf16x8*)(Btb + (long)(c0 + bn * 16 + (l & 15)) * ML + ks * 32 + (l >> 4) * 8);
#pragma unroll
    for (int am = 0; am < 2; ++am)
#pragma unroll
      for (int bn = 0; bn < 2; ++bn) acc[am][bn] = mfma16(a[am], b[bn], acc[am][bn]);
  }
#pragma unroll
  for (int am = 0; am < 2; ++am)
#pragma unroll
    for (int bn = 0; bn < 2; ++bn)
#pragma unroll
      for (int rr = 0; rr < 4; ++rr) {
        int R = r0 + am * 16 + ((l >> 4) << 2) + rr;
        int C = c0 + bn * 16 + (l & 15);
        float x = acc[am][bn][rr];
        float dg = (R == C) ? 1.f : 0.f;
        if (outN) outN[off + (long)R * ML + C] = f2b(aN * x + dN * dg);
        if (outT) outT[off + (long)C * ML + R] = f2b(aT * x + dT * dg);
        if (outF) outF[off + (long)R * ML + C] = aF * x;
      }
}

// split-precision GEMM: C = (Ah+Al)@(Bh+Bl) via 3 MFMA chains; fp32 out
__global__ __launch_bounds__(256) void k_pinv_gs(
    const short* __restrict__ Ah, const short* __restrict__ Al,
    const short* __restrict__ BhT, const short* __restrict__ BlT,
    float* __restrict__ outF, float alpha, float diag)
{
  const int bh = blockIdx.z;
  const long off = (long)bh * SQ;
  const int t = threadIdx.x, w = t >> 6, l = t & 63;
  const int r0 = blockIdx.x * 64 + (w >> 1) * 32;
  const int c0 = blockIdx.y * 64 + (w & 1) * 32;
  f32x4 acc[2][2] = {};
#pragma unroll
  for (int ks = 0; ks < 8; ++ks) {
    bf16x8 ah[2], al[2], bh_[2], bl[2];
#pragma unroll
    for (int am = 0; am < 2; ++am) {
      long base = off + (long)(r0 + am * 16 + (l & 15)) * ML + ks * 32 + (l >> 4) * 8;
      ah[am] = *(const bf16x8*)(Ah + base);
      al[am] = *(const bf16x8*)(Al + base);
    }
#pragma unroll
    for (int bn = 0; bn < 2; ++bn) {
      long base = off + (long)(c0 + bn * 16 + (l & 15)) * ML + ks * 32 + (l >> 4) * 8;
      bh_[bn] = *(const bf16x8*)(BhT + base);
      bl[bn] = *(const bf16x8*)(BlT + base);
    }
#pragma unroll
    for (int am = 0; am < 2; ++am)
#pragma unroll
      for (int bn = 0; bn < 2; ++bn) {
        acc[am][bn] = mfma16(ah[am], bh_[bn], acc[am][bn]);
        acc[am][bn] = mfma16(ah[am], bl[bn], acc[am][bn]);
        acc[am][bn] = mfma16(al[am], bh_[bn], acc[am][bn]);
      }
  }
#pragma unroll
  for (int am = 0; am < 2; ++am)
#pragma unroll
    for (int bn = 0; bn < 2; ++bn)
#pragma unroll
      for (int rr = 0; rr < 4; ++rr) {
        int R = r0 + am * 16 + ((l >> 4) << 2) + rr;
        int C = c0 + bn * 16 + (l & 15);
        float y = alpha * acc[am][bn][rr];
        if (R == C) y += diag;
        outF[off + (long)R * ML + C] = y;
      }
}

// attn2 scores via MFMA: C = ql @ kl^T (K=64)
__global__ __launch_bounds__(256) void k_score_g(
    const bf16* __restrict__ A, const bf16* __restrict__ Bt, float* __restrict__ C)
{
  const int bh = blockIdx.z;
  const u16* Ab = (const u16*)A + (long)bh * ML * DHD;
  const u16* Btb = (const u16*)Bt + (long)bh * ML * DHD;
  float* Cb = C + (long)bh * SQ;
  const int t = threadIdx.x, w = t >> 6, l = t & 63;
  const int r0 = blockIdx.x * 64 + (w >> 1) * 32;
  const int c0 = blockIdx.y * 64 + (w & 1) * 32;
  f32x4 acc[2][2] = {};
#pragma unroll
  for (int ks = 0; ks < 2; ++ks) {
    bf16x8 a[2], b[2];
#pragma unroll
    for (int am = 0; am < 2; ++am)
      a[am] = *(const bf16x8*)(Ab + (long)(r0 + am * 16 + (l & 15)) * DHD + ks * 32 + (l >> 4) * 8);
#pragma unroll
    for (int bn = 0; bn < 2; ++bn)
      b[bn] = *(const bf16x8*)(Btb + (long)(c0 + bn * 16 + (l & 15)) * DHD + ks * 32 + (l >> 4) * 8);
#pragma unroll
    for (int am = 0; am < 2; ++am)
#pragma unroll
      for (int bn = 0; bn < 2; ++bn) acc[am][bn] = mfma16(a[am], b[bn], acc[am][bn]);
  }
#pragma unroll
  for (int am = 0; am < 2; ++am)
#pragma unroll
    for (int bn = 0; bn < 2; ++bn)
#pragma unroll
      for (int rr = 0; rr < 4; ++rr) {
        int R = r0 + am * 16 + ((l >> 4) << 2) + rr;
        int Cc = c0 + bn * 16 + (l & 15);
        Cb[(long)R * ML + Cc] = acc[am][bn][rr];
      }
}

// ---------------- fused attentions ----------------

__device__ __forceinline__ int pswz(int row, int col) {
  return row * 256 + ((((col >> 3) ^ (row & 7)) << 3) | (col & 7));
}

// attn3 (single-pass, no max-subtraction): t3v[bh] = softmax(ql @ k^T) @ v
__global__ __launch_bounds__(256) void k_attn3(
    const bf16* __restrict__ QL, const bf16* __restrict__ Kb,
    const bf16* __restrict__ VT, float* __restrict__ T3V)
{
  __shared__ __align__(16) u16 Pl[64 * 256];
  __shared__ float psum[4][64];
  __shared__ float lsum[64];
  const int bh = blockIdx.y;
  const int m0 = blockIdx.x * 64;
  const int t = threadIdx.x, w = t >> 6, l = t & 63;
  const u16* qlp = (const u16*)QL + (long)bh * ML * DHD;
  const u16* kp  = (const u16*)Kb + (long)bh * NPAD * DHD;
  const u16* vtp = (const u16*)VT + (long)bh * DHD * NPAD;

  bf16x8 a[4][2];
#pragma unroll
  for (int am = 0; am < 4; ++am)
#pragma unroll
    for (int ks = 0; ks < 2; ++ks)
      a[am][ks] = *(const bf16x8*)(qlp + (long)(m0 + am * 16 + (l & 15)) * DHD + ks * 32 + (l >> 4) * 8);

  float p_[16];
#pragma unroll
  for (int i = 0; i < 16; ++i) p_[i] = 0.f;
  f32x4 o[4][4] = {};

  for (int kt = 0; kt < NPAD / 256; ++kt) {
    const int kv0 = kt * 256 + w * 64;
    f32x4 s[4][4] = {};
#pragma unroll
    for (int ks = 0; ks < 2; ++ks)
#pragma unroll
      for (int bc = 0; bc < 4; ++bc) {
        bf16x8 bbv = *(const bf16x8*)(kp + (long)(kv0 + bc * 16 + (l & 15)) * DHD + ks * 32 + (l >> 4) * 8);
#pragma unroll
        for (int am = 0; am < 4; ++am) s[am][bc] = mfma16(a[am][ks], bbv, s[am][bc]);
      }
#pragma unroll
    for (int am = 0; am < 4; ++am)
#pragma unroll
      for (int bc = 0; bc < 4; ++bc)
#pragma unroll
        for (int rr = 0; rr < 4; ++rr) {
          float e = __expf(s[am][bc][rr]);
          p_[am * 4 + rr] += e;
          Pl[pswz(am * 16 + ((l >> 4) << 2) + rr, w * 64 + bc * 16 + (l & 15))] = (u16)f2b(e);
        }
    __syncthreads();
#pragma unroll
    for (int ks = 0; ks < 2; ++ks) {
      bf16x8 pa[4];
#pragma unroll
      for (int am = 0; am < 4; ++am)
        pa[am] = *(const bf16x8*)(Pl + pswz(am * 16 + (l & 15), w * 64 + ks * 32 + (l >> 4) * 8));
#pragma unroll
      for (int dn = 0; dn < 4; ++dn) {
        bf16x8 vb = *(const bf16x8*)(vtp + (long)(dn * 16 + (l & 15)) * NPAD + kt * 256 + w * 64 + ks * 32 + (l >> 4) * 8);
#pragma unroll
        for (int am = 0; am < 4; ++am) o[am][dn] = mfma16(pa[am], vb, o[am][dn]);
      }
    }
    __syncthreads();
  }
#pragma unroll
  for (int i = 0; i < 16; ++i) {
    float v = p_[i];
    v += __shfl_xor(v, 1); v += __shfl_xor(v, 2); v += __shfl_xor(v, 4); v += __shfl_xor(v, 8);
    p_[i] = v;
  }
  if ((l & 15) == 0) {
#pragma unroll
    for (int am = 0; am < 4; ++am)
#pragma unroll
      for (int rr = 0; rr < 4; ++rr)
        psum[w][am * 16 + ((l >> 4) << 2) + rr] = p_[am * 4 + rr];
  }
  __syncthreads();
  if (t < 64) lsum[t] = psum[0][t] + psum[1][t] + psum[2][t] + psum[3][t];
  __syncthreads();

  float* Obuf = (float*)Pl;
  for (int wv = 0; wv < 4; ++wv) {
    if (w == wv) {
#pragma unroll
      for (int am = 0; am < 4; ++am)
#pragma unroll
        for (int dn = 0; dn < 4; ++dn)
#pragma unroll
          for (int rr = 0; rr < 4; ++rr) {
            int row = am * 16 + ((l >> 4) << 2) + rr, col = dn * 16 + (l & 15);
            if (wv == 0) Obuf[row * 64 + col] = o[am][dn][rr];
            else         Obuf[row * 64 + col] += o[am][dn][rr];
          }
    }
    __syncthreads();
  }
  {
    int row = t >> 2, c0 = (t & 3) * 16;
    float inv = 1.0f / lsum[row];
    float* dst = T3V + ((long)bh * ML + m0 + row) * DHD + c0;
#pragma unroll
    for (int i = 0; i < 16; ++i) dst[i] = Obuf[row * 64 + c0 + i] * inv;
  }
}

// attn1: out1[bh] = softmax(q @ kl^T) @ t2m (fused, K-len 256)
__global__ __launch_bounds__(256) void k_attn1(
    const bf16* __restrict__ Qb, const bf16* __restrict__ KL,
    const short* __restrict__ T2MT, bf16* __restrict__ O1)
{
  __shared__ __align__(16) u16 Pl[64 * 256];
  __shared__ float psum[4][64];
  __shared__ float lsum[64];
  const int bh = blockIdx.y;
  const int m0 = blockIdx.x * 64;
  const int t = threadIdx.x, w = t >> 6, l = t & 63;
  const u16* qp  = (const u16*)Qb + (long)bh * NPAD * DHD;
  const u16* klp = (const u16*)KL + (long)bh * ML * DHD;
  const short* tp = T2MT + (long)bh * DHD * ML;

  bf16x8 a[4][2];
#pragma unroll
  for (int am = 0; am < 4; ++am)
#pragma unroll
    for (int ks = 0; ks < 2; ++ks)
      a[am][ks] = *(const bf16x8*)(qp + (long)(m0 + am * 16 + (l & 15)) * DHD + ks * 32 + (l >> 4) * 8);

  f32x4 s[4][4] = {};
#pragma unroll
  for (int ks = 0; ks < 2; ++ks)
#pragma unroll
    for (int bc = 0; bc < 4; ++bc) {
      bf16x8 bbv = *(const bf16x8*)(klp + (long)(w * 64 + bc * 16 + (l & 15)) * DHD + ks * 32 + (l >> 4) * 8);
#pragma unroll
      for (int am = 0; am < 4; ++am) s[am][bc] = mfma16(a[am][ks], bbv, s[am][bc]);
    }
  float p_[16];
#pragma unroll
  for (int am = 0; am < 4; ++am)
#pragma unroll
    for (int rr = 0; rr < 4; ++rr)
      p_[am * 4 + rr] = __expf(s[am][0][rr]) + __expf(s[am][1][rr])
                      + __expf(s[am][2][rr]) + __expf(s[am][3][rr]);
#pragma unroll
  for (int i = 0; i < 16; ++i) {
    float v = p_[i];
    v += __shfl_xor(v, 1); v += __shfl_xor(v, 2); v += __shfl_xor(v, 4); v += __shfl_xor(v, 8);
    p_[i] = v;
  }
  if ((l & 15) == 0) {
#pragma unroll
    for (int am = 0; am < 4; ++am)
#pragma unroll
      for (int rr = 0; rr < 4; ++rr)
        psum[w][am * 16 + ((l >> 4) << 2) + rr] = p_[am * 4 + rr];
  }
#pragma unroll
  for (int am = 0; am < 4; ++am)
#pragma unroll
    for (int bc = 0; bc < 4; ++bc)
#pragma unroll
      for (int rr = 0; rr < 4; ++rr)
        Pl[pswz(am * 16 + ((l >> 4) << 2) + rr, w * 64 + bc * 16 + (l & 15))] =
            (u16)f2b(__expf(s[am][bc][rr]));
  __syncthreads();
  if (t < 64) lsum[t] = psum[0][t] + psum[1][t] + psum[2][t] + psum[3][t];
  __syncthreads();

  f32x4 o[4][4] = {};
#pragma unroll
  for (int ks = 0; ks < 2; ++ks) {
    bf16x8 pa[4];
#pragma unroll
    for (int am = 0; am < 4; ++am)
      pa[am] = *(const bf16x8*)(Pl + pswz(am * 16 + (l & 15), w * 64 + ks * 32 + (l >> 4) * 8));
#pragma unroll
    for (int dn = 0; dn < 4; ++dn) {
      bf16x8 vb = *(const bf16x8*)((const u16*)tp + (long)(dn * 16 + (l & 15)) * ML + w * 64 + ks * 32 + (l >> 4) * 8);
#pragma unroll
      for (int am = 0; am < 4; ++am) o[am][dn] = mfma16(pa[am], vb, o[am][dn]);
    }
  }
  float* Obuf = (float*)Pl;
  __syncthreads();
  for (int wv = 0; wv < 4; ++wv) {
    if (w == wv) {
#pragma unroll
      for (int am = 0; am < 4; ++am)
#pragma unroll
        for (int dn = 0; dn < 4; ++dn)
#pragma unroll
          for (int rr = 0; rr < 4; ++rr) {
            int row = am * 16 + ((l >> 4) << 2) + rr, col = dn * 16 + (l & 15);
            if (wv == 0) Obuf[row * 64 + col] = o[am][dn][rr];
            else         Obuf[row * 64 + col] += o[am][dn][rr];
          }
    }
    __syncthreads();
  }
  {
    int row = t >> 2, c0 = (t & 3) * 16;
    float inv = 1.0f / lsum[row];
    u16* dst = (u16*)O1 + ((long)bh * NPAD + m0 + row) * DHD + c0;
    bf16x8 r0, r1;
#pragma unroll
    for (int i = 0; i < 8; ++i) {
      r0[i] = f2b(Obuf[row * 64 + c0 + i] * inv);
      r1[i] = f2b(Obuf[row * 64 + c0 + 8 + i] * inv);
    }
    *(bf16x8*)dst = r0;
    *(bf16x8*)(dst + 8) = r1;
  }
}

// ---------------- host orchestration ----------------

struct WSP {
  float *h, *a2, *Za, *t3v, *t2m, *red;
  bf16 *q, *k, *v, *vT, *ql, *kl, *lnq;
  short *pu, *wqb, *wob, *t2mT;
  short *Ab, *Zc, *Zt, *Z2, *Z2t, *xz, *w1t, *w2t;
};

static void run_translayer(const float* nw, const float* nb, const float* qkvw,
                           const float* outw, const float* outb, const float* resw,
                           WSP& w, hipStream_t s)
{
  const size_t S2 = (size_t)BH * SQ;
  short* U = w.pu;

  k_cvt<<<768, 256, 0, s>>>(qkvw, w.wqb, (long)3 * CDIM * CDIM);
  k_cvt<<<256, 256, 0, s>>>(outw, w.wob, (long)CDIM * CDIM);
  k_lnq<<<ROWS, 256, 0, s>>>(w.h, nw, nb, w.lnq);
  k_zpad<<<dim3(8, 48), 256, 0, s>>>((uint4*)w.q);
  k_mfma_qkv2<<<dim3(129, 12), 256, 0, s>>>(w.lnq, w.wqb, w.q, w.k, w.v);
  k_vT<<<dim3(NPAD / 64, BH), 256, 0, s>>>(w.v, w.vT);   // overwrites lnq (dead)

  const int lmN = BH * ML * DHD;
  k_landmark<<<(lmN + 255) / 256, 256, 0, s>>>(w.q, w.ql);
  k_landmark<<<(lmN + 255) / 256, 256, 0, s>>>(w.k, w.kl);

  // attn2 = softmax(ql @ kl^T)
  k_score_g<<<dim3(4, 4, BH), 256, 0, s>>>(w.ql, w.kl, w.a2);
  k_softmax<<<BH * ML, 256, 0, s>>>(w.a2, ML);
  k_pinv_prep<<<BH, 256, 0, s>>>(w.a2, w.red);
  k_pinv_scale<<<1, 64, 0, s>>>(w.red);

  // attn3 fused single-pass (last use of vT)
  k_attn3<<<dim3(4, BH), 256, 0, s>>>(w.ql, w.k, w.vT, w.t3v);

  // pinv: 5 bf16 MFMA iterations (scratch aliases vT region)
  const long nz = (long)BH * SQ;
  const int sg = (int)((nz + 255) / 256);
  k_tscale2<<<sg, 256, 0, s>>>(w.a2, w.red, w.Ab, w.Zc, w.Zt);
  short *Zc = w.Zc, *Zt = w.Zt, *Z2 = w.Z2, *Z2t = w.Z2t;
  for (int it = 0; it < 5; ++it) {
    k_pinv_g<<<dim3(4, 4, BH), 256, 0, s>>>(w.Ab, Zt, w.xz, 1.f, 0.f, w.w1t, -1.f, 7.f, nullptr, 0.f);
    k_pinv_g<<<dim3(4, 4, BH), 256, 0, s>>>(w.xz, w.w1t, nullptr, 0.f, 0.f, w.w2t, -1.f, 15.f, nullptr, 0.f);
    k_pinv_g<<<dim3(4, 4, BH), 256, 0, s>>>(w.xz, w.w2t, nullptr, 0.f, 0.f, w.w1t, -1.f, 13.f, nullptr, 0.f);
    k_pinv_g<<<dim3(4, 4, BH), 256, 0, s>>>(Zc, w.w1t, Z2, 0.25f, 0.f, Z2t, 0.25f, 0.f,
                                            (it == 4) ? w.Za : nullptr, 0.25f);
    short* tm;
    tm = Zc; Zc = Z2; Z2 = tm;
    tm = Zt; Zt = Z2t; Z2t = tm;
  }
  // final iteration in split-bf16 (fp32-equivalent accuracy)
  float* T0f = (float*)(U + 4 * S2);
  float* Tf2 = (float*)(U + 2 * S2);
  k_split<<<sg, 256, 0, s>>>(w.a2, 1.f, 0.f, U + 0 * S2, U + 1 * S2, nullptr, nullptr);
  k_split<<<sg, 256, 0, s>>>(w.Za, 1.f, 0.f, nullptr, nullptr, U + 2 * S2, U + 3 * S2);
  k_pinv_gs<<<dim3(4, 4, BH), 256, 0, s>>>(U + 0 * S2, U + 1 * S2, U + 2 * S2, U + 3 * S2, T0f, 1.f, 0.f);
  k_split<<<sg, 256, 0, s>>>(T0f, -1.f, 7.f, nullptr, nullptr, U + 6 * S2, U + 7 * S2);
  k_split<<<sg, 256, 0, s>>>(T0f, 1.f, 0.f, U + 0 * S2, U + 1 * S2, nullptr, nullptr);
  k_pinv_gs<<<dim3(4, 4, BH), 256, 0, s>>>(U + 0 * S2, U + 1 * S2, U + 6 * S2, U + 7 * S2, Tf2, 1.f, 0.f);
  k_split<<<sg, 256, 0, s>>>(Tf2, -1.f, 15.f, nullptr, nullptr, U + 6 * S2, U + 7 * S2);
  k_pinv_gs<<<dim3(4, 4, BH), 256, 0, s>>>(U + 0 * S2, U + 1 * S2, U + 6 * S2, U + 7 * S2, Tf2, 1.f, 0.f);
  k_split<<<sg, 256, 0, s>>>(Tf2, -1.f, 13.f, nullptr, nullptr, U + 4 * S2, U + 5 * S2);
  k_split<<<sg, 256, 0, s>>>(w.Za, 1.f, 0.f, U + 6 * S2, U + 7 * S2, nullptr, nullptr);
  k_pinv_gs<<<dim3(4, 4, BH), 256, 0, s>>>(U + 6 * S2, U + 7 * S2, U + 4 * S2, U + 5 * S2, w.Za, 0.25f, 0.f);

  // t2m = Z @ t3v ; transpose to bf16
  k_gemm_nn<<<dim3(4, 1, BH), 256, 0, s>>>(w.Za, w.t3v, w.t2m, ML, DHD, ML,
                                           SQ, (long)ML * DHD, (long)ML * DHD, 1.f, 0.f);
  k_t2mT<<<(BH * DHD * ML + 255) / 256, 256, 0, s>>>(w.t2m, w.t2mT);

  // out1 = softmax(q @ kl^T) @ t2m (fused; overwrites q)
  k_attn1<<<dim3(NPAD / 64, BH), 256, 0, s>>>(w.q, w.kl, w.t2mT, w.q);

  // out1 += depthwise res conv of v (tiled)
  k_resconv2<<<dim3(NPAD / 64, BH), 256, 0, s>>>(w.v, resw, w.q);

  // h += merge(out1) @ out_w^T + out_b
  k_mfma_out2<<<dim3(129, 4), 256, 0, s>>>(w.q, w.wob, outb, w.h);
}

extern "C" void kernel_launch(void* const* d_in, const int* in_sizes, int n_in,
                              void* d_out, int out_size, void* d_ws, size_t ws_size,
                              hipStream_t stream)
{
  const float* x      = (const float*)d_in[0];
  const float* cls    = (const float*)d_in[1];
  const float* l1nw   = (const float*)d_in[2];
  const float* l1nb   = (const float*)d_in[3];
  const float* l1qkvw = (const float*)d_in[4];
  const float* l1outw = (const float*)d_in[5];
  const float* l1outb = (const float*)d_in[6];
  const float* l1resw = (const float*)d_in[7];
  const float* l2nw   = (const float*)d_in[8];
  const float* l2nb   = (const float*)d_in[9];
  const float* l2qkvw = (const float*)d_in[10];
  const float* l2outw = (const float*)d_in[11];
  const float* l2outb = (const float*)d_in[12];
  const float* l2resw = (const float*)d_in[13];
  const float* pw7    = (const float*)d_in[14];
  const float* pb7    = (const float*)d_in[15];
  const float* pw5    = (const float*)d_in[16];
  const float* pb5    = (const float*)d_in[17];
  const float* pw3    = (const float*)d_in[18];
  const float* pb3    = (const float*)d_in[19];
  const float* fnw    = (const float*)d_in[20];
  const float* fnb    = (const float*)d_in[21];
  (void)in_sizes; (void)n_in; (void)out_size; (void)ws_size;

  float* W = (float*)d_ws;
  size_t o = 0;
  auto alloc = [&](size_t n) { float* p = W + o; o += n; return p; };
  WSP w;
  w.h = alloc((size_t)ROWS * CDIM);                        // 33.6 MB
  float* qkvr = alloc((size_t)3 * BH * NPAD * DHD / 2);    // 51.9 MB bf16
  w.q = (bf16*)qkvr;
  w.k = w.q + (size_t)BH * NPAD * DHD;
  w.v = w.k + (size_t)BH * NPAD * DHD;
  // vtr (17.3 MB) multiplexes: lnq (16.8 MB) | vT (17.3 MB) | pinv scratch (8 x 2MB units)
  float* vtr = alloc((size_t)BH * NPAD * DHD / 2);
  w.vT  = (bf16*)vtr;
  w.lnq = (bf16*)vtr;
  w.pu  = (short*)vtr;
  {
    const size_t S2 = (size_t)BH * SQ;
    w.Ab = w.pu;             w.Zc  = w.pu + S2;     w.Zt  = w.pu + 2 * S2; w.Z2 = w.pu + 3 * S2;
    w.Z2t = w.pu + 4 * S2;   w.xz  = w.pu + 5 * S2; w.w1t = w.pu + 6 * S2; w.w2t = w.pu + 7 * S2;
  }
  float* wbr = alloc((size_t)(3 * CDIM * CDIM + CDIM * CDIM) / 2);  // 2 MB bf16 weights
  w.wqb = (short*)wbr;
  w.wob = w.wqb + (size_t)3 * CDIM * CDIM;
  float* lmr = alloc((size_t)2 * BH * ML * DHD / 2);       // 1 MB bf16
  w.ql = (bf16*)lmr;
  w.kl = w.ql + (size_t)BH * ML * DHD;
  w.a2  = alloc((size_t)BH * SQ);                          // 4.2 MB
  w.Za  = alloc((size_t)BH * SQ);                          // 4.2 MB
  w.t3v = alloc((size_t)BH * ML * DHD);
  w.t2m = alloc((size_t)BH * ML * DHD);
  float* ttr = alloc((size_t)BH * ML * DHD / 2);
  w.t2mT = (short*)ttr;
  w.red = alloc(64);
  // total ~117 MB (< 121 MB proven safe)

  const long nh = (long)ROWS * CDIM;
  k_build_h<<<(int)((nh + 255) / 256), 256, 0, stream>>>(x, cls, w.h);

  run_translayer(l1nw, l1nb, l1qkvw, l1outw, l1outb, l1resw, w, stream);

  // PPEG: feat aliases q/k (34.6 MB), ofeat aliases v+vtr (34.6 MB)
  float* feat  = (float*)w.q;
  float* ofeat = (float*)w.v;
  k_ppeg_build_t<<<dim3(16, 259, BB), 256, 0, stream>>>(w.h, feat);
  k_ppeg_conv2<<<BB * CDIM, 256, 0, stream>>>(feat, pw7, pb7, pw5, pb5, pw3, pb3, ofeat);
  k_ppeg_scat_t<<<dim3(16, 256, BB), 256, 0, stream>>>(ofeat, w.h);

  run_translayer(l2nw, l2nb, l2qkvw, l2outw, l2outb, l2resw, w, stream);

  k_final_ln<<<BB, 256, 0, stream>>>(w.h, fnw, fnb, (float*)d_out);
}

// Round 7
// 1393.512 us; speedup vs baseline: 16.2733x; 1.2286x over previous
//
#include <hip/hip_runtime.h>
#include <hip/hip_bf16.h>

using bf16 = __hip_bfloat16;
typedef unsigned short u16;
typedef short bf16x8 __attribute__((ext_vector_type(8)));
typedef float f32x4 __attribute__((ext_vector_type(4)));

constexpr int BB    = 2;
constexpr int NSEQ  = 8193;
constexpr int CDIM  = 512;
constexpr int NH    = 8;
constexpr int DHD   = 64;
constexpr int ML    = 256;
constexpr int LF    = 33;
constexpr int NPAD  = 8448;
constexpr int PADL  = 255;
constexpr int ROWS  = BB * NSEQ;     // 16386
constexpr int BH    = BB * NH;       // 16
constexpr int RKS   = 33;
constexpr int HG    = 91;
constexpr int HW2   = HG * HG;       // 8281
constexpr int NPATCH = 8192;
constexpr long SQ   = (long)ML * ML; // 65536 per bh
constexpr int KSPLIT = 4;
constexpr int NKT   = NPAD / 256;    // 33

__device__ __forceinline__ float b2f(u16 u) {
  union { unsigned int i; float f; } x; x.i = (unsigned int)u << 16; return x.f;
}
__device__ __forceinline__ short f2b(float f) {
  __hip_bfloat16 h = __float2bfloat16(f);
  return *reinterpret_cast<short*>(&h);
}
__device__ __forceinline__ f32x4 mfma16(bf16x8 a, bf16x8 b, f32x4 c) {
  return __builtin_amdgcn_mfma_f32_16x16x32_bf16(a, b, c, 0, 0, 0);
}

// ---------------- small kernels ----------------

__global__ __launch_bounds__(256) void k_build_h(
    const float* __restrict__ x, const float* __restrict__ cls, float* __restrict__ h)
{
  long idx = (long)blockIdx.x * 256 + threadIdx.x;
  if (idx >= (long)ROWS * CDIM) return;
  int c = idx & 511;
  long r = idx >> 9;
  int b = (int)(r / NSEQ), i = (int)(r % NSEQ);
  h[idx] = (i == 0) ? cls[c] : x[((long)b * (NSEQ - 1) + (i - 1)) * CDIM + c];
}

__global__ __launch_bounds__(256) void k_cvt(
    const float* __restrict__ X, short* __restrict__ Y, long n)
{
  long i = (long)blockIdx.x * 256 + threadIdx.x;
  const long st = (long)gridDim.x * 256;
  for (; i < n; i += st) Y[i] = f2b(X[i]);
}

// zero the PADL pad rows of q,k,v (3 contiguous buffers)
__global__ __launch_bounds__(256) void k_zpad(uint4* __restrict__ q)
{
  const int seg = blockIdx.y;            // buf*16 + bh
  const int buf = seg >> 4, bh = seg & 15;
  const long base_e = ((long)buf * BH + bh) * ((long)NPAD * DHD);
  uint4* p = (uint4*)((u16*)q + base_e);
  const int n16 = PADL * DHD * 2 / 16;   // 2040
  for (int i = blockIdx.x * 256 + threadIdx.x; i < n16; i += gridDim.x * 256)
    p[i] = make_uint4(0u, 0u, 0u, 0u);
}

// fused LayerNorm -> bf16 output
__global__ __launch_bounds__(256) void k_lnq(
    const float* __restrict__ X, const float* __restrict__ g,
    const float* __restrict__ bb, bf16* __restrict__ Y)
{
  __shared__ float red[4];
  const long row = blockIdx.x;
  const float* x = X + row * CDIM;
  const int t = threadIdx.x;
  float a0 = x[t], a1 = x[t + 256];
  float s = a0 + a1;
  for (int o = 32; o; o >>= 1) s += __shfl_down(s, o);
  if ((t & 63) == 0) red[t >> 6] = s;
  __syncthreads();
  const float mu = (red[0] + red[1] + red[2] + red[3]) * (1.0f / CDIM);
  __syncthreads();
  float d0 = a0 - mu, d1 = a1 - mu;
  float q = d0 * d0 + d1 * d1;
  for (int o = 32; o; o >>= 1) q += __shfl_down(q, o);
  if ((t & 63) == 0) red[t >> 6] = q;
  __syncthreads();
  const float var = (red[0] + red[1] + red[2] + red[3]) * (1.0f / CDIM);
  const float rs = rsqrtf(var + 1e-5f);
  u16* y = (u16*)Y + row * CDIM;
  y[t]       = (u16)f2b(d0 * rs * g[t]       + bb[t]);
  y[t + 256] = (u16)f2b(d1 * rs * g[t + 256] + bb[t + 256]);
}

__global__ __launch_bounds__(256) void k_final_ln(
    const float* __restrict__ H, const float* __restrict__ g,
    const float* __restrict__ bb, float* __restrict__ out)
{
  __shared__ float red[4];
  const float* x = H + (long)blockIdx.x * NSEQ * CDIM;
  const int t = threadIdx.x;
  float a0 = x[t], a1 = x[t + 256];
  float s = a0 + a1;
  for (int o = 32; o; o >>= 1) s += __shfl_down(s, o);
  if ((t & 63) == 0) red[t >> 6] = s;
  __syncthreads();
  const float mu = (red[0] + red[1] + red[2] + red[3]) * (1.0f / CDIM);
  __syncthreads();
  float d0 = a0 - mu, d1 = a1 - mu;
  float q = d0 * d0 + d1 * d1;
  for (int o = 32; o; o >>= 1) q += __shfl_down(q, o);
  if ((t & 63) == 0) red[t >> 6] = q;
  __syncthreads();
  const float var = (red[0] + red[1] + red[2] + red[3]) * (1.0f / CDIM);
  const float rs = rsqrtf(var + 1e-5f);
  out[blockIdx.x * CDIM + t]       = d0 * rs * g[t]       + bb[t];
  out[blockIdx.x * CDIM + t + 256] = d1 * rs * g[t + 256] + bb[t + 256];
}

__global__ __launch_bounds__(256) void k_landmark(
    const bf16* __restrict__ src, bf16* __restrict__ dst)
{
  int idx = blockIdx.x * 256 + threadIdx.x;
  if (idx >= BH * ML * DHD) return;
  int d = idx & 63, j = (idx >> 6) & 255, bh = idx >> 14;
  const u16* p = (const u16*)src + ((long)bh * NPAD + (long)j * LF) * DHD + d;
  float s = 0.f;
#pragma unroll
  for (int t = 0; t < LF; ++t) s += b2f(p[t * DHD]);
  ((u16*)dst)[idx] = (u16)f2b(s * (1.0f / LF));
}

__global__ __launch_bounds__(256) void k_softmax(float* __restrict__ S, int W)
{
  __shared__ float buf[ML];
  __shared__ float red[4];
  float* p = S + (long)blockIdx.x * W;
  const int t = threadIdx.x;
  float mx = -3.4e38f;
  for (int j = t; j < W; j += 256) { float v = p[j]; buf[j] = v; mx = fmaxf(mx, v); }
  for (int o = 32; o; o >>= 1) mx = fmaxf(mx, __shfl_down(mx, o));
  if ((t & 63) == 0) red[t >> 6] = mx;
  __syncthreads();
  mx = fmaxf(fmaxf(red[0], red[1]), fmaxf(red[2], red[3]));
  __syncthreads();
  float sum = 0.f;
  for (int j = t; j < W; j += 256) { float e = __expf(buf[j] - mx); buf[j] = e; sum += e; }
  for (int o = 32; o; o >>= 1) sum += __shfl_down(sum, o);
  if ((t & 63) == 0) red[t >> 6] = sum;
  __syncthreads();
  const float inv = 1.0f / (red[0] + red[1] + red[2] + red[3]);
  for (int j = t; j < W; j += 256) p[j] = buf[j] * inv;
}

__global__ __launch_bounds__(256) void k_pinv_prep(
    const float* __restrict__ A, float* __restrict__ red)
{
  __shared__ float r1[4], r2[4];
  const float* Ab = A + (long)blockIdx.x * SQ;
  const int t = threadIdx.x;
  float rs = 0.f, cs = 0.f;
  for (int j = 0; j < ML; ++j) { rs += fabsf(Ab[t * ML + j]); cs += fabsf(Ab[j * ML + t]); }
  for (int o = 32; o; o >>= 1) { rs = fmaxf(rs, __shfl_down(rs, o)); cs = fmaxf(cs, __shfl_down(cs, o)); }
  if ((t & 63) == 0) { r1[t >> 6] = rs; r2[t >> 6] = cs; }
  __syncthreads();
  if (t == 0) {
    red[blockIdx.x]      = fmaxf(fmaxf(r1[0], r1[1]), fmaxf(r1[2], r1[3]));
    red[16 + blockIdx.x] = fmaxf(fmaxf(r2[0], r2[1]), fmaxf(r2[2], r2[3]));
  }
}

__global__ void k_pinv_scale(float* __restrict__ red)
{
  if (threadIdx.x == 0 && blockIdx.x == 0) {
    float cmax = red[0], rmax = red[16];
    for (int i = 1; i < 16; ++i) { cmax = fmaxf(cmax, red[i]); rmax = fmaxf(rmax, red[16 + i]); }
    red[32] = 1.0f / (cmax * rmax);
  }
}

// Ab = bf16(attn2); Zt = bf16(attn2*s) [= z0^T]; Z = bf16(attn2^T*s) [= z0]
__global__ __launch_bounds__(256) void k_tscale2(
    const float* __restrict__ A, const float* __restrict__ red,
    short* __restrict__ Ab, short* __restrict__ Z, short* __restrict__ Zt)
{
  long idx = (long)blockIdx.x * 256 + threadIdx.x;
  if (idx >= (long)BH * SQ) return;
  int c = idx & 255, r = (int)((idx >> 8) & 255);
  long bh = idx >> 16;
  float a = A[idx];
  float s = red[32];
  Ab[idx] = f2b(a);
  Zt[idx] = f2b(a * s);
  Z[(bh << 16) + ((long)c << 8) + r] = f2b(a * s);
}

// hi/lo bf16 split of (alpha*X + diag*I): optional row-major and transposed outputs
__global__ __launch_bounds__(256) void k_split(
    const float* __restrict__ X, float alpha, float diag,
    short* __restrict__ rH, short* __restrict__ rL,
    short* __restrict__ cH, short* __restrict__ cL)
{
  long idx = (long)blockIdx.x * 256 + threadIdx.x;
  if (idx >= (long)BH * SQ) return;
  int c = idx & 255, r = (int)((idx >> 8) & 255);
  long bh = idx >> 16;
  float v = alpha * X[idx] + ((r == c) ? diag : 0.f);
  short h = f2b(v);
  short lo = f2b(v - b2f((u16)h));
  if (rH) { rH[idx] = h; rL[idx] = lo; }
  if (cH) { long tix = (bh << 16) + ((long)c << 8) + r; cH[tix] = h; cL[tix] = lo; }
}

// depthwise seq-conv of v, tiled in LDS; out1 += res
__global__ __launch_bounds__(256) void k_resconv2(
    const bf16* __restrict__ v, const float* __restrict__ w, bf16* __restrict__ out)
{
  __shared__ u16 vb[96][64];
  __shared__ float ws[RKS];
  const int bh = blockIdx.y, i0 = blockIdx.x * 64;
  const int t = threadIdx.x;
  if (t < RKS) ws[t] = w[(bh & 7) * RKS + t];
  const u16* vsrc = (const u16*)v + (long)bh * NPAD * DHD;
#pragma unroll
  for (int i = 0; i < 3; ++i) {
    int chunk = t + 256 * i;
    int row = chunk >> 3, c8 = (chunk & 7) * 8;
    int vrow = i0 - 16 + row;
    bf16x8 val;
    if (vrow >= 0 && vrow < NPAD) val = *(const bf16x8*)(vsrc + (long)vrow * DHD + c8);
    else { for (int j = 0; j < 8; ++j) val[j] = 0; }
    *(bf16x8*)(&vb[row][c8]) = val;
  }
  __syncthreads();
  const int d = t & 63;
  u16* ob = (u16*)out + ((long)bh * NPAD + i0) * DHD;
#pragma unroll
  for (int j = 0; j < 16; ++j) {
    int r = (t >> 6) + j * 4;
    float s = 0.f;
#pragma unroll
    for (int k = 0; k < RKS; ++k) s += b2f(vb[r + k][d]) * ws[k];
    long oi = (long)r * DHD + d;
    ob[oi] = (u16)f2b(b2f(ob[oi]) + s);
  }
}

// row-0-only resconv (layer 2)
__global__ __launch_bounds__(256) void k_resconv_r0(
    const bf16* __restrict__ v, const float* __restrict__ w, bf16* __restrict__ out)
{
  int idx = blockIdx.x * 256 + threadIdx.x;
  if (idx >= BH * DHD) return;
  int bh = idx >> 6, d = idx & 63;
  const float* wp = w + (bh & 7) * RKS;
  const u16* vb = (const u16*)v + (long)bh * NPAD * DHD + d;
  float s = 0.f;
#pragma unroll
  for (int t = 0; t < RKS; ++t) {
    int src = PADL + t - 16;
    s += b2f(vb[(long)src * DHD]) * wp[t];
  }
  u16* ob = (u16*)out + ((long)bh * NPAD + PADL) * DHD + d;
  *ob = (u16)f2b(b2f(*ob) + s);
}

// vT[bh][d][row] = v[bh][row][d]
__global__ __launch_bounds__(256) void k_vT(const bf16* __restrict__ V, bf16* __restrict__ VT)
{
  __shared__ u16 tl[64][72];
  const int r0 = blockIdx.x * 64, bh = blockIdx.y;
  const u16* vp = (const u16*)V + ((long)bh * NPAD + r0) * DHD;
  const int t = threadIdx.x;
  {
    int r = t >> 2, c0 = (t & 3) * 16;
    bf16x8 u0 = *(const bf16x8*)(vp + (long)r * DHD + c0);
    bf16x8 u1 = *(const bf16x8*)(vp + (long)r * DHD + c0 + 8);
#pragma unroll
    for (int i = 0; i < 8; ++i) { tl[r][c0 + i] = (u16)u0[i]; tl[r][c0 + 8 + i] = (u16)u1[i]; }
  }
  __syncthreads();
  {
    int d = t >> 2, k0 = (t & 3) * 16;
    bf16x8 u0, u1;
#pragma unroll
    for (int i = 0; i < 8; ++i) { u0[i] = (short)tl[k0 + i][d]; u1[i] = (short)tl[k0 + 8 + i][d]; }
    u16* dst = (u16*)VT + ((long)bh * DHD + d) * NPAD + r0 + k0;
    *(bf16x8*)dst = u0;
    *(bf16x8*)(dst + 8) = u1;
  }
}

__global__ __launch_bounds__(256) void k_t2mT(const float* __restrict__ T2M, short* __restrict__ T2MT)
{
  int idx = blockIdx.x * 256 + threadIdx.x;
  if (idx >= BH * DHD * ML) return;
  int k = idx & 255, d = (idx >> 8) & 63, bh = idx >> 14;
  T2MT[idx] = f2b(T2M[((long)bh * ML + k) * DHD + d]);
}

// ---------------- PPEG ----------------

__global__ __launch_bounds__(256) void k_ppeg_build_t(
    const float* __restrict__ h, float* __restrict__ feat)
{
  __shared__ float tile[32][33];
  const int c0 = blockIdx.x * 32;
  const int p0 = blockIdx.y * 32;
  const int b  = blockIdx.z;
  const int t = threadIdx.x;
  const int tc = t & 31, tr8 = t >> 5;
  const int srcb = (p0 >= NPATCH) ? p0 - NPATCH : p0;
#pragma unroll
  for (int i = 0; i < 4; ++i) {
    int pp = tr8 + i * 8;
    if (p0 + pp < HW2)
      tile[pp][tc] = h[((long)b * NSEQ + 1 + srcb + pp) * CDIM + c0 + tc];
  }
  __syncthreads();
#pragma unroll
  for (int i = 0; i < 4; ++i) {
    int cc = tr8 + i * 8;
    if (p0 + tc < HW2)
      feat[((long)(b * CDIM + c0 + cc)) * HW2 + p0 + tc] = tile[tc][cc];
  }
}

__global__ __launch_bounds__(256) void k_ppeg_conv2(
    const float* __restrict__ feat,
    const float* __restrict__ w7, const float* __restrict__ b7,
    const float* __restrict__ w5, const float* __restrict__ b5,
    const float* __restrict__ w3, const float* __restrict__ b3,
    float* __restrict__ ofeat)
{
  __shared__ float P[97 * 97];
  __shared__ float ws[84];
  const int bx = blockIdx.x;       // b*512 + c
  const int c = bx & 511;
  const int t = threadIdx.x;
  for (int i = t; i < 97 * 97; i += 256) P[i] = 0.f;
  if (t < 49) ws[t] = w7[c * 49 + t];
  else if (t < 74) ws[t] = w5[c * 25 + (t - 49)];
  else if (t < 83) ws[t] = w3[c * 9 + (t - 74)];
  __syncthreads();
  const float* fp = feat + (long)bx * HW2;
  for (int i = t; i < HW2; i += 256) {
    int y = i / HG, x = i - y * HG;
    P[(y + 3) * 97 + x + 3] = fp[i];
  }
  __syncthreads();
  const float bias = b7[c] + b5[c] + b3[c];
  float* op = ofeat + (long)bx * HW2;
  for (int i = t; i < HW2; i += 256) {
    int y = i / HG, x = i - y * HG;
    const float* pc = &P[y * 97 + x];
    float s = pc[3 * 97 + 3] + bias;
#pragma unroll
    for (int dy = 0; dy < 7; ++dy)
#pragma unroll
      for (int dx = 0; dx < 7; ++dx)
        s += pc[dy * 97 + dx] * ws[dy * 7 + dx];
#pragma unroll
    for (int dy = 0; dy < 5; ++dy)
#pragma unroll
      for (int dx = 0; dx < 5; ++dx)
        s += pc[(dy + 1) * 97 + dx + 1] * ws[49 + dy * 5 + dx];
#pragma unroll
    for (int dy = 0; dy < 3; ++dy)
#pragma unroll
      for (int dx = 0; dx < 3; ++dx)
        s += pc[(dy + 2) * 97 + dx + 2] * ws[74 + dy * 3 + dx];
    op[i] = s;
  }
}

__global__ __launch_bounds__(256) void k_ppeg_scat_t(
    const float* __restrict__ ofeat, float* __restrict__ h)
{
  __shared__ float tile[32][33];
  const int c0 = blockIdx.x * 32;
  const int p0 = blockIdx.y * 32;
  const int b  = blockIdx.z;
  const int t = threadIdx.x;
  const int tc = t & 31, tr8 = t >> 5;
#pragma unroll
  for (int i = 0; i < 4; ++i) {
    int cc = tr8 + i * 8;
    tile[cc][tc] = ofeat[((long)(b * CDIM + c0 + cc)) * HW2 + p0 + tc];
  }
  __syncthreads();
#pragma unroll
  for (int i = 0; i < 4; ++i) {
    int pp = tr8 + i * 8;
    h[((long)b * NSEQ + 1 + p0 + pp) * CDIM + c0 + tc] = tile[tc][pp];
  }
}

// ---------------- fp32 GEMM (t2m only) ----------------

__global__ __launch_bounds__(256) void k_gemm_nn(
    const float* __restrict__ A, const float* __restrict__ Bm, float* __restrict__ Cm,
    int M, int N, int K, long sA, long sB, long sC, float alpha, float diag)
{
  __shared__ float As[64][17], Bs[16][68];
  const float* Ab = A + (long)blockIdx.z * sA;
  const float* Bb = Bm + (long)blockIdx.z * sB;
  float* Cb = Cm + (long)blockIdx.z * sC;
  const int m0 = blockIdx.x << 6, n0 = blockIdx.y << 6;
  const int t = threadIdx.x, ty = t >> 4, tx = t & 15;
  const int lr = t >> 2, lk = (t & 3) << 2;
  const int bk = t >> 4, bn = (t & 15) << 2;
  float acc[4][4] = {};
  for (int k0 = 0; k0 < K; k0 += 16) {
    float4 av = make_float4(0.f, 0.f, 0.f, 0.f), bv = make_float4(0.f, 0.f, 0.f, 0.f);
    if (m0 + lr < M) av = *(const float4*)(Ab + (long)(m0 + lr) * K + k0 + lk);
    if (n0 + bn < N) bv = *(const float4*)(Bb + (long)(k0 + bk) * N + n0 + bn);
    As[lr][lk] = av.x; As[lr][lk + 1] = av.y; As[lr][lk + 2] = av.z; As[lr][lk + 3] = av.w;
    Bs[bk][bn] = bv.x; Bs[bk][bn + 1] = bv.y; Bs[bk][bn + 2] = bv.z; Bs[bk][bn + 3] = bv.w;
    __syncthreads();
#pragma unroll
    for (int kk = 0; kk < 16; ++kk) {
      float a[4], b[4];
#pragma unroll
      for (int i = 0; i < 4; ++i) a[i] = As[ty * 4 + i][kk];
#pragma unroll
      for (int j = 0; j < 4; ++j) b[j] = Bs[kk][tx * 4 + j];
#pragma unroll
      for (int i = 0; i < 4; ++i)
#pragma unroll
        for (int j = 0; j < 4; ++j) acc[i][j] += a[i] * b[j];
    }
    __syncthreads();
  }
#pragma unroll
  for (int i = 0; i < 4; ++i) {
    int r = m0 + ty * 4 + i;
    if (r >= M) continue;
#pragma unroll
    for (int j = 0; j < 4; ++j) {
      int n = n0 + tx * 4 + j;
      if (n >= N) continue;
      float v = alpha * acc[i][j];
      if (r == n) v += diag;
      Cb[(long)r * N + n] = v;
    }
  }
}

// ---------------- MFMA projection GEMMs ----------------

__global__ __launch_bounds__(256) void k_mfma_qkv2(
    const bf16* __restrict__ Aq, const short* __restrict__ Wm,
    bf16* __restrict__ Q, bf16* __restrict__ Kp, bf16* __restrict__ V)
{
  __shared__ __align__(16) short As[128 * 32];
  __shared__ __align__(16) short Bs[128 * 32];
  const int m0 = blockIdx.x * 128, n0 = blockIdx.y * 128;
  const int t = threadIdx.x, w = t >> 6, l = t & 63;
  const int srow = t >> 1, skh = (t & 1) * 16;
  const int aR = m0 + srow;
  const int wR = n0 + srow;
  const int g0 = skh >> 3;
  const int sw0 = ((g0 ^ (srow & 3)) << 3), sw1 = (((g0 + 1) ^ (srow & 3)) << 3);
  const u16* ap = (const u16*)Aq;
  f32x4 acc[4][4] = {};
  for (int kt = 0; kt < 16; ++kt) {
    const int kbase = kt * 32 + skh;
    {
      bf16x8 v0, v1;
      if (aR < ROWS) {
        v0 = *(const bf16x8*)(ap + (long)aR * CDIM + kbase);
        v1 = *(const bf16x8*)(ap + (long)aR * CDIM + kbase + 8);
      } else {
#pragma unroll
        for (int i = 0; i < 8; ++i) { v0[i] = 0; v1[i] = 0; }
      }
      *(bf16x8*)(As + srow * 32 + sw0) = v0;
      *(bf16x8*)(As + srow * 32 + sw1) = v1;
    }
    {
      bf16x8 v0 = *(const bf16x8*)(Wm + (long)wR * CDIM + kbase);
      bf16x8 v1 = *(const bf16x8*)(Wm + (long)wR * CDIM + kbase + 8);
      *(bf16x8*)(Bs + srow * 32 + sw0) = v0;
      *(bf16x8*)(Bs + srow * 32 + sw1) = v1;
    }
    __syncthreads();
    const int ar0 = (w >> 1) * 64, bc0 = (w & 1) * 64;
    const int kg = l >> 4;
    bf16x8 a[4], b[4];
#pragma unroll
    for (int am = 0; am < 4; ++am) {
      int row = ar0 + am * 16 + (l & 15);
      a[am] = *(const bf16x8*)(As + row * 32 + ((kg ^ (row & 3)) << 3));
    }
#pragma unroll
    for (int bn = 0; bn < 4; ++bn) {
      int row = bc0 + bn * 16 + (l & 15);
      b[bn] = *(const bf16x8*)(Bs + row * 32 + ((kg ^ (row & 3)) << 3));
    }
#pragma unroll
    for (int am = 0; am < 4; ++am)
#pragma unroll
      for (int bn = 0; bn < 4; ++bn) acc[am][bn] = mfma16(a[am], b[bn], acc[am][bn]);
    __syncthreads();
  }
  const int ar0 = (w >> 1) * 64, bc0 = (w & 1) * 64;
#pragma unroll
  for (int am = 0; am < 4; ++am) {
#pragma unroll
    for (int rr = 0; rr < 4; ++rr) {
      int R = m0 + ar0 + am * 16 + ((l >> 4) << 2) + rr;
      if (R >= ROWS) continue;
      int b = R / NSEQ, ii = R - b * NSEQ;
#pragma unroll
      for (int bn = 0; bn < 4; ++bn) {
        int n = n0 + bc0 + bn * 16 + (l & 15);
        int which = n >> 9, rem = n & 511, hd = rem >> 6, d = rem & 63;
        float val = acc[am][bn][rr];
        if (which == 0) val *= 0.125f;
        u16* dst = (u16*)(which == 0 ? Q : (which == 1 ? Kp : V));
        dst[(((long)(b * NH + hd)) * NPAD + PADL + ii) * DHD + d] = (u16)f2b(val);
      }
    }
  }
}

__global__ __launch_bounds__(256) void k_mfma_out2(
    const bf16* __restrict__ O1, const short* __restrict__ Wm,
    const float* __restrict__ bias, float* __restrict__ Hh)
{
  __shared__ __align__(16) short As[128 * 32];
  __shared__ __align__(16) short Bs[128 * 32];
  const int m0 = blockIdx.x * 128, n0 = blockIdx.y * 128;
  const int t = threadIdx.x, w = t >> 6, l = t & 63;
  const int srow = t >> 1, skh = (t & 1) * 16;
  const int aR = m0 + srow;
  int bb = 0, ii = 0;
  if (aR < ROWS) { bb = aR / NSEQ; ii = aR - bb * NSEQ; }
  const int wR = n0 + srow;
  const int g0 = skh >> 3;
  const int sw0 = ((g0 ^ (srow & 3)) << 3), sw1 = (((g0 + 1) ^ (srow & 3)) << 3);
  const u16* o1 = (const u16*)O1;
  f32x4 acc[4][4] = {};
  for (int kt = 0; kt < 16; ++kt) {
    const int kbase = kt * 32 + skh;
    {
      bf16x8 v0, v1;
      if (aR < ROWS) {
        int hd = kbase >> 6, d0 = kbase & 63;
        const u16* src = o1 + (((long)(bb * NH + hd)) * NPAD + PADL + ii) * DHD + d0;
        v0 = *(const bf16x8*)src;
        v1 = *(const bf16x8*)(src + 8);
      } else {
#pragma unroll
        for (int i = 0; i < 8; ++i) { v0[i] = 0; v1[i] = 0; }
      }
      *(bf16x8*)(As + srow * 32 + sw0) = v0;
      *(bf16x8*)(As + srow * 32 + sw1) = v1;
    }
    {
      bf16x8 v0 = *(const bf16x8*)(Wm + (long)wR * CDIM + kbase);
      bf16x8 v1 = *(const bf16x8*)(Wm + (long)wR * CDIM + kbase + 8);
      *(bf16x8*)(Bs + srow * 32 + sw0) = v0;
      *(bf16x8*)(Bs + srow * 32 + sw1) = v1;
    }
    __syncthreads();
    const int ar0 = (w >> 1) * 64, bc0 = (w & 1) * 64;
    const int kg = l >> 4;
    bf16x8 a[4], b[4];
#pragma unroll
    for (int am = 0; am < 4; ++am) {
      int row = ar0 + am * 16 + (l & 15);
      a[am] = *(const bf16x8*)(As + row * 32 + ((kg ^ (row & 3)) << 3));
    }
#pragma unroll
    for (int bn = 0; bn < 4; ++bn) {
      int row = bc0 + bn * 16 + (l & 15);
      b[bn] = *(const bf16x8*)(Bs + row * 32 + ((kg ^ (row & 3)) << 3));
    }
#pragma unroll
    for (int am = 0; am < 4; ++am)
#pragma unroll
      for (int bn = 0; bn < 4; ++bn) acc[am][bn] = mfma16(a[am], b[bn], acc[am][bn]);
    __syncthreads();
  }
  const int ar0 = (w >> 1) * 64, bc0 = (w & 1) * 64;
#pragma unroll
  for (int am = 0; am < 4; ++am) {
#pragma unroll
    for (int rr = 0; rr < 4; ++rr) {
      int R = m0 + ar0 + am * 16 + ((l >> 4) << 2) + rr;
      if (R >= ROWS) continue;
      float* hrow = Hh + (long)R * CDIM;
#pragma unroll
      for (int bn = 0; bn < 4; ++bn) {
        int n = n0 + bc0 + bn * 16 + (l & 15);
        hrow[n] += acc[am][bn][rr] + bias[n];
      }
    }
  }
}

// row-0-only out projection (layer 2): h[b,0,:] += merged(out1 row0) @ W^T + bias
__global__ __launch_bounds__(256) void k_out_r0(
    const bf16* __restrict__ O1, const short* __restrict__ Wm,
    const float* __restrict__ bias, float* __restrict__ Hh)
{
  __shared__ float mrow[CDIM];
  const int b = blockIdx.x, t = threadIdx.x;
  for (int c = t; c < CDIM; c += 256)
    mrow[c] = b2f(((const u16*)O1)[(((long)(b * NH + (c >> 6))) * NPAD + PADL) * DHD + (c & 63)]);
  __syncthreads();
  for (int n = t; n < CDIM; n += 256) {
    float s = 0.f;
    const u16* wr = (const u16*)Wm + (long)n * CDIM;
    for (int k = 0; k < CDIM; ++k) s += mrow[k] * b2f(wr[k]);
    Hh[(long)b * NSEQ * CDIM + n] += s + bias[n];
  }
}

// ---------------- batched pinv MFMA GEMMs ----------------

__global__ __launch_bounds__(256) void k_pinv_g(
    const short* __restrict__ A, const short* __restrict__ Bt,
    short* __restrict__ outN, float aN, float dN,
    short* __restrict__ outT, float aT, float dT,
    float* __restrict__ outF, float aF)
{
  const int bh = blockIdx.z;
  const long off = (long)bh * SQ;
  const short* Ab = A + off;
  const short* Btb = Bt + off;
  const int t = threadIdx.x, w = t >> 6, l = t & 63;
  const int r0 = blockIdx.x * 64 + (w >> 1) * 32;
  const int c0 = blockIdx.y * 64 + (w & 1) * 32;
  f32x4 acc[2][2] = {};
#pragma unroll
  for (int ks = 0; ks < 8; ++ks) {
    bf16x8 a[2], b[2];
#pragma unroll
    for (int am = 0; am < 2; ++am)
      a[am] = *(const bf16x8*)(Ab + (long)(r0 + am * 16 + (l & 15)) * ML + ks * 32 + (l >> 4) * 8);
#pragma unroll
    for (int bn = 0; bn < 2; ++bn)
      b[bn] = *(const bf16x8*)(Btb + (long)(c0 + bn * 16 + (l & 15)) * ML + ks * 32 + (l >> 4) * 8);
#pragma unroll
    for (int am = 0; am < 2; ++am)
#pragma unroll
      for (int bn = 0; bn < 2; ++bn) acc[am][bn] = mfma16(a[am], b[bn], acc[am][bn]);
  }
#pragma unroll
  for (int am = 0; am < 2; ++am)
#pragma unroll
    for (int bn = 0; bn < 2; ++bn)
#pragma unroll
      for (int rr = 0; rr < 4; ++rr) {
        int R = r0 + am * 16 + ((l >> 4) << 2) + rr;
        int C = c0 + bn * 16 + (l & 15);
        float x = acc[am][bn][rr];
        float dg = (R == C) ? 1.f : 0.f;
        if (outN) outN[off + (long)R * ML + C] = f2b(aN * x + dN * dg);
        if (outT) outT[off + (long)C * ML + R] = f2b(aT * x + dT * dg);
        if (outF) outF[off + (long)R * ML + C] = aF * x;
      }
}

__global__ __launch_bounds__(256) void k_pinv_gs(
    const short* __restrict__ Ah, const short* __restrict__ Al,
    const short* __restrict__ BhT, const short* __restrict__ BlT,
    float* __restrict__ outF, float alpha, float diag)
{
  const int bh = blockIdx.z;
  const long off = (long)bh * SQ;
  const int t = threadIdx.x, w = t >> 6, l = t & 63;
  const int r0 = blockIdx.x * 64 + (w >> 1) * 32;
  const int c0 = blockIdx.y * 64 + (w & 1) * 32;
  f32x4 acc[2][2] = {};
#pragma unroll
  for (int ks = 0; ks < 8; ++ks) {
    bf16x8 ah[2], al[2], bh_[2], bl[2];
#pragma unroll
    for (int am = 0; am < 2; ++am) {
      long base = off + (long)(r0 + am * 16 + (l & 15)) * ML + ks * 32 + (l >> 4) * 8;
      ah[am] = *(const bf16x8*)(Ah + base);
      al[am] = *(const bf16x8*)(Al + base);
    }
#pragma unroll
    for (int bn = 0; bn < 2; ++bn) {
      long base = off + (long)(c0 + bn * 16 + (l & 15)) * ML + ks * 32 + (l >> 4) * 8;
      bh_[bn] = *(const bf16x8*)(BhT + base);
      bl[bn] = *(const bf16x8*)(BlT + base);
    }
#pragma unroll
    for (int am = 0; am < 2; ++am)
#pragma unroll
      for (int bn = 0; bn < 2; ++bn) {
        acc[am][bn] = mfma16(ah[am], bh_[bn], acc[am][bn]);
        acc[am][bn] = mfma16(ah[am], bl[bn], acc[am][bn]);
        acc[am][bn] = mfma16(al[am], bh_[bn], acc[am][bn]);
      }
  }
#pragma unroll
  for (int am = 0; am < 2; ++am)
#pragma unroll
    for (int bn = 0; bn < 2; ++bn)
#pragma unroll
      for (int rr = 0; rr < 4; ++rr) {
        int R = r0 + am * 16 + ((l >> 4) << 2) + rr;
        int C = c0 + bn * 16 + (l & 15);
        float y = alpha * acc[am][bn][rr];
        if (R == C) y += diag;
        outF[off + (long)R * ML + C] = y;
      }
}

__global__ __launch_bounds__(256) void k_score_g(
    const bf16* __restrict__ A, const bf16* __restrict__ Bt, float* __restrict__ C)
{
  const int bh = blockIdx.z;
  const u16* Ab = (const u16*)A + (long)bh * ML * DHD;
  const u16* Btb = (const u16*)Bt + (long)bh * ML * DHD;
  float* Cb = C + (long)bh * SQ;
  const int t = threadIdx.x, w = t >> 6, l = t & 63;
  const int r0 = blockIdx.x * 64 + (w >> 1) * 32;
  const int c0 = blockIdx.y * 64 + (w & 1) * 32;
  f32x4 acc[2][2] = {};
#pragma unroll
  for (int ks = 0; ks < 2; ++ks) {
    bf16x8 a[2], b[2];
#pragma unroll
    for (int am = 0; am < 2; ++am)
      a[am] = *(const bf16x8*)(Ab + (long)(r0 + am * 16 + (l & 15)) * DHD + ks * 32 + (l >> 4) * 8);
#pragma unroll
    for (int bn = 0; bn < 2; ++bn)
      b[bn] = *(const bf16x8*)(Btb + (long)(c0 + bn * 16 + (l & 15)) * DHD + ks * 32 + (l >> 4) * 8);
#pragma unroll
    for (int am = 0; am < 2; ++am)
#pragma unroll
      for (int bn = 0; bn < 2; ++bn) acc[am][bn] = mfma16(a[am], b[bn], acc[am][bn]);
  }
#pragma unroll
  for (int am = 0; am < 2; ++am)
#pragma unroll
    for (int bn = 0; bn < 2; ++bn)
#pragma unroll
      for (int rr = 0; rr < 4; ++rr) {
        int R = r0 + am * 16 + ((l >> 4) << 2) + rr;
        int Cc = c0 + bn * 16 + (l & 15);
        Cb[(long)R * ML + Cc] = acc[am][bn][rr];
      }
}

// ---------------- fused attentions ----------------

__device__ __forceinline__ int pswz(int row, int col) {
  return row * 256 + ((((col >> 3) ^ (row & 7)) << 3) | (col & 7));
}

// attn3 split: partial softmax(ql@k^T)@v over a KV chunk. 32-row tiles.
// po[(bh*8+mblk)*KSPLIT+s][32][64] unnormalized; pl[...][32] partial denominators.
__global__ __launch_bounds__(256) void k_attn3s(
    const bf16* __restrict__ QL, const bf16* __restrict__ Kb,
    const bf16* __restrict__ VT, float* __restrict__ po, float* __restrict__ pl)
{
  __shared__ __align__(16) u16 Pl[32 * 256];
  __shared__ float psum[4][32];
  __shared__ float lsum[32];
  const int bh = blockIdx.z;
  const int m0 = blockIdx.x * 32;
  const int s  = blockIdx.y;
  const int kt0 = (NKT * s) / KSPLIT, kt1 = (NKT * (s + 1)) / KSPLIT;
  const int t = threadIdx.x, w = t >> 6, l = t & 63;
  const u16* qlp = (const u16*)QL + (long)bh * ML * DHD;
  const u16* kp  = (const u16*)Kb + (long)bh * NPAD * DHD;
  const u16* vtp = (const u16*)VT + (long)bh * DHD * NPAD;

  bf16x8 a[2][2];
#pragma unroll
  for (int am = 0; am < 2; ++am)
#pragma unroll
    for (int ks = 0; ks < 2; ++ks)
      a[am][ks] = *(const bf16x8*)(qlp + (long)(m0 + am * 16 + (l & 15)) * DHD + ks * 32 + (l >> 4) * 8);

  float p_[8];
#pragma unroll
  for (int i = 0; i < 8; ++i) p_[i] = 0.f;
  f32x4 o[2][4] = {};

  for (int kt = kt0; kt < kt1; ++kt) {
    const int kv0 = kt * 256 + w * 64;
    f32x4 sa[2][4] = {};
#pragma unroll
    for (int ks = 0; ks < 2; ++ks)
#pragma unroll
      for (int bc = 0; bc < 4; ++bc) {
        bf16x8 bbv = *(const bf16x8*)(kp + (long)(kv0 + bc * 16 + (l & 15)) * DHD + ks * 32 + (l >> 4) * 8);
#pragma unroll
        for (int am = 0; am < 2; ++am) sa[am][bc] = mfma16(a[am][ks], bbv, sa[am][bc]);
      }
#pragma unroll
    for (int am = 0; am < 2; ++am)
#pragma unroll
      for (int bc = 0; bc < 4; ++bc)
#pragma unroll
        for (int rr = 0; rr < 4; ++rr) {
          float e = __expf(sa[am][bc][rr]);
          p_[am * 4 + rr] += e;
          Pl[pswz(am * 16 + ((l >> 4) << 2) + rr, w * 64 + bc * 16 + (l & 15))] = (u16)f2b(e);
        }
    __syncthreads();
#pragma unroll
    for (int ks = 0; ks < 2; ++ks) {
      bf16x8 pa[2];
#pragma unroll
      for (int am = 0; am < 2; ++am)
        pa[am] = *(const bf16x8*)(Pl + pswz(am * 16 + (l & 15), w * 64 + ks * 32 + (l >> 4) * 8));
#pragma unroll
      for (int dn = 0; dn < 4; ++dn) {
        bf16x8 vb = *(const bf16x8*)(vtp + (long)(dn * 16 + (l & 15)) * NPAD + kt * 256 + w * 64 + ks * 32 + (l >> 4) * 8);
#pragma unroll
        for (int am = 0; am < 2; ++am) o[am][dn] = mfma16(pa[am], vb, o[am][dn]);
      }
    }
    __syncthreads();
  }
#pragma unroll
  for (int i = 0; i < 8; ++i) {
    float v = p_[i];
    v += __shfl_xor(v, 1); v += __shfl_xor(v, 2); v += __shfl_xor(v, 4); v += __shfl_xor(v, 8);
    p_[i] = v;
  }
  if ((l & 15) == 0) {
#pragma unroll
    for (int am = 0; am < 2; ++am)
#pragma unroll
      for (int rr = 0; rr < 4; ++rr)
        psum[w][am * 16 + ((l >> 4) << 2) + rr] = p_[am * 4 + rr];
  }
  __syncthreads();
  if (t < 32) lsum[t] = psum[0][t] + psum[1][t] + psum[2][t] + psum[3][t];
  __syncthreads();

  float* Obuf = (float*)Pl;   // 32*64 fp32 = 8KB, fits in Pl (16KB)
  for (int wv = 0; wv < 4; ++wv) {
    if (w == wv) {
#pragma unroll
      for (int am = 0; am < 2; ++am)
#pragma unroll
        for (int dn = 0; dn < 4; ++dn)
#pragma unroll
          for (int rr = 0; rr < 4; ++rr) {
            int row = am * 16 + ((l >> 4) << 2) + rr, col = dn * 16 + (l & 15);
            if (wv == 0) Obuf[row * 64 + col] = o[am][dn][rr];
            else         Obuf[row * 64 + col] += o[am][dn][rr];
          }
    }
    __syncthreads();
  }
  const long pbase = (long)(bh * 8 + blockIdx.x) * KSPLIT + s;
#pragma unroll
  for (int i = 0; i < 8; ++i) {
    int idx2 = t * 8 + i;
    po[pbase * 2048 + idx2] = Obuf[idx2];
  }
  if (t < 32) pl[pbase * 32 + t] = lsum[t];
}

// reduce partials -> t3v
__global__ __launch_bounds__(256) void k_attn3r(
    const float* __restrict__ po, const float* __restrict__ pl, float* __restrict__ T3V)
{
  int idx = blockIdx.x * 256 + threadIdx.x;
  if (idx >= BH * ML * DHD) return;
  int d = idx & 63, row = (idx >> 6) & 255, bh = idx >> 14;
  int mb = row >> 5, r = row & 31;
  long p0 = (long)(bh * 8 + mb) * KSPLIT;
  float o = 0.f, ll = 0.f;
#pragma unroll
  for (int s = 0; s < KSPLIT; ++s) {
    o  += po[(p0 + s) * 2048 + r * 64 + d];
    ll += pl[(p0 + s) * 32 + r];
  }
  T3V[idx] = o / ll;
}

// attn1: out1[bh] = softmax(q @ kl^T) @ t2m (fused, K-len 256) — layer 1 (all rows)
__global__ __launch_bounds__(256) void k_attn1(
    const bf16* __restrict__ Qb, const bf16* __restrict__ KL,
    const short* __restrict__ T2MT, bf16* __restrict__ O1)
{
  __shared__ __align__(16) u16 Pl[64 * 256];
  __shared__ float psum[4][64];
  __shared__ float lsum[64];
  const int bh = blockIdx.y;
  const int m0 = blockIdx.x * 64;
  const int t = threadIdx.x, w = t >> 6, l = t & 63;
  const u16* qp  = (const u16*)Qb + (long)bh * NPAD * DHD;
  const u16* klp = (const u16*)KL + (long)bh * ML * DHD;
  const short* tp = T2MT + (long)bh * DHD * ML;

  bf16x8 a[4][2];
#pragma unroll
  for (int am = 0; am < 4; ++am)
#pragma unroll
    for (int ks = 0; ks < 2; ++ks)
      a[am][ks] = *(const bf16x8*)(qp + (long)(m0 + am * 16 + (l & 15)) * DHD + ks * 32 + (l >> 4) * 8);

  f32x4 s[4][4] = {};
#pragma unroll
  for (int ks = 0; ks < 2; ++ks)
#pragma unroll
    for (int bc = 0; bc < 4; ++bc) {
      bf16x8 bbv = *(const bf16x8*)(klp + (long)(w * 64 + bc * 16 + (l & 15)) * DHD + ks * 32 + (l >> 4) * 8);
#pragma unroll
      for (int am = 0; am < 4; ++am) s[am][bc] = mfma16(a[am][ks], bbv, s[am][bc]);
    }
  float p_[16];
#pragma unroll
  for (int am = 0; am < 4; ++am)
#pragma unroll
    for (int rr = 0; rr < 4; ++rr)
      p_[am * 4 + rr] = __expf(s[am][0][rr]) + __expf(s[am][1][rr])
                      + __expf(s[am][2][rr]) + __expf(s[am][3][rr]);
#pragma unroll
  for (int i = 0; i < 16; ++i) {
    float v = p_[i];
    v += __shfl_xor(v, 1); v += __shfl_xor(v, 2); v += __shfl_xor(v, 4); v += __shfl_xor(v, 8);
    p_[i] = v;
  }
  if ((l & 15) == 0) {
#pragma unroll
    for (int am = 0; am < 4; ++am)
#pragma unroll
      for (int rr = 0; rr < 4; ++rr)
        psum[w][am * 16 + ((l >> 4) << 2) + rr] = p_[am * 4 + rr];
  }
#pragma unroll
  for (int am = 0; am < 4; ++am)
#pragma unroll
    for (int bc = 0; bc < 4; ++bc)
#pragma unroll
      for (int rr = 0; rr < 4; ++rr)
        Pl[pswz(am * 16 + ((l >> 4) << 2) + rr, w * 64 + bc * 16 + (l & 15))] =
            (u16)f2b(__expf(s[am][bc][rr]));
  __syncthreads();
  if (t < 64) lsum[t] = psum[0][t] + psum[1][t] + psum[2][t] + psum[3][t];
  __syncthreads();

  f32x4 o[4][4] = {};
#pragma unroll
  for (int ks = 0; ks < 2; ++ks) {
    bf16x8 pa[4];
#pragma unroll
    for (int am = 0; am < 4; ++am)
      pa[am] = *(const bf16x8*)(Pl + pswz(am * 16 + (l & 15), w * 64 + ks * 32 + (l >> 4) * 8));
#pragma unroll
    for (int dn = 0; dn < 4; ++dn) {
      bf16x8 vb = *(const bf16x8*)((const u16*)tp + (long)(dn * 16 + (l & 15)) * ML + w * 64 + ks * 32 + (l >> 4) * 8);
#pragma unroll
      for (int am = 0; am < 4; ++am) o[am][dn] = mfma16(pa[am], vb, o[am][dn]);
    }
  }
  float* Obuf = (float*)Pl;
  __syncthreads();
  for (int wv = 0; wv < 4; ++wv) {
    if (w == wv) {
#pragma unroll
      for (int am = 0; am < 4; ++am)
#pragma unroll
        for (int dn = 0; dn < 4; ++dn)
#pragma unroll
          for (int rr = 0; rr < 4; ++rr) {
            int row = am * 16 + ((l >> 4) << 2) + rr, col = dn * 16 + (l & 15);
            if (wv == 0) Obuf[row * 64 + col] = o[am][dn][rr];
            else         Obuf[row * 64 + col] += o[am][dn][rr];
          }
    }
    __syncthreads();
  }
  {
    int row = t >> 2, c0 = (t & 3) * 16;
    float inv = 1.0f / lsum[row];
    u16* dst = (u16*)O1 + ((long)bh * NPAD + m0 + row) * DHD + c0;
    bf16x8 r0, r1;
#pragma unroll
    for (int i = 0; i < 8; ++i) {
      r0[i] = f2b(Obuf[row * 64 + c0 + i] * inv);
      r1[i] = f2b(Obuf[row * 64 + c0 + 8 + i] * inv);
    }
    *(bf16x8*)dst = r0;
    *(bf16x8*)(dst + 8) = r1;
  }
}

// row-0-only attn1 (layer 2): one block per bh
__global__ __launch_bounds__(256) void k_attn1_r0(
    const bf16* __restrict__ Qb, const bf16* __restrict__ KL,
    const float* __restrict__ T2M, bf16* __restrict__ O1)
{
  __shared__ float qrow[DHD];
  __shared__ float p[ML];
  __shared__ float red[4];
  __shared__ float ored[4][DHD];
  const int bh = blockIdx.x, t = threadIdx.x;
  const u16* qp = (const u16*)Qb + ((long)bh * NPAD + PADL) * DHD;
  if (t < DHD) qrow[t] = b2f(qp[t]);
  __syncthreads();
  // score for landmark j = t
  const u16* klp = (const u16*)KL + (long)bh * ML * DHD;
  float sj = 0.f;
  for (int d = 0; d < DHD; ++d) sj += qrow[d] * b2f(klp[t * DHD + d]);
  float e = __expf(sj);
  p[t] = e;
  float sum = e;
  for (int o = 32; o; o >>= 1) sum += __shfl_down(sum, o);
  if ((t & 63) == 0) red[t >> 6] = sum;
  __syncthreads();
  const float inv = 1.0f / (red[0] + red[1] + red[2] + red[3]);
  // out[d] = sum_j p[j] * t2m[j][d]
  const float* tm = T2M + (long)bh * ML * DHD;
  const int part = t >> 6, d = t & 63;
  float acc = 0.f;
  for (int j = part * 64; j < part * 64 + 64; ++j) acc += p[j] * tm[(long)j * DHD + d];
  ored[part][d] = acc;
  __syncthreads();
  if (t < DHD) {
    float v = (ored[0][t] + ored[1][t] + ored[2][t] + ored[3][t]) * inv;
    ((u16*)O1)[((long)bh * NPAD + PADL) * DHD + t] = (u16)f2b(v);
  }
}

// ---------------- host orchestration ----------------

struct WSP {
  float *h, *a2, *Za, *t3v, *t2m, *red, *pl;
  bf16 *q, *k, *v, *vT, *ql, *kl, *lnq;
  short *pu, *wqb, *wob, *t2mT;
  short *Ab, *Zc, *Zt, *Z2, *Z2t, *xz, *w1t, *w2t;
};

static void run_translayer(const float* nw, const float* nb, const float* qkvw,
                           const float* outw, const float* outb, const float* resw,
                           WSP& w, hipStream_t s, bool row0)
{
  const size_t S2 = (size_t)BH * SQ;
  short* U = w.pu;

  k_cvt<<<768, 256, 0, s>>>(qkvw, w.wqb, (long)3 * CDIM * CDIM);
  k_cvt<<<256, 256, 0, s>>>(outw, w.wob, (long)CDIM * CDIM);
  k_lnq<<<ROWS, 256, 0, s>>>(w.h, nw, nb, w.lnq);
  k_zpad<<<dim3(8, 48), 256, 0, s>>>((uint4*)w.q);
  k_mfma_qkv2<<<dim3(129, 12), 256, 0, s>>>(w.lnq, w.wqb, w.q, w.k, w.v);
  k_vT<<<dim3(NPAD / 64, BH), 256, 0, s>>>(w.v, w.vT);   // overwrites lnq (dead)

  const int lmN = BH * ML * DHD;
  k_landmark<<<(lmN + 255) / 256, 256, 0, s>>>(w.q, w.ql);
  k_landmark<<<(lmN + 255) / 256, 256, 0, s>>>(w.k, w.kl);

  // attn2 = softmax(ql @ kl^T)
  k_score_g<<<dim3(4, 4, BH), 256, 0, s>>>(w.ql, w.kl, w.a2);
  k_softmax<<<BH * ML, 256, 0, s>>>(w.a2, ML);
  k_pinv_prep<<<BH, 256, 0, s>>>(w.a2, w.red);
  k_pinv_scale<<<1, 64, 0, s>>>(w.red);

  // attn3 split-KV (partials in Za region, which is dead until pinv it==4)
  k_attn3s<<<dim3(8, KSPLIT, BH), 256, 0, s>>>(w.ql, w.k, w.vT, w.Za, w.pl);
  k_attn3r<<<(BH * ML * DHD + 255) / 256, 256, 0, s>>>(w.Za, w.pl, w.t3v);

  // pinv: 5 bf16 MFMA iterations (scratch aliases vT region; vT dead after attn3s)
  const long nz = (long)BH * SQ;
  const int sg = (int)((nz + 255) / 256);
  k_tscale2<<<sg, 256, 0, s>>>(w.a2, w.red, w.Ab, w.Zc, w.Zt);
  short *Zc = w.Zc, *Zt = w.Zt, *Z2 = w.Z2, *Z2t = w.Z2t;
  for (int it = 0; it < 5; ++it) {
    k_pinv_g<<<dim3(4, 4, BH), 256, 0, s>>>(w.Ab, Zt, w.xz, 1.f, 0.f, w.w1t, -1.f, 7.f, nullptr, 0.f);
    k_pinv_g<<<dim3(4, 4, BH), 256, 0, s>>>(w.xz, w.w1t, nullptr, 0.f, 0.f, w.w2t, -1.f, 15.f, nullptr, 0.f);
    k_pinv_g<<<dim3(4, 4, BH), 256, 0, s>>>(w.xz, w.w2t, nullptr, 0.f, 0.f, w.w1t, -1.f, 13.f, nullptr, 0.f);
    k_pinv_g<<<dim3(4, 4, BH), 256, 0, s>>>(Zc, w.w1t, Z2, 0.25f, 0.f, Z2t, 0.25f, 0.f,
                                            (it == 4) ? w.Za : nullptr, 0.25f);
    short* tm;
    tm = Zc; Zc = Z2; Z2 = tm;
    tm = Zt; Zt = Z2t; Z2t = tm;
  }
  // final iteration in split-bf16 (fp32-equivalent accuracy)
  float* T0f = (float*)(U + 4 * S2);
  float* Tf2 = (float*)(U + 2 * S2);
  k_split<<<sg, 256, 0, s>>>(w.a2, 1.f, 0.f, U + 0 * S2, U + 1 * S2, nullptr, nullptr);
  k_split<<<sg, 256, 0, s>>>(w.Za, 1.f, 0.f, nullptr, nullptr, U + 2 * S2, U + 3 * S2);
  k_pinv_gs<<<dim3(4, 4, BH), 256, 0, s>>>(U + 0 * S2, U + 1 * S2, U + 2 * S2, U + 3 * S2, T0f, 1.f, 0.f);
  k_split<<<sg, 256, 0, s>>>(T0f, -1.f, 7.f, nullptr, nullptr, U + 6 * S2, U + 7 * S2);
  k_split<<<sg, 256, 0, s>>>(T0f, 1.f, 0.f, U + 0 * S2, U + 1 * S2, nullptr, nullptr);
  k_pinv_gs<<<dim3(4, 4, BH), 256, 0, s>>>(U + 0 * S2, U + 1 * S2, U + 6 * S2, U + 7 * S2, Tf2, 1.f, 0.f);
  k_split<<<sg, 256, 0, s>>>(Tf2, -1.f, 15.f, nullptr, nullptr, U + 6 * S2, U + 7 * S2);
  k_pinv_gs<<<dim3(4, 4, BH), 256, 0, s>>>(U + 0 * S2, U + 1 * S2, U + 6 * S2, U + 7 * S2, Tf2, 1.f, 0.f);
  k_split<<<sg, 256, 0, s>>>(Tf2, -1.f, 13.f, nullptr, nullptr, U + 4 * S2, U + 5 * S2);
  k_split<<<sg, 256, 0, s>>>(w.Za, 1.f, 0.f, U + 6 * S2, U + 7 * S2, nullptr, nullptr);
  k_pinv_gs<<<dim3(4, 4, BH), 256, 0, s>>>(U + 6 * S2, U + 7 * S2, U + 4 * S2, U + 5 * S2, w.Za, 0.25f, 0.f);

  // t2m = Z @ t3v
  k_gemm_nn<<<dim3(4, 1, BH), 256, 0, s>>>(w.Za, w.t3v, w.t2m, ML, DHD, ML,
                                           SQ, (long)ML * DHD, (long)ML * DHD, 1.f, 0.f);

  if (!row0) {
    k_t2mT<<<(BH * DHD * ML + 255) / 256, 256, 0, s>>>(w.t2m, w.t2mT);
    k_attn1<<<dim3(NPAD / 64, BH), 256, 0, s>>>(w.q, w.kl, w.t2mT, w.q);
    k_resconv2<<<dim3(NPAD / 64, BH), 256, 0, s>>>(w.v, resw, w.q);
    k_mfma_out2<<<dim3(129, 4), 256, 0, s>>>(w.q, w.wob, outb, w.h);
  } else {
    // only h[:,0] is consumed downstream
    k_attn1_r0<<<BH, 256, 0, s>>>(w.q, w.kl, w.t2m, w.q);
    k_resconv_r0<<<(BH * DHD + 255) / 256, 256, 0, s>>>(w.v, resw, w.q);
    k_out_r0<<<BB, 256, 0, s>>>(w.q, w.wob, outb, w.h);
  }
}

extern "C" void kernel_launch(void* const* d_in, const int* in_sizes, int n_in,
                              void* d_out, int out_size, void* d_ws, size_t ws_size,
                              hipStream_t stream)
{
  const float* x      = (const float*)d_in[0];
  const float* cls    = (const float*)d_in[1];
  const float* l1nw   = (const float*)d_in[2];
  const float* l1nb   = (const float*)d_in[3];
  const float* l1qkvw = (const float*)d_in[4];
  const float* l1outw = (const float*)d_in[5];
  const float* l1outb = (const float*)d_in[6];
  const float* l1resw = (const float*)d_in[7];
  const float* l2nw   = (const float*)d_in[8];
  const float* l2nb   = (const float*)d_in[9];
  const float* l2qkvw = (const float*)d_in[10];
  const float* l2outw = (const float*)d_in[11];
  const float* l2outb = (const float*)d_in[12];
  const float* l2resw = (const float*)d_in[13];
  const float* pw7    = (const float*)d_in[14];
  const float* pb7    = (const float*)d_in[15];
  const float* pw5    = (const float*)d_in[16];
  const float* pb5    = (const float*)d_in[17];
  const float* pw3    = (const float*)d_in[18];
  const float* pb3    = (const float*)d_in[19];
  const float* fnw    = (const float*)d_in[20];
  const float* fnb    = (const float*)d_in[21];
  (void)in_sizes; (void)n_in; (void)out_size; (void)ws_size;

  float* W = (float*)d_ws;
  size_t o = 0;
  auto alloc = [&](size_t n) { float* p = W + o; o += n; return p; };
  WSP w;
  w.h = alloc((size_t)ROWS * CDIM);                        // 33.6 MB
  float* qkvr = alloc((size_t)3 * BH * NPAD * DHD / 2);    // 51.9 MB bf16
  w.q = (bf16*)qkvr;
  w.k = w.q + (size_t)BH * NPAD * DHD;
  w.v = w.k + (size_t)BH * NPAD * DHD;
  // vtr (17.3 MB) multiplexes: lnq (16.8 MB) | vT (17.3 MB) | pinv scratch
  float* vtr = alloc((size_t)BH * NPAD * DHD / 2);
  w.vT  = (bf16*)vtr;
  w.lnq = (bf16*)vtr;
  w.pu  = (short*)vtr;
  {
    const size_t S2 = (size_t)BH * SQ;
    w.Ab = w.pu;             w.Zc  = w.pu + S2;     w.Zt  = w.pu + 2 * S2; w.Z2 = w.pu + 3 * S2;
    w.Z2t = w.pu + 4 * S2;   w.xz  = w.pu + 5 * S2; w.w1t = w.pu + 6 * S2; w.w2t = w.pu + 7 * S2;
  }
  float* wbr = alloc((size_t)(3 * CDIM * CDIM + CDIM * CDIM) / 2);  // 2 MB bf16 weights
  w.wqb = (short*)wbr;
  w.wob = w.wqb + (size_t)3 * CDIM * CDIM;
  float* lmr = alloc((size_t)2 * BH * ML * DHD / 2);       // 1 MB bf16
  w.ql = (bf16*)lmr;
  w.kl = w.ql + (size_t)BH * ML * DHD;
  w.a2  = alloc((size_t)BH * SQ);                          // 4.2 MB
  w.Za  = alloc((size_t)BH * SQ);                          // 4.2 MB (also attn3 partials)
  w.t3v = alloc((size_t)BH * ML * DHD);
  w.t2m = alloc((size_t)BH * ML * DHD);
  float* ttr = alloc((size_t)BH * ML * DHD / 2);
  w.t2mT = (short*)ttr;
  w.pl  = alloc((size_t)BH * 8 * KSPLIT * 32);             // 64 KB partial denominators
  w.red = alloc(64);
  // total ~117 MB (< 121 MB proven safe)

  const long nh = (long)ROWS * CDIM;
  k_build_h<<<(int)((nh + 255) / 256), 256, 0, stream>>>(x, cls, w.h);

  run_translayer(l1nw, l1nb, l1qkvw, l1outw, l1outb, l1resw, w, stream, false);

  // PPEG: feat aliases q/k (34.6 MB), ofeat aliases v+vtr (34.6 MB)
  float* feat  = (float*)w.q;
  float* ofeat = (float*)w.v;
  k_ppeg_build_t<<<dim3(16, 259, BB), 256, 0, stream>>>(w.h, feat);
  k_ppeg_conv2<<<BB * CDIM, 256, 0, stream>>>(feat, pw7, pb7, pw5, pb5, pw3, pb3, ofeat);
  k_ppeg_scat_t<<<dim3(16, 256, BB), 256, 0, stream>>>(ofeat, w.h);

  run_translayer(l2nw, l2nb, l2qkvw, l2outw, l2outb, l2resw, w, stream, true);

  k_final_ln<<<BB, 256, 0, stream>>>(w.h, fnw, fnb, (float*)d_out);
}